// Round 1
// baseline (1118.397 us; speedup 1.0000x reference)
//
#include <hip/hip_runtime.h>
#include <math.h>

// ---------------- helpers ----------------
__device__ __forceinline__ unsigned fenc(float f){
  unsigned b = __float_as_uint(f);
  return (b & 0x80000000u) ? ~b : (b | 0x80000000u);
}
__device__ __forceinline__ float fdec(unsigned u){
  unsigned b = (u & 0x80000000u) ? (u ^ 0x80000000u) : ~u;
  return __uint_as_float(b);
}

// ---------------- prep ----------------
__global__ __launch_bounds__(256) void init_mind2(unsigned* minD2, int B){
  int i = blockIdx.x*blockDim.x + threadIdx.x;
  if (i < B) minD2[i] = 0xFFFFFFFFu;
}

// k2[m] = sum(mem_keys[m]^2), one wave per row (K=256)
__global__ __launch_bounds__(256) void prep_k2(const float* __restrict__ mk, float* __restrict__ k2, int M){
  int wid = threadIdx.x >> 6, lane = threadIdx.x & 63;
  int row = blockIdx.x*4 + wid;
  if (row >= M) return;
  float4 v = *(const float4*)(mk + (size_t)row*256 + lane*4);
  float s = v.x*v.x + v.y*v.y + v.z*v.z + v.w*v.w;
  for (int off = 32; off > 0; off >>= 1) s += __shfl_down(s, off, 64);
  if (lane == 0) k2[row] = s;
}

// f2[b] = sum(features[b]^2); gn[b] = ||gradients[b]||
__global__ __launch_bounds__(256) void prep_feat(const float* __restrict__ F, const float* __restrict__ G,
                                                 float* __restrict__ f2, float* __restrict__ gn, int B){
  int wid = threadIdx.x >> 6, lane = threadIdx.x & 63;
  int row = blockIdx.x*4 + wid;
  if (row >= B) return;
  float4 a = *(const float4*)(F + (size_t)row*256 + lane*4);
  float4 g = *(const float4*)(G + (size_t)row*256 + lane*4);
  float s = a.x*a.x + a.y*a.y + a.z*a.z + a.w*a.w;
  float t = g.x*g.x + g.y*g.y + g.z*g.z + g.w*g.w;
  for (int off = 32; off > 0; off >>= 1){ s += __shfl_down(s, off, 64); t += __shfl_down(t, off, 64); }
  if (lane == 0){ f2[row] = s; gn[row] = sqrtf(t); }
}

// ---------------- generic tiled GEMM: C[M,N] = A[M,K] @ W[K, ...](ldw, col off) + bias ----------------
__global__ __launch_bounds__(256) void gemm_bias(const float* __restrict__ A, const float* __restrict__ W,
                                                 const float* __restrict__ bias, float* __restrict__ C,
                                                 int M, int K, int N, int ldw, int woff){
  __shared__ float As[32*68];
  __shared__ float Ws[32*68];
  int m0 = blockIdx.x*64, c0 = blockIdx.y*64;
  int t = threadIdx.x;
  int mq = (t & 15)*4, cq = (t >> 4)*4;
  float acc[16];
  #pragma unroll
  for (int i = 0; i < 16; ++i) acc[i] = 0.f;
  for (int k0 = 0; k0 < K; k0 += 32){
    #pragma unroll
    for (int i = 0; i < 2; ++i){
      int idx = t + 256*i;
      int row = idx >> 3, kk = (idx & 7)*4;
      int gm = m0 + row, gk = k0 + kk;
      float x=0.f, y=0.f, z=0.f, w=0.f;
      if (gm < M){
        const float* ap = A + (size_t)gm*K + gk;
        if (gk + 3 < K){ float4 v = *(const float4*)ap; x=v.x; y=v.y; z=v.z; w=v.w; }
        else {
          if (gk   < K) x = ap[0];
          if (gk+1 < K) y = ap[1];
          if (gk+2 < K) z = ap[2];
          if (gk+3 < K) w = ap[3];
        }
      }
      As[(kk+0)*68+row]=x; As[(kk+1)*68+row]=y; As[(kk+2)*68+row]=z; As[(kk+3)*68+row]=w;
    }
    #pragma unroll
    for (int i = 0; i < 2; ++i){
      int idx = t + 256*i;
      int kk = idx >> 4, cc = (idx & 15)*4;
      int gk = k0 + kk, gc = c0 + cc;
      float4 v = make_float4(0.f,0.f,0.f,0.f);
      if (gk < K){
        const float* wp = W + (size_t)gk*ldw + woff + gc;
        if (gc + 3 < N) v = *(const float4*)wp;
        else {
          if (gc   < N) v.x = wp[0];
          if (gc+1 < N) v.y = wp[1];
          if (gc+2 < N) v.z = wp[2];
          if (gc+3 < N) v.w = wp[3];
        }
      }
      *(float4*)(Ws + kk*68 + cc) = v;
    }
    __syncthreads();
    #pragma unroll
    for (int j = 0; j < 32; ++j){
      float4 a = *(const float4*)(As + j*68 + mq);
      float4 w = *(const float4*)(Ws + j*68 + cq);
      acc[ 0]+=a.x*w.x; acc[ 1]+=a.x*w.y; acc[ 2]+=a.x*w.z; acc[ 3]+=a.x*w.w;
      acc[ 4]+=a.y*w.x; acc[ 5]+=a.y*w.y; acc[ 6]+=a.y*w.z; acc[ 7]+=a.y*w.w;
      acc[ 8]+=a.z*w.x; acc[ 9]+=a.z*w.y; acc[10]+=a.z*w.z; acc[11]+=a.z*w.w;
      acc[12]+=a.w*w.x; acc[13]+=a.w*w.y; acc[14]+=a.w*w.z; acc[15]+=a.w*w.w;
    }
    __syncthreads();
  }
  #pragma unroll
  for (int i = 0; i < 4; ++i){
    int gm = m0 + mq + i;
    if (gm >= M) continue;
    #pragma unroll
    for (int j = 0; j < 4; ++j){
      int gc = c0 + cq + j;
      if (gc >= N) continue;
      float r = acc[i*4+j] + (bias ? bias[gc] : 0.f);
      C[(size_t)gm*N + gc] = r;
    }
  }
}

// ---------------- surprise: per-b min over m of (k2[m] - 2 f.k) via atomicMin ----------------
__global__ __launch_bounds__(256) void surprise_min(const float* __restrict__ F, const float* __restrict__ MK,
                                                    const float* __restrict__ k2, unsigned* __restrict__ minD2){
  __shared__ float Fs[32*68];
  __shared__ float Ks[32*68];
  __shared__ float red[64*16];
  int b0 = blockIdx.x*64, m0 = blockIdx.y*64;
  int t = threadIdx.x;
  int bq = (t & 15)*4, mq = (t >> 4)*4;
  float acc[16];
  #pragma unroll
  for (int i = 0; i < 16; ++i) acc[i] = 0.f;
  for (int k0 = 0; k0 < 256; k0 += 32){
    #pragma unroll
    for (int i = 0; i < 2; ++i){
      int idx = t + 256*i;
      int row = idx >> 3, kk = (idx & 7)*4;
      float4 v = *(const float4*)(F  + (size_t)(b0+row)*256 + k0 + kk);
      Fs[(kk+0)*68+row]=v.x; Fs[(kk+1)*68+row]=v.y; Fs[(kk+2)*68+row]=v.z; Fs[(kk+3)*68+row]=v.w;
      float4 u = *(const float4*)(MK + (size_t)(m0+row)*256 + k0 + kk);
      Ks[(kk+0)*68+row]=u.x; Ks[(kk+1)*68+row]=u.y; Ks[(kk+2)*68+row]=u.z; Ks[(kk+3)*68+row]=u.w;
    }
    __syncthreads();
    #pragma unroll
    for (int j = 0; j < 32; ++j){
      float4 a = *(const float4*)(Fs + j*68 + bq);
      float4 w = *(const float4*)(Ks + j*68 + mq);
      acc[ 0]+=a.x*w.x; acc[ 1]+=a.x*w.y; acc[ 2]+=a.x*w.z; acc[ 3]+=a.x*w.w;
      acc[ 4]+=a.y*w.x; acc[ 5]+=a.y*w.y; acc[ 6]+=a.y*w.z; acc[ 7]+=a.y*w.w;
      acc[ 8]+=a.z*w.x; acc[ 9]+=a.z*w.y; acc[10]+=a.z*w.z; acc[11]+=a.z*w.w;
      acc[12]+=a.w*w.x; acc[13]+=a.w*w.y; acc[14]+=a.w*w.z; acc[15]+=a.w*w.w;
    }
    __syncthreads();
  }
  float k2v[4];
  #pragma unroll
  for (int j = 0; j < 4; ++j) k2v[j] = k2[m0 + mq + j];
  #pragma unroll
  for (int i = 0; i < 4; ++i){
    float mn = k2v[0] - 2.f*acc[i*4+0];
    #pragma unroll
    for (int j = 1; j < 4; ++j){
      float v = k2v[j] - 2.f*acc[i*4+j];
      mn = fminf(mn, v);
    }
    red[(bq+i)*16 + (t >> 4)] = mn;
  }
  __syncthreads();
  if (t < 64){
    float mn = red[t*16];
    #pragma unroll
    for (int i = 1; i < 16; ++i) mn = fminf(mn, red[t*16+i]);
    atomicMin(&minD2[b0+t], fenc(mn));
  }
}

__global__ __launch_bounds__(256) void finalize_surprise(const unsigned* __restrict__ minD2,
                                                         const float* __restrict__ f2, const float* __restrict__ gn,
                                                         float* __restrict__ surprise, int* __restrict__ memorize, int B){
  int b = blockIdx.x*blockDim.x + threadIdx.x;
  if (b >= B) return;
  float d2 = fdec(minD2[b]) + f2[b];
  d2 = fmaxf(d2, 0.f);
  float s = gn[b]*sqrtf(d2);
  surprise[b] = s;
  memorize[b] = (s > 0.1f) ? 1 : 0;
}

// ---------------- eviction scan ----------------
// Fast path: the picked slots are the k smallest original p = surp*0.95^age in ascending (p,idx)
// order, valid iff every written surprise > the largest candidate used (checked exactly; slow
// fallback otherwise reproduces the sequential scan faithfully).
#define SCAN_CAP 1024
__global__ __launch_bounds__(1024) void scan_kernel(
    const float* __restrict__ mem_surprise, const float* __restrict__ mem_ages,
    const float* __restrict__ surprise, const int* __restrict__ memorize,
    float* __restrict__ parr, int* __restrict__ slotForB, int* __restrict__ lastB){
  __shared__ unsigned hist[2048];
  __shared__ float candV[SCAN_CAP];
  __shared__ int   candI[SCAN_CAP];
  __shared__ float tv[1024];
  __shared__ int   ti[1024];
  __shared__ int   wtot[16];
  __shared__ int   sh_misc[8]; // [0]=cnt [1]=threshKey [2]=fastOK [3]=min written surprise bits [4]=ktotal
  int t = threadIdx.x;

  // p values -> global scratch; init lastB
  #pragma unroll
  for (int j = 0; j < 16; ++j){
    int m = t*16 + j;
    float p = mem_surprise[m] * powf(0.95f, mem_ages[m]);
    parr[m] = p;
    lastB[m] = -1;
  }
  hist[t] = 0u; hist[t + 1024] = 0u;
  if (t < 8) sh_misc[t] = (t == 3) ? 0x7F800000 : 0;
  __syncthreads();

  // histogram of float-bit key (monotone for p>=0)
  #pragma unroll
  for (int j = 0; j < 16; ++j){
    int m = t*16 + j;
    unsigned key = __float_as_uint(parr[m]) >> 20;
    if (key > 2047u) key = 2047u;
    atomicAdd(&hist[key], 1u);
  }
  __syncthreads();
  // hierarchical threshold search for cumulative >= 512
  if (t < 512){ ti[t] = (int)(hist[4*t] + hist[4*t+1] + hist[4*t+2] + hist[4*t+3]); }
  __syncthreads();
  if (t < 32){ int s = 0; for (int i = 0; i < 16; ++i) s += ti[16*t + i]; ti[512 + t] = s; }
  __syncthreads();
  if (t == 0){
    int cum = 0, i2 = 0;
    for (; i2 < 32; ++i2){ if (cum + ti[512+i2] >= 512) break; cum += ti[512+i2]; }
    int i1 = i2*16;
    for (;; ++i1){ if (cum + ti[i1] >= 512) break; cum += ti[i1]; }
    int bin = i1*4;
    for (;; ++bin){ if (cum + (int)hist[bin] >= 512) break; cum += (int)hist[bin]; }
    sh_misc[1] = bin;
  }
  __syncthreads();
  int threshKey = sh_misc[1];
  // collect candidates
  #pragma unroll
  for (int j = 0; j < 16; ++j){
    int m = t*16 + j;
    unsigned key = __float_as_uint(parr[m]) >> 20;
    if (key > 2047u) key = 2047u;
    if ((int)key <= threshKey){
      int pos = atomicAdd(&sh_misc[0], 1);
      if (pos < SCAN_CAP){ candV[pos] = parr[m]; candI[pos] = m; }
    }
  }
  __syncthreads();
  int cnt = sh_misc[0];
  if (t >= cnt && t < SCAN_CAP){ candV[t] = INFINITY; candI[t] = 0x7FFFFFFF; }
  __syncthreads();
  // bitonic sort (p, idx) ascending
  for (int ksz = 2; ksz <= SCAN_CAP; ksz <<= 1){
    for (int jj = ksz >> 1; jj > 0; jj >>= 1){
      int ixj = t ^ jj;
      if (ixj > t){
        float v1 = candV[t], v2 = candV[ixj];
        int i1 = candI[t], i2 = candI[ixj];
        bool lt21 = (v2 < v1) || (v2 == v1 && i2 < i1);
        bool lt12 = (v1 < v2) || (v1 == v2 && i1 < i2);
        bool up = ((t & ksz) == 0);
        bool sw = up ? lt21 : lt12;
        if (sw){ candV[t] = v2; candI[t] = i2; candV[ixj] = v1; candI[ixj] = i1; }
      }
      __syncthreads();
    }
  }
  // memorize prefix + validation
  int mem = (t < 512) ? memorize[t] : 0;
  int lp = 0;
  if (t < 512){
    unsigned long long mask = __ballot(mem != 0);
    int lane = t & 63;
    lp = __popcll(mask & ((1ull << lane) - 1ull));
    if (lane == 0) wtot[t >> 6] = __popcll(mask);
  }
  if (t < 512 && mem) atomicMin(&sh_misc[3], __float_as_int(surprise[t]));
  __syncthreads();
  if (t == 0){
    int ksum = 0;
    for (int wv = 0; wv < 8; ++wv) ksum += wtot[wv];
    sh_misc[4] = ksum;
    bool okf = (cnt <= SCAN_CAP) && (ksum <= cnt);
    if (okf && ksum > 0){
      float minw = __int_as_float(sh_misc[3]);
      okf = (minw > candV[ksum - 1]);
    }
    sh_misc[2] = okf ? 1 : 0;
  }
  __syncthreads();
  if (sh_misc[2] == 1){
    if (t < 512){
      int wv = t >> 6, base = 0;
      for (int i = 0; i < wv; ++i) base += wtot[i];
      int slot = -1;
      if (mem){ slot = candI[base + lp]; atomicMax(&lastB[slot], t); }
      slotForB[t] = slot;
    }
  } else {
    // exact sequential fallback (general-case correct; effectively never taken on this data)
    for (int b = 0; b < 512; ++b){
      float bv = parr[t*16]; int bi = t*16;
      #pragma unroll
      for (int j = 1; j < 16; ++j){
        float v = parr[t*16 + j];
        if (v < bv){ bv = v; bi = t*16 + j; }
      }
      tv[t] = bv; ti[t] = bi;
      __syncthreads();
      for (int s = 512; s > 0; s >>= 1){
        if (t < s){
          float v2 = tv[t+s]; int i2 = ti[t+s];
          if (v2 < tv[t] || (v2 == tv[t] && i2 < ti[t])){ tv[t] = v2; ti[t] = i2; }
        }
        __syncthreads();
      }
      int slot = ti[0];
      int memb = memorize[b];
      if (t == 0) slotForB[b] = memb ? slot : -1;
      if (memb && t == (slot >> 4)) parr[slot] = surprise[b];
      __syncthreads();
    }
    if (t < 512){ int s = slotForB[t]; if (s >= 0) atomicMax(&lastB[s], t); }
  }
}

// ---------------- fixup written slots: kh[slot] = newK[b]@Wpk + bpk, vh[slot] = newV[b]@Wpv + bpv ----------------
__global__ __launch_bounds__(64) void fixup_rows(const int* __restrict__ slotForB, const int* __restrict__ lastB,
                                                 const float* __restrict__ newK, const float* __restrict__ newV,
                                                 const float* __restrict__ Wpk, const float* __restrict__ Wpv,
                                                 const float* __restrict__ bpk, const float* __restrict__ bpv,
                                                 float* __restrict__ kh, float* __restrict__ vh){
  int b = blockIdx.x;
  int slot = slotForB[b];
  if (slot < 0) return;
  if (lastB[slot] != b) return;
  __shared__ float kr[256], vr[256];
  int t = threadIdx.x;
  *(float4*)(kr + t*4) = *(const float4*)(newK + (size_t)b*256 + t*4);
  *(float4*)(vr + t*4) = *(const float4*)(newV + (size_t)b*256 + t*4);
  __syncthreads();
  for (int c = t; c < 264; c += 64){
    float aK = bpk[c], aV = bpv[c];
    for (int k = 0; k < 256; ++k){
      aK += kr[k]*Wpk[(size_t)k*264 + c];
      aV += vr[k]*Wpv[(size_t)k*264 + c];
    }
    kh[(size_t)slot*264 + c] = aK;
    vh[(size_t)slot*264 + c] = aV;
  }
}

// ---------------- fused bias precompute: out[c] = addv[c] + sum_k vin[k]*W[k*ldw+woff+c] ----------------
__global__ __launch_bounds__(256) void fuse_bias(const float* __restrict__ vin, const float* __restrict__ W,
                                                 const float* __restrict__ addv, float* __restrict__ outv,
                                                 int K, int N, int ldw, int woff){
  int c = blockIdx.x*blockDim.x + threadIdx.x;
  if (c >= N) return;
  float a = addv[c];
  for (int k = 0; k < K; ++k) a += vin[k]*W[(size_t)k*ldw + woff + c];
  outv[c] = a;
}

// ---------------- flash attention partials: grid (h=8, btile=8, msplit=8), block 256 ----------------
__global__ __launch_bounds__(256) void attn_kernel(
    const float* __restrict__ qh, const float* __restrict__ kh, const float* __restrict__ vh,
    float* __restrict__ pm, float* __restrict__ pl, float* __restrict__ pctx){
  const int h = blockIdx.x, bt = blockIdx.y, ms = blockIdx.z;
  const int b0 = bt*64;
  const int mbase = ms*2048;
  const int t = threadIdx.x;
  __shared__ float qsT[33*68];
  __shared__ float ksT[33*68];
  __shared__ float vsm[64*36];
  __shared__ float PsT[64*68];
  __shared__ float ctxs[64*36];
  __shared__ float rM[64], rL[64], alf[64];
  __shared__ float red[64*16];

  for (int e = t; e < 2112; e += 256){
    int bl = e/33, d = e - bl*33;
    qsT[d*68 + bl] = qh[(size_t)(b0+bl)*264 + h*33 + d];
  }
  for (int e = t; e < 64*36; e += 256) ctxs[e] = 0.f;
  for (int e = t; e < 192; e += 256){ int ml = e/3; vsm[ml*36 + 33 + (e - ml*3)] = 0.f; }
  if (t < 64){ rM[t] = -INFINITY; rL[t] = 0.f; }
  const float scale = 0.17407765595569785f; // 1/sqrt(33)
  const int bq = (t & 15)*4;
  const int mq = (t >> 4)*4;
  const int dq = (t >> 4);

  for (int mt = 0; mt < 32; ++mt){
    const int m0 = mbase + mt*64;
    __syncthreads();
    for (int e = t; e < 2112; e += 256){
      int ml = e/33, d = e - ml*33;
      size_t gi = (size_t)(m0+ml)*264 + h*33 + d;
      ksT[d*68 + ml] = kh[gi];
      vsm[ml*36 + d] = vh[gi];
    }
    __syncthreads();
    float s[16];
    #pragma unroll
    for (int i = 0; i < 16; ++i) s[i] = 0.f;
    #pragma unroll
    for (int d = 0; d < 33; ++d){
      float4 qa = *(const float4*)(qsT + d*68 + bq);
      float4 kb = *(const float4*)(ksT + d*68 + mq);
      s[ 0]+=qa.x*kb.x; s[ 1]+=qa.x*kb.y; s[ 2]+=qa.x*kb.z; s[ 3]+=qa.x*kb.w;
      s[ 4]+=qa.y*kb.x; s[ 5]+=qa.y*kb.y; s[ 6]+=qa.y*kb.z; s[ 7]+=qa.y*kb.w;
      s[ 8]+=qa.z*kb.x; s[ 9]+=qa.z*kb.y; s[10]+=qa.z*kb.z; s[11]+=qa.z*kb.w;
      s[12]+=qa.w*kb.x; s[13]+=qa.w*kb.y; s[14]+=qa.w*kb.z; s[15]+=qa.w*kb.w;
    }
    #pragma unroll
    for (int i = 0; i < 16; ++i) s[i] *= scale;
    #pragma unroll
    for (int i = 0; i < 4; ++i){
      float mx = fmaxf(fmaxf(s[i*4+0], s[i*4+1]), fmaxf(s[i*4+2], s[i*4+3]));
      red[(bq+i)*16 + (t >> 4)] = mx;
    }
    __syncthreads();
    if (t < 64){
      float mx = red[t*16];
      #pragma unroll
      for (int i = 1; i < 16; ++i) mx = fmaxf(mx, red[t*16+i]);
      float old = rM[t];
      float nm = fmaxf(old, mx);
      alf[t] = expf(old - nm);
      rM[t] = nm;
    }
    __syncthreads();
    #pragma unroll
    for (int i = 0; i < 4; ++i){
      float rsum = 0.f;
      float nm = rM[bq+i];
      #pragma unroll
      for (int j = 0; j < 4; ++j){
        float p = expf(s[i*4+j] - nm);
        PsT[(mq+j)*68 + (bq+i)] = p;
        rsum += p;
      }
      red[(bq+i)*16 + (t >> 4)] = rsum;
    }
    __syncthreads();
    if (t < 64){
      float sm = 0.f;
      #pragma unroll
      for (int i = 0; i < 16; ++i) sm += red[t*16+i];
      rL[t] = rL[t]*alf[t] + sm;
    }
    if (dq < 9){
      float acc2[16];
      #pragma unroll
      for (int i = 0; i < 16; ++i) acc2[i] = 0.f;
      #pragma unroll
      for (int m = 0; m < 64; ++m){
        float4 pa = *(const float4*)(PsT + m*68 + bq);
        float4 vb = *(const float4*)(vsm + m*36 + dq*4);
        acc2[ 0]+=pa.x*vb.x; acc2[ 1]+=pa.x*vb.y; acc2[ 2]+=pa.x*vb.z; acc2[ 3]+=pa.x*vb.w;
        acc2[ 4]+=pa.y*vb.x; acc2[ 5]+=pa.y*vb.y; acc2[ 6]+=pa.y*vb.z; acc2[ 7]+=pa.y*vb.w;
        acc2[ 8]+=pa.z*vb.x; acc2[ 9]+=pa.z*vb.y; acc2[10]+=pa.z*vb.z; acc2[11]+=pa.z*vb.w;
        acc2[12]+=pa.w*vb.x; acc2[13]+=pa.w*vb.y; acc2[14]+=pa.w*vb.z; acc2[15]+=pa.w*vb.w;
      }
      #pragma unroll
      for (int i = 0; i < 4; ++i){
        float al = alf[bq+i];
        #pragma unroll
        for (int j = 0; j < 4; ++j){
          float* cp = ctxs + (bq+i)*36 + dq*4 + j;
          *cp = (*cp)*al + acc2[i*4+j];
        }
      }
    }
  }
  __syncthreads();
  int g = (h*8 + bt)*8 + ms;
  if (t < 64){ pm[(size_t)g*64 + t] = rM[t]; pl[(size_t)g*64 + t] = rL[t]; }
  for (int e = t; e < 2112; e += 256){
    int bl = e/33, d = e - bl*33;
    pctx[((size_t)g*64 + bl)*33 + d] = ctxs[bl*36 + d];
  }
}

__global__ __launch_bounds__(256) void combine_kernel(const float* __restrict__ pm, const float* __restrict__ pl,
                                                      const float* __restrict__ pctx, float* __restrict__ ctxf){
  int idx = blockIdx.x*256 + threadIdx.x;
  if (idx >= 512*264) return;
  int b = idx / 264, c = idx - b*264;
  int h = c / 33, d = c - h*33;
  int bt = b >> 6, bl = b & 63;
  int g0 = (h*8 + bt)*8;
  float gm = -INFINITY;
  for (int ms = 0; ms < 8; ++ms) gm = fmaxf(gm, pm[(g0+ms)*64 + bl]);
  float L = 0.f, cv = 0.f;
  for (int ms = 0; ms < 8; ++ms){
    int gg = (g0+ms)*64 + bl;
    float w = expf(pm[gg] - gm);
    L += pl[gg]*w;
    cv += pctx[(size_t)gg*33 + d]*w;
  }
  ctxf[idx] = cv / L;
}

// ---------------- host ----------------
extern "C" void kernel_launch(void* const* d_in, const int* in_sizes, int n_in,
                              void* d_out, int out_size, void* d_ws, size_t ws_size,
                              hipStream_t stream){
  (void)in_sizes; (void)n_in; (void)out_size; (void)ws_size;
  const float* features     = (const float*)d_in[0];
  const float* gradients    = (const float*)d_in[1];
  const float* mem_keys     = (const float*)d_in[2];
  const float* mem_values   = (const float*)d_in[3];
  const float* mem_ages     = (const float*)d_in[4];
  const float* mem_surprise = (const float*)d_in[5];
  const float* Wk   = (const float*)d_in[6];
  const float* bk   = (const float*)d_in[7];
  const float* Wv   = (const float*)d_in[8];
  const float* bv   = (const float*)d_in[9];
  const float* Wp   = (const float*)d_in[10];
  const float* bp   = (const float*)d_in[11];
  const float* Win  = (const float*)d_in[12];
  const float* b_in = (const float*)d_in[13];
  const float* Wout = (const float*)d_in[14];
  const float* bout = (const float*)d_in[15];
  const float* Wo   = (const float*)d_in[16];
  const float* bo   = (const float*)d_in[17];
  float* out = (float*)d_out;

  float* w = (float*)d_ws;
  size_t off = 0;
  auto alloc = [&](size_t n)->float*{ float* p = w + off; off += (n + 63) & ~(size_t)63; return p; };
  float*    k2       = alloc(16384);
  unsigned* minD2    = (unsigned*)alloc(512);
  float*    f2       = alloc(512);
  float*    gn       = alloc(512);
  float*    surprise = alloc(512);
  int*      memorize = (int*)alloc(512);
  int*      slotForB = (int*)alloc(512);
  int*      lastB    = (int*)alloc(16384);
  float*    parr     = alloc(16384);
  float*    newK     = alloc((size_t)512*256);
  float*    newV     = alloc((size_t)512*256);
  float*    qh       = alloc((size_t)512*264);
  float*    kh       = alloc((size_t)16384*264);
  float*    vh       = alloc((size_t)16384*264);
  float*    Wpk      = alloc((size_t)256*264);
  float*    Wpv      = alloc((size_t)256*264);
  float*    Wpq      = alloc((size_t)256*264);
  float*    Wco      = alloc((size_t)264*256);
  float*    bpk      = alloc(264);
  float*    bpv      = alloc(264);
  float*    bpq      = alloc(264);
  float*    bco      = alloc(256);
  float*    ctxf     = alloc((size_t)512*264);
  float*    pm       = alloc((size_t)512*64);
  float*    pl       = alloc((size_t)512*64);
  float*    pctx     = alloc((size_t)512*64*33);

  init_mind2<<<2, 256, 0, stream>>>(minD2, 512);
  prep_k2<<<4096, 256, 0, stream>>>(mem_keys, k2, 16384);
  prep_feat<<<128, 256, 0, stream>>>(features, gradients, f2, gn, 512);

  // fused projection weights: Wpx = Wp @ Win-slice ; Wco = Wout @ Wo
  gemm_bias<<<dim3(4,5), 256, 0, stream>>>(Wp, Win, nullptr, Wpk, 256, 264, 264, 792, 264);
  gemm_bias<<<dim3(4,5), 256, 0, stream>>>(Wp, Win, nullptr, Wpv, 256, 264, 264, 792, 528);
  gemm_bias<<<dim3(4,5), 256, 0, stream>>>(Wp, Win, nullptr, Wpq, 256, 264, 264, 792, 0);
  gemm_bias<<<dim3(5,4), 256, 0, stream>>>(Wout, Wo, nullptr, Wco, 264, 264, 256, 256, 0);
  fuse_bias<<<2, 256, 0, stream>>>(bp, Win, b_in + 264, bpk, 264, 264, 792, 264);
  fuse_bias<<<2, 256, 0, stream>>>(bp, Win, b_in + 528, bpv, 264, 264, 792, 528);
  fuse_bias<<<2, 256, 0, stream>>>(bp, Win, b_in,       bpq, 264, 264, 792, 0);
  fuse_bias<<<1, 256, 0, stream>>>(bout, Wo, bo,        bco, 264, 256, 256, 0);

  // candidate writes and projections
  gemm_bias<<<dim3(8,4), 256, 0, stream>>>(features, Wk, bk, newK, 512, 256, 256, 256, 0);
  gemm_bias<<<dim3(8,4), 256, 0, stream>>>(features, Wv, bv, newV, 512, 256, 256, 256, 0);
  gemm_bias<<<dim3(8,5), 256, 0, stream>>>(features, Wpq, bpq, qh, 512, 256, 264, 264, 0);
  gemm_bias<<<dim3(256,5), 256, 0, stream>>>(mem_keys,   Wpk, bpk, kh, 16384, 256, 264, 264, 0);
  gemm_bias<<<dim3(256,5), 256, 0, stream>>>(mem_values, Wpv, bpv, vh, 16384, 256, 264, 264, 0);

  // surprise + scan + fixup
  surprise_min<<<dim3(8,256), 256, 0, stream>>>(features, mem_keys, k2, minD2);
  finalize_surprise<<<2, 256, 0, stream>>>(minD2, f2, gn, surprise, memorize, 512);
  scan_kernel<<<1, 1024, 0, stream>>>(mem_surprise, mem_ages, surprise, memorize, parr, slotForB, lastB);
  fixup_rows<<<512, 64, 0, stream>>>(slotForB, lastB, newK, newV, Wpk, Wpv, bpk, bpv, kh, vh);

  // attention + output
  attn_kernel<<<dim3(8,8,8), 256, 0, stream>>>(qh, kh, vh, pm, pl, pctx);
  combine_kernel<<<528, 256, 0, stream>>>(pm, pl, pctx, ctxf);
  gemm_bias<<<dim3(8,4), 256, 0, stream>>>(ctxf, Wco, bco, out, 512, 264, 256, 256, 0);
}

// Round 2
// 1017.119 us; speedup vs baseline: 1.0996x; 1.0996x over previous
//
#include <hip/hip_runtime.h>
#include <math.h>

typedef unsigned short ushort_t;
typedef float v4f __attribute__((ext_vector_type(4)));
typedef short v8s __attribute__((ext_vector_type(8)));

// ---------------- helpers ----------------
__device__ __forceinline__ unsigned fenc(float f){
  unsigned b = __float_as_uint(f);
  return (b & 0x80000000u) ? ~b : (b | 0x80000000u);
}
__device__ __forceinline__ float fdec(unsigned u){
  unsigned b = (u & 0x80000000u) ? (u ^ 0x80000000u) : ~u;
  return __uint_as_float(b);
}
// round-to-nearest-even f32 -> bf16, plus split (x ~= hi + lo)
__device__ __forceinline__ ushort_t bf16_rne(float x){
  unsigned u = __float_as_uint(x);
  unsigned r = u + 0x7FFFu + ((u >> 16) & 1u);
  return (ushort_t)(r >> 16);
}
__device__ __forceinline__ void split2(float x, ushort_t& h, ushort_t& l){
  unsigned u = __float_as_uint(x);
  unsigned r = u + 0x7FFFu + ((u >> 16) & 1u);
  h = (ushort_t)(r >> 16);
  float hf = __uint_as_float(r & 0xFFFF0000u);
  l = bf16_rne(x - hf);
}

// ---------------- prep ----------------
__global__ __launch_bounds__(256) void init_mind2(unsigned* minD2, int B){
  int i = blockIdx.x*blockDim.x + threadIdx.x;
  if (i < B) minD2[i] = 0xFFFFFFFFu;
}

__global__ __launch_bounds__(256) void prep_k2(const float* __restrict__ mk, float* __restrict__ k2, int M){
  int wid = threadIdx.x >> 6, lane = threadIdx.x & 63;
  int row = blockIdx.x*4 + wid;
  if (row >= M) return;
  float4 v = *(const float4*)(mk + (size_t)row*256 + lane*4);
  float s = v.x*v.x + v.y*v.y + v.z*v.z + v.w*v.w;
  for (int off = 32; off > 0; off >>= 1) s += __shfl_down(s, off, 64);
  if (lane == 0) k2[row] = s;
}

__global__ __launch_bounds__(256) void prep_feat(const float* __restrict__ F, const float* __restrict__ G,
                                                 float* __restrict__ f2, float* __restrict__ gn, int B){
  int wid = threadIdx.x >> 6, lane = threadIdx.x & 63;
  int row = blockIdx.x*4 + wid;
  if (row >= B) return;
  float4 a = *(const float4*)(F + (size_t)row*256 + lane*4);
  float4 g = *(const float4*)(G + (size_t)row*256 + lane*4);
  float s = a.x*a.x + a.y*a.y + a.z*a.z + a.w*a.w;
  float t = g.x*g.x + g.y*g.y + g.z*g.z + g.w*g.w;
  for (int off = 32; off > 0; off >>= 1){ s += __shfl_down(s, off, 64); t += __shfl_down(t, off, 64); }
  if (lane == 0){ f2[row] = s; gn[row] = sqrtf(t); }
}

// transpose + split weight: W[K=256][N] -> H/L[NP][256] (rows >= N zero-filled)
__global__ __launch_bounds__(256) void tsplit_w(const float* __restrict__ W, ushort_t* __restrict__ H,
                                                ushort_t* __restrict__ L, int N, int NP){
  int n = blockIdx.x;
  int k = threadIdx.x;
  float x = (n < N) ? W[(size_t)k*N + n] : 0.f;
  ushort_t h, l; split2(x, h, l);
  H[(size_t)n*256 + k] = h;
  L[(size_t)n*256 + k] = l;
}

// ---------------- generic small f32 GEMM (kept for small matrices) ----------------
__global__ __launch_bounds__(256) void gemm_bias(const float* __restrict__ A, const float* __restrict__ W,
                                                 const float* __restrict__ bias, float* __restrict__ C,
                                                 int M, int K, int N, int ldw, int woff){
  __shared__ float As[32*68];
  __shared__ float Ws[32*68];
  int m0 = blockIdx.x*64, c0 = blockIdx.y*64;
  int t = threadIdx.x;
  int mq = (t & 15)*4, cq = (t >> 4)*4;
  float acc[16];
  #pragma unroll
  for (int i = 0; i < 16; ++i) acc[i] = 0.f;
  for (int k0 = 0; k0 < K; k0 += 32){
    #pragma unroll
    for (int i = 0; i < 2; ++i){
      int idx = t + 256*i;
      int row = idx >> 3, kk = (idx & 7)*4;
      int gm = m0 + row, gk = k0 + kk;
      float x=0.f, y=0.f, z=0.f, w=0.f;
      if (gm < M){
        const float* ap = A + (size_t)gm*K + gk;
        if (gk + 3 < K){ float4 v = *(const float4*)ap; x=v.x; y=v.y; z=v.z; w=v.w; }
        else {
          if (gk   < K) x = ap[0];
          if (gk+1 < K) y = ap[1];
          if (gk+2 < K) z = ap[2];
          if (gk+3 < K) w = ap[3];
        }
      }
      As[(kk+0)*68+row]=x; As[(kk+1)*68+row]=y; As[(kk+2)*68+row]=z; As[(kk+3)*68+row]=w;
    }
    #pragma unroll
    for (int i = 0; i < 2; ++i){
      int idx = t + 256*i;
      int kk = idx >> 4, cc = (idx & 15)*4;
      int gk = k0 + kk, gc = c0 + cc;
      float4 v = make_float4(0.f,0.f,0.f,0.f);
      if (gk < K){
        const float* wp = W + (size_t)gk*ldw + woff + gc;
        if (gc + 3 < N) v = *(const float4*)wp;
        else {
          if (gc   < N) v.x = wp[0];
          if (gc+1 < N) v.y = wp[1];
          if (gc+2 < N) v.z = wp[2];
          if (gc+3 < N) v.w = wp[3];
        }
      }
      *(float4*)(Ws + kk*68 + cc) = v;
    }
    __syncthreads();
    #pragma unroll
    for (int j = 0; j < 32; ++j){
      float4 a = *(const float4*)(As + j*68 + mq);
      float4 w = *(const float4*)(Ws + j*68 + cq);
      acc[ 0]+=a.x*w.x; acc[ 1]+=a.x*w.y; acc[ 2]+=a.x*w.z; acc[ 3]+=a.x*w.w;
      acc[ 4]+=a.y*w.x; acc[ 5]+=a.y*w.y; acc[ 6]+=a.y*w.z; acc[ 7]+=a.y*w.w;
      acc[ 8]+=a.z*w.x; acc[ 9]+=a.z*w.y; acc[10]+=a.z*w.z; acc[11]+=a.z*w.w;
      acc[12]+=a.w*w.x; acc[13]+=a.w*w.y; acc[14]+=a.w*w.z; acc[15]+=a.w*w.w;
    }
    __syncthreads();
  }
  #pragma unroll
  for (int i = 0; i < 4; ++i){
    int gm = m0 + mq + i;
    if (gm >= M) continue;
    #pragma unroll
    for (int j = 0; j < 4; ++j){
      int gc = c0 + cq + j;
      if (gc >= N) continue;
      float r = acc[i*4+j] + (bias ? bias[gc] : 0.f);
      C[(size_t)gm*N + gc] = r;
    }
  }
}

// ---------------- MFMA split-bf16 GEMM: C[M,N<=Ntile*grid] = A[M,256] @ Wt^T + bias ----------------
// A: f32 row-major [M][256] (split on the fly). Wt: pre-split bf16 [NP][256] (hi/lo).
// Tile: M=128, N=64, 4 waves in 2x2 (each wave 64m x 32n).
__global__ __launch_bounds__(256) void gemm_mfma_split(const float* __restrict__ A,
                                                       const ushort_t* __restrict__ WtH, const ushort_t* __restrict__ WtL,
                                                       const float* __restrict__ bias, float* __restrict__ C, int N){
  __shared__ ushort_t AsH[128*40];
  __shared__ ushort_t AsL[128*40];
  __shared__ ushort_t BsH[64*40];
  __shared__ ushort_t BsL[64*40];
  int t = threadIdx.x;
  int m0 = blockIdx.x*128, n0 = blockIdx.y*64;
  int lane = t & 63, w = t >> 6;
  int wm = (w & 1)*64, wn = (w >> 1)*32;
  int l15 = lane & 15, q = lane >> 4;
  v4f acc[4][2];
  #pragma unroll
  for (int i = 0; i < 4; ++i)
    #pragma unroll
    for (int j = 0; j < 2; ++j) acc[i][j] = (v4f){0.f,0.f,0.f,0.f};

  for (int k0 = 0; k0 < 256; k0 += 32){
    // stage A: 128 rows x 32 k (f32 -> split bf16)
    #pragma unroll
    for (int rdx = 0; rdx < 4; ++rdx){
      int idx = t + 256*rdx;            // 0..1023
      int row = idx >> 3, kq = idx & 7;
      float4 v = *(const float4*)(A + (size_t)(m0+row)*256 + k0 + kq*4);
      ushort_t h0,h1,h2,h3,l0,l1,l2,l3;
      split2(v.x,h0,l0); split2(v.y,h1,l1); split2(v.z,h2,l2); split2(v.w,h3,l3);
      uint2 hp = make_uint2((unsigned)h0 | ((unsigned)h1<<16), (unsigned)h2 | ((unsigned)h3<<16));
      uint2 lp = make_uint2((unsigned)l0 | ((unsigned)l1<<16), (unsigned)l2 | ((unsigned)l3<<16));
      *(uint2*)(AsH + row*40 + kq*4) = hp;
      *(uint2*)(AsL + row*40 + kq*4) = lp;
    }
    // stage B: 64 rows x 32 k (already split in global)
    #pragma unroll
    for (int rdx = 0; rdx < 2; ++rdx){
      int idx = t + 256*rdx;            // 0..511
      int row = idx >> 3, kq = idx & 7;
      uint2 hp = *(const uint2*)(WtH + (size_t)(n0+row)*256 + k0 + kq*4);
      uint2 lp = *(const uint2*)(WtL + (size_t)(n0+row)*256 + k0 + kq*4);
      *(uint2*)(BsH + row*40 + kq*4) = hp;
      *(uint2*)(BsL + row*40 + kq*4) = lp;
    }
    __syncthreads();
    v8s aH[4], aL[4], bH[2], bL[2];
    #pragma unroll
    for (int im = 0; im < 4; ++im){
      aH[im] = *(const v8s*)(AsH + (wm + im*16 + l15)*40 + q*8);
      aL[im] = *(const v8s*)(AsL + (wm + im*16 + l15)*40 + q*8);
    }
    #pragma unroll
    for (int jn = 0; jn < 2; ++jn){
      bH[jn] = *(const v8s*)(BsH + (wn + jn*16 + l15)*40 + q*8);
      bL[jn] = *(const v8s*)(BsL + (wn + jn*16 + l15)*40 + q*8);
    }
    #pragma unroll
    for (int im = 0; im < 4; ++im)
      #pragma unroll
      for (int jn = 0; jn < 2; ++jn){
        acc[im][jn] = __builtin_amdgcn_mfma_f32_16x16x32_bf16(aH[im], bH[jn], acc[im][jn], 0, 0, 0);
        acc[im][jn] = __builtin_amdgcn_mfma_f32_16x16x32_bf16(aH[im], bL[jn], acc[im][jn], 0, 0, 0);
        acc[im][jn] = __builtin_amdgcn_mfma_f32_16x16x32_bf16(aL[im], bH[jn], acc[im][jn], 0, 0, 0);
      }
    __syncthreads();
  }
  #pragma unroll
  for (int im = 0; im < 4; ++im){
    #pragma unroll
    for (int jn = 0; jn < 2; ++jn){
      int n = n0 + wn + jn*16 + l15;
      if (n >= N) continue;
      float bv = bias[n];
      #pragma unroll
      for (int r = 0; r < 4; ++r){
        int m = m0 + wm + im*16 + q*4 + r;
        C[(size_t)m*N + n] = acc[im][jn][r] + bv;
      }
    }
  }
}

// ---------------- MFMA surprise: per-b min over m of (k2[m] - 2 f.k), plain bf16 ----------------
__global__ __launch_bounds__(256) void surprise_mfma(const float* __restrict__ MK, const float* __restrict__ F,
                                                     const float* __restrict__ k2, unsigned* __restrict__ minD2){
  __shared__ ushort_t AsH[128*40];
  __shared__ ushort_t BsH[64*40];
  __shared__ unsigned sminU[64];
  int t = threadIdx.x;
  int m0 = blockIdx.x*128, b0 = blockIdx.y*64;
  int lane = t & 63, w = t >> 6;
  int wm = (w & 1)*64, wn = (w >> 1)*32;
  int l15 = lane & 15, q = lane >> 4;
  if (t < 64) sminU[t] = 0xFFFFFFFFu;
  v4f acc[4][2];
  #pragma unroll
  for (int i = 0; i < 4; ++i)
    #pragma unroll
    for (int j = 0; j < 2; ++j) acc[i][j] = (v4f){0.f,0.f,0.f,0.f};

  for (int k0 = 0; k0 < 256; k0 += 32){
    #pragma unroll
    for (int rdx = 0; rdx < 4; ++rdx){
      int idx = t + 256*rdx;
      int row = idx >> 3, kq = idx & 7;
      float4 v = *(const float4*)(MK + (size_t)(m0+row)*256 + k0 + kq*4);
      unsigned h0=bf16_rne(v.x), h1=bf16_rne(v.y), h2=bf16_rne(v.z), h3=bf16_rne(v.w);
      *(uint2*)(AsH + row*40 + kq*4) = make_uint2(h0 | (h1<<16), h2 | (h3<<16));
    }
    #pragma unroll
    for (int rdx = 0; rdx < 2; ++rdx){
      int idx = t + 256*rdx;
      int row = idx >> 3, kq = idx & 7;
      float4 v = *(const float4*)(F + (size_t)(b0+row)*256 + k0 + kq*4);
      unsigned h0=bf16_rne(v.x), h1=bf16_rne(v.y), h2=bf16_rne(v.z), h3=bf16_rne(v.w);
      *(uint2*)(BsH + row*40 + kq*4) = make_uint2(h0 | (h1<<16), h2 | (h3<<16));
    }
    __syncthreads();
    v8s aH[4], bH[2];
    #pragma unroll
    for (int im = 0; im < 4; ++im) aH[im] = *(const v8s*)(AsH + (wm + im*16 + l15)*40 + q*8);
    #pragma unroll
    for (int jn = 0; jn < 2; ++jn) bH[jn] = *(const v8s*)(BsH + (wn + jn*16 + l15)*40 + q*8);
    #pragma unroll
    for (int im = 0; im < 4; ++im)
      #pragma unroll
      for (int jn = 0; jn < 2; ++jn)
        acc[im][jn] = __builtin_amdgcn_mfma_f32_16x16x32_bf16(aH[im], bH[jn], acc[im][jn], 0, 0, 0);
    __syncthreads();
  }
  // k2 per (im, r)
  float kk[4][4];
  #pragma unroll
  for (int im = 0; im < 4; ++im)
    #pragma unroll
    for (int r = 0; r < 4; ++r) kk[im][r] = k2[m0 + wm + im*16 + q*4 + r];
  #pragma unroll
  for (int jn = 0; jn < 2; ++jn){
    float mv = INFINITY;
    #pragma unroll
    for (int im = 0; im < 4; ++im)
      #pragma unroll
      for (int r = 0; r < 4; ++r)
        mv = fminf(mv, kk[im][r] - 2.f*acc[im][jn][r]);
    // reduce across quads (m-dim within wave)
    mv = fminf(mv, __shfl_xor(mv, 16, 64));
    mv = fminf(mv, __shfl_xor(mv, 32, 64));
    if (q == 0) atomicMin(&sminU[wn + jn*16 + l15], fenc(mv));
  }
  __syncthreads();
  if (t < 64) atomicMin(&minD2[b0 + t], sminU[t]);
}

__global__ __launch_bounds__(256) void finalize_surprise(const unsigned* __restrict__ minD2,
                                                         const float* __restrict__ f2, const float* __restrict__ gn,
                                                         float* __restrict__ surprise, int* __restrict__ memorize, int B){
  int b = blockIdx.x*blockDim.x + threadIdx.x;
  if (b >= B) return;
  float d2 = fdec(minD2[b]) + f2[b];
  d2 = fmaxf(d2, 0.f);
  float s = gn[b]*sqrtf(d2);
  surprise[b] = s;
  memorize[b] = (s > 0.1f) ? 1 : 0;
}

// ---------------- eviction scan (fast path + exact fallback) ----------------
#define SCAN_CAP 1024
__global__ __launch_bounds__(1024) void scan_kernel(
    const float* __restrict__ mem_surprise, const float* __restrict__ mem_ages,
    const float* __restrict__ surprise, const int* __restrict__ memorize,
    float* __restrict__ parr, int* __restrict__ slotForB, int* __restrict__ lastB){
  __shared__ unsigned hist[2048];
  __shared__ float candV[SCAN_CAP];
  __shared__ int   candI[SCAN_CAP];
  __shared__ float tv[1024];
  __shared__ int   ti[1024];
  __shared__ int   wtot[16];
  __shared__ int   sh_misc[8];
  int t = threadIdx.x;

  #pragma unroll
  for (int j = 0; j < 16; ++j){
    int m = t*16 + j;
    float p = mem_surprise[m] * powf(0.95f, mem_ages[m]);
    parr[m] = p;
    lastB[m] = -1;
  }
  hist[t] = 0u; hist[t + 1024] = 0u;
  if (t < 8) sh_misc[t] = (t == 3) ? 0x7F800000 : 0;
  __syncthreads();

  #pragma unroll
  for (int j = 0; j < 16; ++j){
    int m = t*16 + j;
    unsigned key = __float_as_uint(parr[m]) >> 20;
    if (key > 2047u) key = 2047u;
    atomicAdd(&hist[key], 1u);
  }
  __syncthreads();
  if (t < 512){ ti[t] = (int)(hist[4*t] + hist[4*t+1] + hist[4*t+2] + hist[4*t+3]); }
  __syncthreads();
  if (t < 32){ int s = 0; for (int i = 0; i < 16; ++i) s += ti[16*t + i]; ti[512 + t] = s; }
  __syncthreads();
  if (t == 0){
    int cum = 0, i2 = 0;
    for (; i2 < 32; ++i2){ if (cum + ti[512+i2] >= 512) break; cum += ti[512+i2]; }
    int i1 = i2*16;
    for (;; ++i1){ if (cum + ti[i1] >= 512) break; cum += ti[i1]; }
    int bin = i1*4;
    for (;; ++bin){ if (cum + (int)hist[bin] >= 512) break; cum += (int)hist[bin]; }
    sh_misc[1] = bin;
  }
  __syncthreads();
  int threshKey = sh_misc[1];
  #pragma unroll
  for (int j = 0; j < 16; ++j){
    int m = t*16 + j;
    unsigned key = __float_as_uint(parr[m]) >> 20;
    if (key > 2047u) key = 2047u;
    if ((int)key <= threshKey){
      int pos = atomicAdd(&sh_misc[0], 1);
      if (pos < SCAN_CAP){ candV[pos] = parr[m]; candI[pos] = m; }
    }
  }
  __syncthreads();
  int cnt = sh_misc[0];
  if (t >= cnt && t < SCAN_CAP){ candV[t] = INFINITY; candI[t] = 0x7FFFFFFF; }
  __syncthreads();
  for (int ksz = 2; ksz <= SCAN_CAP; ksz <<= 1){
    for (int jj = ksz >> 1; jj > 0; jj >>= 1){
      int ixj = t ^ jj;
      if (ixj > t){
        float v1 = candV[t], v2 = candV[ixj];
        int i1 = candI[t], i2 = candI[ixj];
        bool lt21 = (v2 < v1) || (v2 == v1 && i2 < i1);
        bool lt12 = (v1 < v2) || (v1 == v2 && i1 < i2);
        bool up = ((t & ksz) == 0);
        bool sw = up ? lt21 : lt12;
        if (sw){ candV[t] = v2; candI[t] = i2; candV[ixj] = v1; candI[ixj] = i1; }
      }
      __syncthreads();
    }
  }
  int mem = (t < 512) ? memorize[t] : 0;
  int lp = 0;
  if (t < 512){
    unsigned long long mask = __ballot(mem != 0);
    int lane = t & 63;
    lp = __popcll(mask & ((1ull << lane) - 1ull));
    if (lane == 0) wtot[t >> 6] = __popcll(mask);
  }
  if (t < 512 && mem) atomicMin(&sh_misc[3], __float_as_int(surprise[t]));
  __syncthreads();
  if (t == 0){
    int ksum = 0;
    for (int wv = 0; wv < 8; ++wv) ksum += wtot[wv];
    sh_misc[4] = ksum;
    bool okf = (cnt <= SCAN_CAP) && (ksum <= cnt);
    if (okf && ksum > 0){
      float minw = __int_as_float(sh_misc[3]);
      okf = (minw > candV[ksum - 1]);
    }
    sh_misc[2] = okf ? 1 : 0;
  }
  __syncthreads();
  if (sh_misc[2] == 1){
    if (t < 512){
      int wv = t >> 6, base = 0;
      for (int i = 0; i < wv; ++i) base += wtot[i];
      int slot = -1;
      if (mem){ slot = candI[base + lp]; atomicMax(&lastB[slot], t); }
      slotForB[t] = slot;
    }
  } else {
    for (int b = 0; b < 512; ++b){
      float bv = parr[t*16]; int bi = t*16;
      #pragma unroll
      for (int j = 1; j < 16; ++j){
        float v = parr[t*16 + j];
        if (v < bv){ bv = v; bi = t*16 + j; }
      }
      tv[t] = bv; ti[t] = bi;
      __syncthreads();
      for (int s = 512; s > 0; s >>= 1){
        if (t < s){
          float v2 = tv[t+s]; int i2 = ti[t+s];
          if (v2 < tv[t] || (v2 == tv[t] && i2 < ti[t])){ tv[t] = v2; ti[t] = i2; }
        }
        __syncthreads();
      }
      int slot = ti[0];
      int memb = memorize[b];
      if (t == 0) slotForB[b] = memb ? slot : -1;
      if (memb && t == (slot >> 4)) parr[slot] = surprise[b];
      __syncthreads();
    }
    if (t < 512){ int s = slotForB[t]; if (s >= 0) atomicMax(&lastB[s], t); }
  }
}

// ---------------- fixup written slots (f32 exact) ----------------
__global__ __launch_bounds__(64) void fixup_rows(const int* __restrict__ slotForB, const int* __restrict__ lastB,
                                                 const float* __restrict__ newK, const float* __restrict__ newV,
                                                 const float* __restrict__ Wpk, const float* __restrict__ Wpv,
                                                 const float* __restrict__ bpk, const float* __restrict__ bpv,
                                                 float* __restrict__ kh, float* __restrict__ vh){
  int b = blockIdx.x;
  int slot = slotForB[b];
  if (slot < 0) return;
  if (lastB[slot] != b) return;
  __shared__ float kr[256], vr[256];
  int t = threadIdx.x;
  *(float4*)(kr + t*4) = *(const float4*)(newK + (size_t)b*256 + t*4);
  *(float4*)(vr + t*4) = *(const float4*)(newV + (size_t)b*256 + t*4);
  __syncthreads();
  for (int c = t; c < 264; c += 64){
    float aK = bpk[c], aV = bpv[c];
    for (int k = 0; k < 256; ++k){
      aK += kr[k]*Wpk[(size_t)k*264 + c];
      aV += vr[k]*Wpv[(size_t)k*264 + c];
    }
    kh[(size_t)slot*264 + c] = aK;
    vh[(size_t)slot*264 + c] = aV;
  }
}

__global__ __launch_bounds__(256) void fuse_bias(const float* __restrict__ vin, const float* __restrict__ W,
                                                 const float* __restrict__ addv, float* __restrict__ outv,
                                                 int K, int N, int ldw, int woff){
  int c = blockIdx.x*blockDim.x + threadIdx.x;
  if (c >= N) return;
  float a = addv[c];
  for (int k = 0; k < K; ++k) a += vin[k]*W[(size_t)k*ldw + woff + c];
  outv[c] = a;
}

// ---------------- flash attention partials ----------------
__global__ __launch_bounds__(256) void attn_kernel(
    const float* __restrict__ qh, const float* __restrict__ kh, const float* __restrict__ vh,
    float* __restrict__ pm, float* __restrict__ pl, float* __restrict__ pctx){
  const int h = blockIdx.x, bt = blockIdx.y, ms = blockIdx.z;
  const int b0 = bt*64;
  const int mbase = ms*2048;
  const int t = threadIdx.x;
  __shared__ float qsT[33*68];
  __shared__ float ksT[33*68];
  __shared__ float vsm[64*36];
  __shared__ float PsT[64*68];
  __shared__ float rM[64], rL[64], alf[64];
  __shared__ float red[64*16];

  for (int e = t; e < 2112; e += 256){
    int bl = e/33, d = e - bl*33;
    qsT[d*68 + bl] = qh[(size_t)(b0+bl)*264 + h*33 + d];
  }
  for (int e = t; e < 192; e += 256){ int ml = e/3; vsm[ml*36 + 33 + (e - ml*3)] = 0.f; }
  if (t < 64){ rM[t] = -INFINITY; rL[t] = 0.f; }
  const float scale = 0.17407765595569785f; // 1/sqrt(33)
  const int bq = (t & 15)*4;
  const int mq = (t >> 4)*4;
  const int dq = (t >> 4);
  float ctxreg[16];
  #pragma unroll
  for (int i = 0; i < 16; ++i) ctxreg[i] = 0.f;

  for (int mt = 0; mt < 32; ++mt){
    const int m0 = mbase + mt*64;
    __syncthreads();
    for (int e = t; e < 2112; e += 256){
      int ml = e/33, d = e - ml*33;
      size_t gi = (size_t)(m0+ml)*264 + h*33 + d;
      ksT[d*68 + ml] = kh[gi];
      vsm[ml*36 + d] = vh[gi];
    }
    __syncthreads();
    float s[16];
    #pragma unroll
    for (int i = 0; i < 16; ++i) s[i] = 0.f;
    #pragma unroll
    for (int d = 0; d < 33; ++d){
      float4 qa = *(const float4*)(qsT + d*68 + bq);
      float4 kb = *(const float4*)(ksT + d*68 + mq);
      s[ 0]+=qa.x*kb.x; s[ 1]+=qa.x*kb.y; s[ 2]+=qa.x*kb.z; s[ 3]+=qa.x*kb.w;
      s[ 4]+=qa.y*kb.x; s[ 5]+=qa.y*kb.y; s[ 6]+=qa.y*kb.z; s[ 7]+=qa.y*kb.w;
      s[ 8]+=qa.z*kb.x; s[ 9]+=qa.z*kb.y; s[10]+=qa.z*kb.z; s[11]+=qa.z*kb.w;
      s[12]+=qa.w*kb.x; s[13]+=qa.w*kb.y; s[14]+=qa.w*kb.z; s[15]+=qa.w*kb.w;
    }
    #pragma unroll
    for (int i = 0; i < 16; ++i) s[i] *= scale;
    #pragma unroll
    for (int i = 0; i < 4; ++i){
      float mx = fmaxf(fmaxf(s[i*4+0], s[i*4+1]), fmaxf(s[i*4+2], s[i*4+3]));
      red[(bq+i)*16 + (t >> 4)] = mx;
    }
    __syncthreads();
    if (t < 64){
      float mx = red[t*16];
      #pragma unroll
      for (int i = 1; i < 16; ++i) mx = fmaxf(mx, red[t*16+i]);
      float old = rM[t];
      float nm = fmaxf(old, mx);
      alf[t] = expf(old - nm);
      rM[t] = nm;
    }
    __syncthreads();
    float pv4[4][4];
    #pragma unroll
    for (int i = 0; i < 4; ++i){
      float rsum = 0.f;
      float nm = rM[bq+i];
      #pragma unroll
      for (int j = 0; j < 4; ++j){
        float p = expf(s[i*4+j] - nm);
        pv4[i][j] = p;
        rsum += p;
      }
      red[(bq+i)*16 + (t >> 4)] = rsum;
    }
    // conflict-free float4 column writes into PsT[m][b]
    #pragma unroll
    for (int j = 0; j < 4; ++j){
      *(float4*)(PsT + (mq+j)*68 + bq) = make_float4(pv4[0][j], pv4[1][j], pv4[2][j], pv4[3][j]);
    }
    __syncthreads();
    if (t < 64){
      float sm = 0.f;
      #pragma unroll
      for (int i = 0; i < 16; ++i) sm += red[t*16+i];
      rL[t] = rL[t]*alf[t] + sm;
    }
    if (dq < 9){
      float acc2[16];
      #pragma unroll
      for (int i = 0; i < 16; ++i) acc2[i] = 0.f;
      #pragma unroll
      for (int m = 0; m < 64; ++m){
        float4 pa = *(const float4*)(PsT + m*68 + bq);
        float4 vb = *(const float4*)(vsm + m*36 + dq*4);
        acc2[ 0]+=pa.x*vb.x; acc2[ 1]+=pa.x*vb.y; acc2[ 2]+=pa.x*vb.z; acc2[ 3]+=pa.x*vb.w;
        acc2[ 4]+=pa.y*vb.x; acc2[ 5]+=pa.y*vb.y; acc2[ 6]+=pa.y*vb.z; acc2[ 7]+=pa.y*vb.w;
        acc2[ 8]+=pa.z*vb.x; acc2[ 9]+=pa.z*vb.y; acc2[10]+=pa.z*vb.z; acc2[11]+=pa.z*vb.w;
        acc2[12]+=pa.w*vb.x; acc2[13]+=pa.w*vb.y; acc2[14]+=pa.w*vb.z; acc2[15]+=pa.w*vb.w;
      }
      #pragma unroll
      for (int i = 0; i < 4; ++i){
        float al = alf[bq+i];
        #pragma unroll
        for (int j = 0; j < 4; ++j){
          ctxreg[i*4+j] = ctxreg[i*4+j]*al + acc2[i*4+j];
        }
      }
    }
  }
  __syncthreads();
  int g = (h*8 + bt)*8 + ms;
  if (t < 64){ pm[(size_t)g*64 + t] = rM[t]; pl[(size_t)g*64 + t] = rL[t]; }
  if (dq < 9){
    #pragma unroll
    for (int i = 0; i < 4; ++i){
      #pragma unroll
      for (int j = 0; j < 4; ++j){
        int d = dq*4 + j;
        if (d < 33) pctx[((size_t)g*64 + (bq+i))*33 + d] = ctxreg[i*4+j];
      }
    }
  }
}

__global__ __launch_bounds__(256) void combine_kernel(const float* __restrict__ pm, const float* __restrict__ pl,
                                                      const float* __restrict__ pctx, float* __restrict__ ctxf){
  int idx = blockIdx.x*256 + threadIdx.x;
  if (idx >= 512*264) return;
  int b = idx / 264, c = idx - b*264;
  int h = c / 33, d = c - h*33;
  int bt = b >> 6, bl = b & 63;
  int g0 = (h*8 + bt)*8;
  float gm = -INFINITY;
  for (int ms = 0; ms < 8; ++ms) gm = fmaxf(gm, pm[(g0+ms)*64 + bl]);
  float L = 0.f, cv = 0.f;
  for (int ms = 0; ms < 8; ++ms){
    int gg = (g0+ms)*64 + bl;
    float w = expf(pm[gg] - gm);
    L += pl[gg]*w;
    cv += pctx[(size_t)gg*33 + d]*w;
  }
  ctxf[idx] = cv / L;
}

// ---------------- host ----------------
extern "C" void kernel_launch(void* const* d_in, const int* in_sizes, int n_in,
                              void* d_out, int out_size, void* d_ws, size_t ws_size,
                              hipStream_t stream){
  (void)in_sizes; (void)n_in; (void)out_size; (void)ws_size;
  const float* features     = (const float*)d_in[0];
  const float* gradients    = (const float*)d_in[1];
  const float* mem_keys     = (const float*)d_in[2];
  const float* mem_values   = (const float*)d_in[3];
  const float* mem_ages     = (const float*)d_in[4];
  const float* mem_surprise = (const float*)d_in[5];
  const float* Wk   = (const float*)d_in[6];
  const float* bk   = (const float*)d_in[7];
  const float* Wv   = (const float*)d_in[8];
  const float* bv   = (const float*)d_in[9];
  const float* Wp   = (const float*)d_in[10];
  const float* bp   = (const float*)d_in[11];
  const float* Win  = (const float*)d_in[12];
  const float* b_in = (const float*)d_in[13];
  const float* Wout = (const float*)d_in[14];
  const float* bout = (const float*)d_in[15];
  const float* Wo   = (const float*)d_in[16];
  const float* bo   = (const float*)d_in[17];
  float* out = (float*)d_out;

  float* w = (float*)d_ws;
  size_t off = 0;
  auto alloc = [&](size_t n)->float*{ float* p = w + off; off += (n + 63) & ~(size_t)63; return p; };
  float*    k2       = alloc(16384);
  unsigned* minD2    = (unsigned*)alloc(512);
  float*    f2       = alloc(512);
  float*    gn       = alloc(512);
  float*    surprise = alloc(512);
  int*      memorize = (int*)alloc(512);
  int*      slotForB = (int*)alloc(512);
  int*      lastB    = (int*)alloc(16384);
  float*    parr     = alloc(16384);
  float*    newK     = alloc((size_t)512*256);
  float*    newV     = alloc((size_t)512*256);
  float*    qh       = alloc((size_t)512*264);
  float*    kh       = alloc((size_t)16384*264);
  float*    vh       = alloc((size_t)16384*264);
  float*    Wpk      = alloc((size_t)256*264);
  float*    Wpv      = alloc((size_t)256*264);
  float*    Wpq      = alloc((size_t)256*264);
  float*    Wco      = alloc((size_t)264*256);
  float*    bpk      = alloc(264);
  float*    bpv      = alloc(264);
  float*    bpq      = alloc(264);
  float*    bco      = alloc(256);
  float*    ctxf     = alloc((size_t)512*264);
  float*    pm       = alloc((size_t)512*64);
  float*    pl       = alloc((size_t)512*64);
  float*    pctx     = alloc((size_t)512*64*33);
  ushort_t* WtkH     = (ushort_t*)alloc((size_t)320*256/2);
  ushort_t* WtkL     = (ushort_t*)alloc((size_t)320*256/2);
  ushort_t* WtvH     = (ushort_t*)alloc((size_t)320*256/2);
  ushort_t* WtvL     = (ushort_t*)alloc((size_t)320*256/2);

  init_mind2<<<2, 256, 0, stream>>>(minD2, 512);
  prep_k2<<<4096, 256, 0, stream>>>(mem_keys, k2, 16384);
  prep_feat<<<128, 256, 0, stream>>>(features, gradients, f2, gn, 512);

  // fused projection weights: Wpx = Wp @ Win-slice ; Wco = Wout @ Wo
  gemm_bias<<<dim3(4,5), 256, 0, stream>>>(Wp, Win, nullptr, Wpk, 256, 264, 264, 792, 264);
  gemm_bias<<<dim3(4,5), 256, 0, stream>>>(Wp, Win, nullptr, Wpv, 256, 264, 264, 792, 528);
  gemm_bias<<<dim3(4,5), 256, 0, stream>>>(Wp, Win, nullptr, Wpq, 256, 264, 264, 792, 0);
  gemm_bias<<<dim3(5,4), 256, 0, stream>>>(Wout, Wo, nullptr, Wco, 264, 264, 256, 256, 0);
  fuse_bias<<<2, 256, 0, stream>>>(bp, Win, b_in + 264, bpk, 264, 264, 792, 264);
  fuse_bias<<<2, 256, 0, stream>>>(bp, Win, b_in + 528, bpv, 264, 264, 792, 528);
  fuse_bias<<<2, 256, 0, stream>>>(bp, Win, b_in,       bpq, 264, 264, 792, 0);
  fuse_bias<<<1, 256, 0, stream>>>(bout, Wo, bo,        bco, 264, 256, 256, 0);

  // transpose + split fused weights for MFMA GEMMs
  tsplit_w<<<320, 256, 0, stream>>>(Wpk, WtkH, WtkL, 264, 320);
  tsplit_w<<<320, 256, 0, stream>>>(Wpv, WtvH, WtvL, 264, 320);

  // small f32 GEMMs
  gemm_bias<<<dim3(8,4), 256, 0, stream>>>(features, Wk, bk, newK, 512, 256, 256, 256, 0);
  gemm_bias<<<dim3(8,4), 256, 0, stream>>>(features, Wv, bv, newV, 512, 256, 256, 256, 0);
  gemm_bias<<<dim3(8,5), 256, 0, stream>>>(features, Wpq, bpq, qh, 512, 256, 264, 264, 0);

  // big projections via MFMA split-bf16
  gemm_mfma_split<<<dim3(128,5), 256, 0, stream>>>(mem_keys,   WtkH, WtkL, bpk, kh, 264);
  gemm_mfma_split<<<dim3(128,5), 256, 0, stream>>>(mem_values, WtvH, WtvL, bpv, vh, 264);

  // surprise via MFMA (plain bf16, decision-safe)
  surprise_mfma<<<dim3(128,8), 256, 0, stream>>>(mem_keys, features, k2, minD2);
  finalize_surprise<<<2, 256, 0, stream>>>(minD2, f2, gn, surprise, memorize, 512);
  scan_kernel<<<1, 1024, 0, stream>>>(mem_surprise, mem_ages, surprise, memorize, parr, slotForB, lastB);
  fixup_rows<<<512, 64, 0, stream>>>(slotForB, lastB, newK, newV, Wpk, Wpv, bpk, bpv, kh, vh);

  // attention + output
  attn_kernel<<<dim3(8,8,8), 256, 0, stream>>>(qh, kh, vh, pm, pl, pctx);
  combine_kernel<<<528, 256, 0, stream>>>(pm, pl, pctx, ctxf);
  gemm_bias<<<dim3(8,4), 256, 0, stream>>>(ctxf, Wco, bco, out, 512, 264, 256, 256, 0);
}

// Round 3
// 517.462 us; speedup vs baseline: 2.1613x; 1.9656x over previous
//
#include <hip/hip_runtime.h>
#include <math.h>

typedef unsigned short ushort_t;
typedef float v4f __attribute__((ext_vector_type(4)));
typedef short v8s __attribute__((ext_vector_type(8)));

// ---------------- helpers ----------------
__device__ __forceinline__ unsigned fenc(float f){
  unsigned b = __float_as_uint(f);
  return (b & 0x80000000u) ? ~b : (b | 0x80000000u);
}
__device__ __forceinline__ float fdec(unsigned u){
  unsigned b = (u & 0x80000000u) ? (u ^ 0x80000000u) : ~u;
  return __uint_as_float(b);
}
__device__ __forceinline__ ushort_t bf16_rne(float x){
  unsigned u = __float_as_uint(x);
  unsigned r = u + 0x7FFFu + ((u >> 16) & 1u);
  return (ushort_t)(r >> 16);
}
__device__ __forceinline__ void split2(float x, ushort_t& h, ushort_t& l){
  unsigned u = __float_as_uint(x);
  unsigned r = u + 0x7FFFu + ((u >> 16) & 1u);
  h = (ushort_t)(r >> 16);
  float hf = __uint_as_float(r & 0xFFFF0000u);
  l = bf16_rne(x - hf);
}
__device__ __forceinline__ float bf2f(ushort_t x){ return __uint_as_float(((unsigned)x) << 16); }

// ---------------- prep ----------------
__global__ __launch_bounds__(256) void prep_k2(const float* __restrict__ mk, float* __restrict__ k2, int M){
  int wid = threadIdx.x >> 6, lane = threadIdx.x & 63;
  int row = blockIdx.x*4 + wid;
  if (row >= M) return;
  float4 v = *(const float4*)(mk + (size_t)row*256 + lane*4);
  float s = v.x*v.x + v.y*v.y + v.z*v.z + v.w*v.w;
  for (int off = 32; off > 0; off >>= 1) s += __shfl_down(s, off, 64);
  if (lane == 0) k2[row] = s;
}

// f2, gn, and minD2 init
__global__ __launch_bounds__(256) void prep_feat(const float* __restrict__ F, const float* __restrict__ G,
                                                 float* __restrict__ f2, float* __restrict__ gn,
                                                 unsigned* __restrict__ minD2, int B){
  int wid = threadIdx.x >> 6, lane = threadIdx.x & 63;
  int row = blockIdx.x*4 + wid;
  if (row >= B) return;
  float4 a = *(const float4*)(F + (size_t)row*256 + lane*4);
  float4 g = *(const float4*)(G + (size_t)row*256 + lane*4);
  float s = a.x*a.x + a.y*a.y + a.z*a.z + a.w*a.w;
  float t = g.x*g.x + g.y*g.y + g.z*g.z + g.w*g.w;
  for (int off = 32; off > 0; off >>= 1){ s += __shfl_down(s, off, 64); t += __shfl_down(t, off, 64); }
  if (lane == 0){ f2[row] = s; gn[row] = sqrtf(t); minD2[row] = 0xFFFFFFFFu; }
}

// zero the pad rows (d=33..47 per head) of the transposed split V
__global__ __launch_bounds__(256) void zero_pads(ushort_t* __restrict__ VtH, ushort_t* __restrict__ VtL){
  const int PER4 = 8*15*16384/4;  // 491520 ushort4 units per array
  int idx = blockIdx.x*256 + threadIdx.x;
  if (idx >= 2*PER4) return;
  ushort_t* base = (idx < PER4) ? VtH : VtL;
  int i = (idx < PER4) ? idx : idx - PER4;
  int s = i*4;
  int hh = s / (15*16384);
  int r2 = s - hh*(15*16384);
  int row = 33 + (r2 >> 14);
  int col = r2 & 16383;
  ushort4 z; z.x = 0; z.y = 0; z.z = 0; z.w = 0;
  *(ushort4*)(base + (size_t)(hh*48 + row)*16384 + col) = z;
}

// ---------------- generic small f32 GEMM ----------------
__global__ __launch_bounds__(256) void gemm_bias(const float* __restrict__ A, const float* __restrict__ W,
                                                 const float* __restrict__ bias, float* __restrict__ C,
                                                 int M, int K, int N, int ldw, int woff){
  __shared__ float As[32*68];
  __shared__ float Ws[32*68];
  int m0 = blockIdx.x*64, c0 = blockIdx.y*64;
  int t = threadIdx.x;
  int mq = (t & 15)*4, cq = (t >> 4)*4;
  float acc[16];
  #pragma unroll
  for (int i = 0; i < 16; ++i) acc[i] = 0.f;
  for (int k0 = 0; k0 < K; k0 += 32){
    #pragma unroll
    for (int i = 0; i < 2; ++i){
      int idx = t + 256*i;
      int row = idx >> 3, kk = (idx & 7)*4;
      int gm = m0 + row, gk = k0 + kk;
      float x=0.f, y=0.f, z=0.f, w=0.f;
      if (gm < M){
        const float* ap = A + (size_t)gm*K + gk;
        if (gk + 3 < K){ float4 v = *(const float4*)ap; x=v.x; y=v.y; z=v.z; w=v.w; }
        else {
          if (gk   < K) x = ap[0];
          if (gk+1 < K) y = ap[1];
          if (gk+2 < K) z = ap[2];
          if (gk+3 < K) w = ap[3];
        }
      }
      As[(kk+0)*68+row]=x; As[(kk+1)*68+row]=y; As[(kk+2)*68+row]=z; As[(kk+3)*68+row]=w;
    }
    #pragma unroll
    for (int i = 0; i < 2; ++i){
      int idx = t + 256*i;
      int kk = idx >> 4, cc = (idx & 15)*4;
      int gk = k0 + kk, gc = c0 + cc;
      float4 v = make_float4(0.f,0.f,0.f,0.f);
      if (gk < K){
        const float* wp = W + (size_t)gk*ldw + woff + gc;
        if (gc + 3 < N) v = *(const float4*)wp;
        else {
          if (gc   < N) v.x = wp[0];
          if (gc+1 < N) v.y = wp[1];
          if (gc+2 < N) v.z = wp[2];
          if (gc+3 < N) v.w = wp[3];
        }
      }
      *(float4*)(Ws + kk*68 + cc) = v;
    }
    __syncthreads();
    #pragma unroll
    for (int j = 0; j < 32; ++j){
      float4 a = *(const float4*)(As + j*68 + mq);
      float4 w = *(const float4*)(Ws + j*68 + cq);
      acc[ 0]+=a.x*w.x; acc[ 1]+=a.x*w.y; acc[ 2]+=a.x*w.z; acc[ 3]+=a.x*w.w;
      acc[ 4]+=a.y*w.x; acc[ 5]+=a.y*w.y; acc[ 6]+=a.y*w.z; acc[ 7]+=a.y*w.w;
      acc[ 8]+=a.z*w.x; acc[ 9]+=a.z*w.y; acc[10]+=a.z*w.z; acc[11]+=a.z*w.w;
      acc[12]+=a.w*w.x; acc[13]+=a.w*w.y; acc[14]+=a.w*w.z; acc[15]+=a.w*w.w;
    }
    __syncthreads();
  }
  #pragma unroll
  for (int i = 0; i < 4; ++i){
    int gm = m0 + mq + i;
    if (gm >= M) continue;
    #pragma unroll
    for (int j = 0; j < 4; ++j){
      int gc = c0 + cq + j;
      if (gc >= N) continue;
      C[(size_t)gm*N + gc] = acc[i*4+j] + (bias ? bias[gc] : 0.f);
    }
  }
}

// ---------------- batched weight-prep GEMM with transpose-split epilogue ----------------
// z=0: Wpk = Wp@Win[:,264:528]  -> Wtk split + Wpk f32
// z=1: Wpv = Wp@Win[:,528:792]  -> Wtv split + Wpv f32
// z=2: Wpq = Wp@Win[:,0:264]    -> Wtq split only
// z=3: Wco = Wout@Wo            -> f32 only
__global__ __launch_bounds__(256) void wprep_gemm(
    const float* __restrict__ Wp, const float* __restrict__ Win,
    const float* __restrict__ Wout, const float* __restrict__ Wo,
    ushort_t* __restrict__ WtkH, ushort_t* __restrict__ WtkL,
    ushort_t* __restrict__ WtvH, ushort_t* __restrict__ WtvL,
    ushort_t* __restrict__ WtqH, ushort_t* __restrict__ WtqL,
    float* __restrict__ Wpk, float* __restrict__ Wpv, float* __restrict__ Wco){
  __shared__ float As[32*68];
  __shared__ float Ws[32*68];
  int z = blockIdx.z;
  const float* A = (z < 3) ? Wp : Wout;
  const float* W = (z < 3) ? Win : Wo;
  const int M = (z < 3) ? 256 : 264;
  const int K = 264;
  const int N = (z < 3) ? 264 : 256;
  const int ldw = (z < 3) ? 792 : 256;
  const int woff = (z == 0) ? 264 : (z == 1) ? 528 : 0;
  int m0 = blockIdx.x*64, c0 = blockIdx.y*64;
  int t = threadIdx.x;
  int mq = (t & 15)*4, cq = (t >> 4)*4;
  float acc[16];
  #pragma unroll
  for (int i = 0; i < 16; ++i) acc[i] = 0.f;
  for (int k0 = 0; k0 < K; k0 += 32){
    #pragma unroll
    for (int i = 0; i < 2; ++i){
      int idx = t + 256*i;
      int row = idx >> 3, kk = (idx & 7)*4;
      int gm = m0 + row, gk = k0 + kk;
      float x=0.f, y=0.f, z2=0.f, w=0.f;
      if (gm < M){
        const float* ap = A + (size_t)gm*K + gk;
        if (gk + 3 < K){ float4 v = *(const float4*)ap; x=v.x; y=v.y; z2=v.z; w=v.w; }
        else {
          if (gk   < K) x = ap[0];
          if (gk+1 < K) y = ap[1];
          if (gk+2 < K) z2 = ap[2];
          if (gk+3 < K) w = ap[3];
        }
      }
      As[(kk+0)*68+row]=x; As[(kk+1)*68+row]=y; As[(kk+2)*68+row]=z2; As[(kk+3)*68+row]=w;
    }
    #pragma unroll
    for (int i = 0; i < 2; ++i){
      int idx = t + 256*i;
      int kk = idx >> 4, cc = (idx & 15)*4;
      int gk = k0 + kk, gc = c0 + cc;
      float4 v = make_float4(0.f,0.f,0.f,0.f);
      if (gk < K){
        const float* wp = W + (size_t)gk*ldw + woff + gc;
        if (gc + 3 < N) v = *(const float4*)wp;
        else {
          if (gc   < N) v.x = wp[0];
          if (gc+1 < N) v.y = wp[1];
          if (gc+2 < N) v.z = wp[2];
          if (gc+3 < N) v.w = wp[3];
        }
      }
      *(float4*)(Ws + kk*68 + cc) = v;
    }
    __syncthreads();
    #pragma unroll
    for (int j = 0; j < 32; ++j){
      float4 a = *(const float4*)(As + j*68 + mq);
      float4 w = *(const float4*)(Ws + j*68 + cq);
      acc[ 0]+=a.x*w.x; acc[ 1]+=a.x*w.y; acc[ 2]+=a.x*w.z; acc[ 3]+=a.x*w.w;
      acc[ 4]+=a.y*w.x; acc[ 5]+=a.y*w.y; acc[ 6]+=a.y*w.z; acc[ 7]+=a.y*w.w;
      acc[ 8]+=a.z*w.x; acc[ 9]+=a.z*w.y; acc[10]+=a.z*w.z; acc[11]+=a.z*w.w;
      acc[12]+=a.w*w.x; acc[13]+=a.w*w.y; acc[14]+=a.w*w.z; acc[15]+=a.w*w.w;
    }
    __syncthreads();
  }
  if (z < 3){
    ushort_t* WH = (z==0) ? WtkH : (z==1) ? WtvH : WtqH;
    ushort_t* WL = (z==0) ? WtkL : (z==1) ? WtvL : WtqL;
    float* Wf = (z==0) ? Wpk : (z==1) ? Wpv : nullptr;
    #pragma unroll
    for (int i = 0; i < 4; ++i){
      int gm = m0 + mq + i;
      if (gm >= 256) continue;
      #pragma unroll
      for (int j = 0; j < 4; ++j){
        int gc = c0 + cq + j;       // < 320 by grid
        float r = acc[i*4+j];       // 0 for gc >= 264 via W-guard
        ushort_t hh, ll; split2(r, hh, ll);
        WH[(size_t)gc*256 + gm] = hh;
        WL[(size_t)gc*256 + gm] = ll;
        if (Wf && gc < 264) Wf[(size_t)gm*264 + gc] = r;
      }
    }
  } else {
    #pragma unroll
    for (int i = 0; i < 4; ++i){
      int gm = m0 + mq + i;
      if (gm >= 264) continue;
      #pragma unroll
      for (int j = 0; j < 4; ++j){
        int gc = c0 + cq + j;
        if (gc < 256) Wco[(size_t)gm*256 + gc] = acc[i*4+j];
      }
    }
  }
}

// batched fused-bias precompute
__global__ __launch_bounds__(256) void wbias_batch(
    const float* __restrict__ bp, const float* __restrict__ Win, const float* __restrict__ b_in,
    const float* __restrict__ bout, const float* __restrict__ Wo, const float* __restrict__ bo,
    float* __restrict__ bpk, float* __restrict__ bpv, float* __restrict__ bpq, float* __restrict__ bco){
  int z = blockIdx.y;
  int c = blockIdx.x*256 + threadIdx.x;
  if (z < 3){
    if (c >= 264) return;
    int off = (z==0) ? 264 : (z==1) ? 528 : 0;
    float a = b_in[off + c];
    for (int k = 0; k < 264; ++k) a += bp[k]*Win[(size_t)k*792 + off + c];
    ((z==0) ? bpk : (z==1) ? bpv : bpq)[c] = a;
  } else {
    if (c >= 256) return;
    float a = bo[c];
    for (int k = 0; k < 264; ++k) a += bout[k]*Wo[(size_t)k*256 + c];
    bco[c] = a;
  }
}

// ---------------- MFMA split-bf16 GEMM: A[M,256] (f32) @ Wt^T + bias ----------------
// mode 0: f32 C0[m*264 + n]                       (qh)
// mode 1: split CH/CL[m*320 + (n/33)*40 + n%33]   (kh, head-padded)
// mode 2: split CH/CL[((n/33)*48 + n%33)*16384+m] (Vt, transposed)
__global__ __launch_bounds__(256) void gemm_mfma_split(const float* __restrict__ A,
                                                       const ushort_t* __restrict__ WtH, const ushort_t* __restrict__ WtL,
                                                       const float* __restrict__ bias, float* __restrict__ C0,
                                                       ushort_t* __restrict__ CH, ushort_t* __restrict__ CL,
                                                       int N, int mode){
  __shared__ ushort_t AsH[128*40];
  __shared__ ushort_t AsL[128*40];
  __shared__ ushort_t BsH[64*40];
  __shared__ ushort_t BsL[64*40];
  int t = threadIdx.x;
  int m0 = blockIdx.x*128, n0 = blockIdx.y*64;
  int lane = t & 63, w = t >> 6;
  int wm = (w & 1)*64, wn = (w >> 1)*32;
  int l15 = lane & 15, q = lane >> 4;
  v4f acc[4][2];
  #pragma unroll
  for (int i = 0; i < 4; ++i)
    #pragma unroll
    for (int j = 0; j < 2; ++j) acc[i][j] = (v4f){0.f,0.f,0.f,0.f};

  for (int k0 = 0; k0 < 256; k0 += 32){
    #pragma unroll
    for (int rdx = 0; rdx < 4; ++rdx){
      int idx = t + 256*rdx;
      int row = idx >> 3, kq = idx & 7;
      float4 v = *(const float4*)(A + (size_t)(m0+row)*256 + k0 + kq*4);
      ushort_t h0,h1,h2,h3,l0,l1,l2,l3;
      split2(v.x,h0,l0); split2(v.y,h1,l1); split2(v.z,h2,l2); split2(v.w,h3,l3);
      *(uint2*)(AsH + row*40 + kq*4) = make_uint2((unsigned)h0 | ((unsigned)h1<<16), (unsigned)h2 | ((unsigned)h3<<16));
      *(uint2*)(AsL + row*40 + kq*4) = make_uint2((unsigned)l0 | ((unsigned)l1<<16), (unsigned)l2 | ((unsigned)l3<<16));
    }
    #pragma unroll
    for (int rdx = 0; rdx < 2; ++rdx){
      int idx = t + 256*rdx;
      int row = idx >> 3, kq = idx & 7;
      *(uint2*)(BsH + row*40 + kq*4) = *(const uint2*)(WtH + (size_t)(n0+row)*256 + k0 + kq*4);
      *(uint2*)(BsL + row*40 + kq*4) = *(const uint2*)(WtL + (size_t)(n0+row)*256 + k0 + kq*4);
    }
    __syncthreads();
    v8s aH[4], aL[4], bH[2], bL[2];
    #pragma unroll
    for (int im = 0; im < 4; ++im){
      aH[im] = *(const v8s*)(AsH + (wm + im*16 + l15)*40 + q*8);
      aL[im] = *(const v8s*)(AsL + (wm + im*16 + l15)*40 + q*8);
    }
    #pragma unroll
    for (int jn = 0; jn < 2; ++jn){
      bH[jn] = *(const v8s*)(BsH + (wn + jn*16 + l15)*40 + q*8);
      bL[jn] = *(const v8s*)(BsL + (wn + jn*16 + l15)*40 + q*8);
    }
    #pragma unroll
    for (int im = 0; im < 4; ++im)
      #pragma unroll
      for (int jn = 0; jn < 2; ++jn){
        acc[im][jn] = __builtin_amdgcn_mfma_f32_16x16x32_bf16(aH[im], bH[jn], acc[im][jn], 0, 0, 0);
        acc[im][jn] = __builtin_amdgcn_mfma_f32_16x16x32_bf16(aH[im], bL[jn], acc[im][jn], 0, 0, 0);
        acc[im][jn] = __builtin_amdgcn_mfma_f32_16x16x32_bf16(aL[im], bH[jn], acc[im][jn], 0, 0, 0);
      }
    __syncthreads();
  }
  #pragma unroll
  for (int im = 0; im < 4; ++im){
    #pragma unroll
    for (int jn = 0; jn < 2; ++jn){
      int n = n0 + wn + jn*16 + l15;
      if (n >= N) continue;
      float bv = bias[n];
      int mb = m0 + wm + im*16 + q*4;
      if (mode == 0){
        #pragma unroll
        for (int r = 0; r < 4; ++r) C0[(size_t)(mb+r)*264 + n] = acc[im][jn][r] + bv;
      } else if (mode == 1){
        int hh = n/33, dd = n - hh*33;
        int col = hh*40 + dd;
        #pragma unroll
        for (int r = 0; r < 4; ++r){
          ushort_t sh, sl; split2(acc[im][jn][r] + bv, sh, sl);
          CH[(size_t)(mb+r)*320 + col] = sh;
          CL[(size_t)(mb+r)*320 + col] = sl;
        }
      } else {
        int hh = n/33, dd = n - hh*33;
        size_t rowb = (size_t)(hh*48 + dd)*16384 + mb;
        ushort4 hv, lv;
        split2(acc[im][jn][0] + bv, hv.x, lv.x);
        split2(acc[im][jn][1] + bv, hv.y, lv.y);
        split2(acc[im][jn][2] + bv, hv.z, lv.z);
        split2(acc[im][jn][3] + bv, hv.w, lv.w);
        *(ushort4*)(CH + rowb) = hv;
        *(ushort4*)(CL + rowb) = lv;
      }
    }
  }
}

// ---------------- MFMA surprise (plain bf16, decision-safe) ----------------
__global__ __launch_bounds__(256) void surprise_mfma(const float* __restrict__ MK, const float* __restrict__ F,
                                                     const float* __restrict__ k2, unsigned* __restrict__ minD2){
  __shared__ ushort_t AsH[128*40];
  __shared__ ushort_t BsH[64*40];
  __shared__ unsigned sminU[64];
  int t = threadIdx.x;
  int m0 = blockIdx.x*128, b0 = blockIdx.y*64;
  int lane = t & 63, w = t >> 6;
  int wm = (w & 1)*64, wn = (w >> 1)*32;
  int l15 = lane & 15, q = lane >> 4;
  if (t < 64) sminU[t] = 0xFFFFFFFFu;
  v4f acc[4][2];
  #pragma unroll
  for (int i = 0; i < 4; ++i)
    #pragma unroll
    for (int j = 0; j < 2; ++j) acc[i][j] = (v4f){0.f,0.f,0.f,0.f};

  for (int k0 = 0; k0 < 256; k0 += 32){
    #pragma unroll
    for (int rdx = 0; rdx < 4; ++rdx){
      int idx = t + 256*rdx;
      int row = idx >> 3, kq = idx & 7;
      float4 v = *(const float4*)(MK + (size_t)(m0+row)*256 + k0 + kq*4);
      unsigned h0=bf16_rne(v.x), h1=bf16_rne(v.y), h2=bf16_rne(v.z), h3=bf16_rne(v.w);
      *(uint2*)(AsH + row*40 + kq*4) = make_uint2(h0 | (h1<<16), h2 | (h3<<16));
    }
    #pragma unroll
    for (int rdx = 0; rdx < 2; ++rdx){
      int idx = t + 256*rdx;
      int row = idx >> 3, kq = idx & 7;
      float4 v = *(const float4*)(F + (size_t)(b0+row)*256 + k0 + kq*4);
      unsigned h0=bf16_rne(v.x), h1=bf16_rne(v.y), h2=bf16_rne(v.z), h3=bf16_rne(v.w);
      *(uint2*)(BsH + row*40 + kq*4) = make_uint2(h0 | (h1<<16), h2 | (h3<<16));
    }
    __syncthreads();
    v8s aH[4], bH[2];
    #pragma unroll
    for (int im = 0; im < 4; ++im) aH[im] = *(const v8s*)(AsH + (wm + im*16 + l15)*40 + q*8);
    #pragma unroll
    for (int jn = 0; jn < 2; ++jn) bH[jn] = *(const v8s*)(BsH + (wn + jn*16 + l15)*40 + q*8);
    #pragma unroll
    for (int im = 0; im < 4; ++im)
      #pragma unroll
      for (int jn = 0; jn < 2; ++jn)
        acc[im][jn] = __builtin_amdgcn_mfma_f32_16x16x32_bf16(aH[im], bH[jn], acc[im][jn], 0, 0, 0);
    __syncthreads();
  }
  float kk[4][4];
  #pragma unroll
  for (int im = 0; im < 4; ++im)
    #pragma unroll
    for (int r = 0; r < 4; ++r) kk[im][r] = k2[m0 + wm + im*16 + q*4 + r];
  #pragma unroll
  for (int jn = 0; jn < 2; ++jn){
    float mv = INFINITY;
    #pragma unroll
    for (int im = 0; im < 4; ++im)
      #pragma unroll
      for (int r = 0; r < 4; ++r)
        mv = fminf(mv, kk[im][r] - 2.f*acc[im][jn][r]);
    mv = fminf(mv, __shfl_xor(mv, 16, 64));
    mv = fminf(mv, __shfl_xor(mv, 32, 64));
    if (q == 0) atomicMin(&sminU[wn + jn*16 + l15], fenc(mv));
  }
  __syncthreads();
  if (t < 64) atomicMin(&minD2[b0 + t], sminU[t]);
}

// ---------------- eviction scan (finalize folded; fast path + exact fallback) ----------------
#define SCAN_CAP 1024
__global__ __launch_bounds__(1024) void scan_kernel(
    const float* __restrict__ mem_surprise, const float* __restrict__ mem_ages,
    const unsigned* __restrict__ minD2, const float* __restrict__ f2, const float* __restrict__ gn,
    float* __restrict__ parr, int* __restrict__ slotForB, int* __restrict__ lastB){
  __shared__ unsigned hist[2048];
  __shared__ float candV[SCAN_CAP];
  __shared__ int   candI[SCAN_CAP];
  __shared__ float tv[1024];
  __shared__ int   ti[1024];
  __shared__ float ssur[512];
  __shared__ int   smemz[512];
  __shared__ int   wtot[16];
  __shared__ int   sh_misc[8];
  int t = threadIdx.x;

  int mem = 0;
  if (t < 512){
    float d2 = fdec(minD2[t]) + f2[t];
    float s = gn[t]*sqrtf(fmaxf(d2, 0.f));
    ssur[t] = s;
    mem = (s > 0.1f) ? 1 : 0;
    smemz[t] = mem;
  }

  const float LN095 = -0.05129329438755058f;
  #pragma unroll
  for (int j = 0; j < 16; ++j){
    int m = t*16 + j;
    float p = mem_surprise[m] * __expf(mem_ages[m] * LN095);
    parr[m] = p;
    lastB[m] = -1;
  }
  hist[t] = 0u; hist[t + 1024] = 0u;
  if (t < 8) sh_misc[t] = (t == 3) ? 0x7F800000 : 0;
  __syncthreads();

  #pragma unroll
  for (int j = 0; j < 16; ++j){
    int m = t*16 + j;
    unsigned key = __float_as_uint(parr[m]) >> 20;
    if (key > 2047u) key = 2047u;
    atomicAdd(&hist[key], 1u);
  }
  __syncthreads();
  if (t < 512){ ti[t] = (int)(hist[4*t] + hist[4*t+1] + hist[4*t+2] + hist[4*t+3]); }
  __syncthreads();
  if (t < 32){ int s = 0; for (int i = 0; i < 16; ++i) s += ti[16*t + i]; ti[512 + t] = s; }
  __syncthreads();
  if (t == 0){
    int cum = 0, i2 = 0;
    for (; i2 < 32; ++i2){ if (cum + ti[512+i2] >= 512) break; cum += ti[512+i2]; }
    int i1 = i2*16;
    for (;; ++i1){ if (cum + ti[i1] >= 512) break; cum += ti[i1]; }
    int bin = i1*4;
    for (;; ++bin){ if (cum + (int)hist[bin] >= 512) break; cum += (int)hist[bin]; }
    sh_misc[1] = bin;
  }
  __syncthreads();
  int threshKey = sh_misc[1];
  #pragma unroll
  for (int j = 0; j < 16; ++j){
    int m = t*16 + j;
    unsigned key = __float_as_uint(parr[m]) >> 20;
    if (key > 2047u) key = 2047u;
    if ((int)key <= threshKey){
      int pos = atomicAdd(&sh_misc[0], 1);
      if (pos < SCAN_CAP){ candV[pos] = parr[m]; candI[pos] = m; }
    }
  }
  __syncthreads();
  int cnt = sh_misc[0];
  if (t >= cnt && t < SCAN_CAP){ candV[t] = INFINITY; candI[t] = 0x7FFFFFFF; }
  __syncthreads();
  for (int ksz = 2; ksz <= SCAN_CAP; ksz <<= 1){
    for (int jj = ksz >> 1; jj > 0; jj >>= 1){
      int ixj = t ^ jj;
      if (ixj > t){
        float v1 = candV[t], v2 = candV[ixj];
        int i1 = candI[t], i2 = candI[ixj];
        bool lt21 = (v2 < v1) || (v2 == v1 && i2 < i1);
        bool lt12 = (v1 < v2) || (v1 == v2 && i1 < i2);
        bool up = ((t & ksz) == 0);
        bool sw = up ? lt21 : lt12;
        if (sw){ candV[t] = v2; candI[t] = i2; candV[ixj] = v1; candI[ixj] = i1; }
      }
      __syncthreads();
    }
  }
  int lp = 0;
  if (t < 512){
    unsigned long long mask = __ballot(mem != 0);
    int lane = t & 63;
    lp = __popcll(mask & ((1ull << lane) - 1ull));
    if (lane == 0) wtot[t >> 6] = __popcll(mask);
  }
  if (t < 512 && mem) atomicMin(&sh_misc[3], __float_as_int(ssur[t]));
  __syncthreads();
  if (t == 0){
    int ksum = 0;
    for (int wv = 0; wv < 8; ++wv) ksum += wtot[wv];
    sh_misc[4] = ksum;
    bool okf = (cnt <= SCAN_CAP) && (ksum <= cnt);
    if (okf && ksum > 0){
      float minw = __int_as_float(sh_misc[3]);
      okf = (minw > candV[ksum - 1]);
    }
    sh_misc[2] = okf ? 1 : 0;
  }
  __syncthreads();
  if (sh_misc[2] == 1){
    if (t < 512){
      int wv = t >> 6, base = 0;
      for (int i = 0; i < wv; ++i) base += wtot[i];
      int slot = -1;
      if (mem){ slot = candI[base + lp]; atomicMax(&lastB[slot], t); }
      slotForB[t] = slot;
    }
  } else {
    for (int b = 0; b < 512; ++b){
      float bv = parr[t*16]; int bi = t*16;
      #pragma unroll
      for (int j = 1; j < 16; ++j){
        float v = parr[t*16 + j];
        if (v < bv){ bv = v; bi = t*16 + j; }
      }
      tv[t] = bv; ti[t] = bi;
      __syncthreads();
      for (int s = 512; s > 0; s >>= 1){
        if (t < s){
          float v2 = tv[t+s]; int i2 = ti[t+s];
          if (v2 < tv[t] || (v2 == tv[t] && i2 < ti[t])){ tv[t] = v2; ti[t] = i2; }
        }
        __syncthreads();
      }
      int slot = ti[0];
      int memb = smemz[b];
      if (t == 0) slotForB[b] = memb ? slot : -1;
      if (memb && t == (slot >> 4)) parr[slot] = ssur[b];
      __syncthreads();
    }
    if (t < 512){ int s = slotForB[t]; if (s >= 0) atomicMax(&lastB[s], t); }
  }
}

// ---------------- fixup written slots: exact f32 projection -> split stores ----------------
__global__ __launch_bounds__(64) void fixup_rows(const int* __restrict__ slotForB, const int* __restrict__ lastB,
                                                 const float* __restrict__ newK, const float* __restrict__ newV,
                                                 const float* __restrict__ Wpk, const float* __restrict__ Wpv,
                                                 const float* __restrict__ bpk, const float* __restrict__ bpv,
                                                 ushort_t* __restrict__ khH, ushort_t* __restrict__ khL,
                                                 ushort_t* __restrict__ VtH, ushort_t* __restrict__ VtL){
  int b = blockIdx.x;
  int slot = slotForB[b];
  if (slot < 0) return;
  if (lastB[slot] != b) return;
  __shared__ float kr[256], vr[256];
  int t = threadIdx.x;
  *(float4*)(kr + t*4) = *(const float4*)(newK + (size_t)b*256 + t*4);
  *(float4*)(vr + t*4) = *(const float4*)(newV + (size_t)b*256 + t*4);
  __syncthreads();
  for (int c = t; c < 264; c += 64){
    float aK = bpk[c], aV = bpv[c];
    for (int k = 0; k < 256; ++k){
      aK += kr[k]*Wpk[(size_t)k*264 + c];
      aV += vr[k]*Wpv[(size_t)k*264 + c];
    }
    int hh = c/33, dd = c - hh*33;
    ushort_t sh, sl;
    split2(aK, sh, sl);
    khH[(size_t)slot*320 + hh*40 + dd] = sh;
    khL[(size_t)slot*320 + hh*40 + dd] = sl;
    split2(aV, sh, sl);
    VtH[(size_t)(hh*48 + dd)*16384 + slot] = sh;
    VtL[(size_t)(hh*48 + dd)*16384 + slot] = sl;
  }
}

// ---------------- MFMA flash attention partials ----------------
// grid (h=8, bt=8, ms=8), 256 threads (4 waves). St = K.Q^T via MFMA (d<32) + scalar d=32 term.
__global__ __launch_bounds__(256) void attn_mfma(
    const float* __restrict__ qh, const ushort_t* __restrict__ khH, const ushort_t* __restrict__ khL,
    const ushort_t* __restrict__ VtGH, const ushort_t* __restrict__ VtGL,
    float* __restrict__ pm, float* __restrict__ pl, float* __restrict__ pctx){
  const int h = blockIdx.x, bt = blockIdx.y, ms = blockIdx.z;
  const int b0 = bt*64, mbase = ms*2048;
  const int t = threadIdx.x;
  const int lane = t & 63, w = t >> 6;
  const int l15 = lane & 15, q = lane >> 4;
  __shared__ ushort_t QH[64*40], QL[64*40];
  __shared__ ushort_t KH[64*40], KL[64*40];
  __shared__ ushort_t VsH[48*72], VsL[48*72];
  __shared__ ushort_t PH[64*72], PL[64*72];
  __shared__ float q32f[64], k32f[64];
  __shared__ float redM[4*64], redL[4*64];
  __shared__ float rM[64], rL[64], alf[64];
  const float scale = 0.17407765595569785f; // 1/sqrt(33)

  // stage Q once (scaled + split); d=32 kept exact in q32f
  for (int e = t; e < 2048; e += 256){
    int bl = e >> 5, d = e & 31;
    float v = qh[(size_t)(b0+bl)*264 + h*33 + d]*scale;
    ushort_t sh, sl; split2(v, sh, sl);
    QH[bl*40 + d] = sh; QL[bl*40 + d] = sl;
  }
  if (t < 64){
    q32f[t] = qh[(size_t)(b0+t)*264 + h*33 + 32]*scale;
    rM[t] = -INFINITY; rL[t] = 0.f;
  }
  v4f cacc[3];
  #pragma unroll
  for (int i = 0; i < 3; ++i) cacc[i] = (v4f){0.f,0.f,0.f,0.f};

  for (int mt = 0; mt < 32; ++mt){
    const int m0 = mbase + mt*64;
    __syncthreads();   // A: prior PV reads done; Q visible (iter 0)
    {
      int ml = t >> 2, ch = t & 3;
      *(uint4*)(KH + ml*40 + ch*8) = *(const uint4*)(khH + (size_t)(m0+ml)*320 + h*40 + ch*8);
      *(uint4*)(KL + ml*40 + ch*8) = *(const uint4*)(khL + (size_t)(m0+ml)*320 + h*40 + ch*8);
      if (t < 64)
        k32f[t] = bf2f(khH[(size_t)(m0+t)*320 + h*40 + 32]) + bf2f(khL[(size_t)(m0+t)*320 + h*40 + 32]);
    }
    #pragma unroll
    for (int i = 0; i < 3; ++i){
      int idx = t + 256*i;          // 0..767
      int arr = (idx >= 384) ? 1 : 0;
      int rem = idx - arr*384;
      int row = rem >> 3, ch = rem & 7;
      const ushort_t* g = (arr ? VtGL : VtGH) + (size_t)(h*48 + row)*16384 + m0 + ch*8;
      ushort_t* dst = (arr ? VsL : VsH) + row*72 + ch*8;
      *(uint4*)dst = *(const uint4*)g;
    }
    __syncthreads();   // B: staging visible
    // ---- QK^T: St[m][b], wave w owns m rows 16w..16w+15 ----
    v8s aH = *(const v8s*)(KH + (16*w + l15)*40 + q*8);
    v8s aL = *(const v8s*)(KL + (16*w + l15)*40 + q*8);
    v4f s[4];
    #pragma unroll
    for (int jn = 0; jn < 4; ++jn){
      s[jn] = (v4f){0.f,0.f,0.f,0.f};
      v8s bH = *(const v8s*)(QH + (jn*16 + l15)*40 + q*8);
      v8s bL = *(const v8s*)(QL + (jn*16 + l15)*40 + q*8);
      s[jn] = __builtin_amdgcn_mfma_f32_16x16x32_bf16(aH, bH, s[jn], 0, 0, 0);
      s[jn] = __builtin_amdgcn_mfma_f32_16x16x32_bf16(aH, bL, s[jn], 0, 0, 0);
      s[jn] = __builtin_amdgcn_mfma_f32_16x16x32_bf16(aL, bH, s[jn], 0, 0, 0);
    }
    float kv[4];
    #pragma unroll
    for (int r = 0; r < 4; ++r) kv[r] = k32f[16*w + q*4 + r];
    #pragma unroll
    for (int jn = 0; jn < 4; ++jn){
      float qv = q32f[jn*16 + l15];
      #pragma unroll
      for (int r = 0; r < 4; ++r) s[jn][r] += kv[r]*qv;
    }
    // wave-partial max per b
    #pragma unroll
    for (int jn = 0; jn < 4; ++jn){
      float m1 = fmaxf(fmaxf(s[jn][0], s[jn][1]), fmaxf(s[jn][2], s[jn][3]));
      m1 = fmaxf(m1, __shfl_xor(m1, 16, 64));
      m1 = fmaxf(m1, __shfl_xor(m1, 32, 64));
      if (q == 0) redM[w*64 + jn*16 + l15] = m1;
    }
    __syncthreads();   // C
    if (t < 64){
      float m4 = fmaxf(fmaxf(redM[t], redM[64+t]), fmaxf(redM[128+t], redM[192+t]));
      float old = rM[t];
      float nm = fmaxf(old, m4);
      alf[t] = __expf(old - nm);
      rM[t] = nm;
    }
    __syncthreads();   // D
    // P = exp(St - nm[b]); sums; packed writes P[b][m]
    #pragma unroll
    for (int jn = 0; jn < 4; ++jn){
      float nm = rM[jn*16 + l15];
      v4f p;
      #pragma unroll
      for (int r = 0; r < 4; ++r) p[r] = __expf(s[jn][r] - nm);
      float sm = p[0] + p[1] + p[2] + p[3];
      sm += __shfl_xor(sm, 16, 64);
      sm += __shfl_xor(sm, 32, 64);
      if (q == 0) redL[w*64 + jn*16 + l15] = sm;
      ushort4 hv, lv;
      split2(p[0], hv.x, lv.x); split2(p[1], hv.y, lv.y);
      split2(p[2], hv.z, lv.z); split2(p[3], hv.w, lv.w);
      *(ushort4*)(PH + (jn*16 + l15)*72 + 16*w + q*4) = hv;
      *(ushort4*)(PL + (jn*16 + l15)*72 + 16*w + q*4) = lv;
    }
    // rescale ctx accumulators by alf[b], b = 16w + q*4 + r
    float av[4];
    #pragma unroll
    for (int r = 0; r < 4; ++r) av[r] = alf[16*w + q*4 + r];
    #pragma unroll
    for (int tile = 0; tile < 3; ++tile)
      #pragma unroll
      for (int r = 0; r < 4; ++r) cacc[tile][r] *= av[r];
    __syncthreads();   // E: P visible, redL done
    if (t < 64) rL[t] = rL[t]*alf[t] + (redL[t] + redL[64+t] + redL[128+t] + redL[192+t]);
    // ---- PV: ctx[b][d] += P[b][m] . Vt[d][m]; wave w owns b rows 16w..16w+15 ----
    #pragma unroll
    for (int ks = 0; ks < 2; ++ks){
      v8s paH = *(const v8s*)(PH + (16*w + l15)*72 + ks*32 + q*8);
      v8s paL = *(const v8s*)(PL + (16*w + l15)*72 + ks*32 + q*8);
      #pragma unroll
      for (int tile = 0; tile < 3; ++tile){
        v8s vbH = *(const v8s*)(VsH + (tile*16 + l15)*72 + ks*32 + q*8);
        v8s vbL = *(const v8s*)(VsL + (tile*16 + l15)*72 + ks*32 + q*8);
        cacc[tile] = __builtin_amdgcn_mfma_f32_16x16x32_bf16(paH, vbH, cacc[tile], 0, 0, 0);
        cacc[tile] = __builtin_amdgcn_mfma_f32_16x16x32_bf16(paH, vbL, cacc[tile], 0, 0, 0);
        cacc[tile] = __builtin_amdgcn_mfma_f32_16x16x32_bf16(paL, vbH, cacc[tile], 0, 0, 0);
      }
    }
  }
  __syncthreads();
  int g = (h*8 + bt)*8 + ms;
  if (t < 64){ pm[(size_t)g*64 + t] = rM[t]; pl[(size_t)g*64 + t] = rL[t]; }
  #pragma unroll
  for (int tile = 0; tile < 3; ++tile){
    int d = tile*16 + l15;
    if (d < 33){
      #pragma unroll
      for (int r = 0; r < 4; ++r){
        int b = 16*w + q*4 + r;
        pctx[((size_t)g*64 + b)*33 + d] = cacc[tile][r];
      }
    }
  }
}

__global__ __launch_bounds__(256) void combine_kernel(const float* __restrict__ pm, const float* __restrict__ pl,
                                                      const float* __restrict__ pctx, float* __restrict__ ctxf){
  int idx = blockIdx.x*256 + threadIdx.x;
  if (idx >= 512*264) return;
  int b = idx / 264, c = idx - b*264;
  int h = c / 33, d = c - h*33;
  int bt = b >> 6, bl = b & 63;
  int g0 = (h*8 + bt)*8;
  float gm = -INFINITY;
  for (int ms = 0; ms < 8; ++ms) gm = fmaxf(gm, pm[(g0+ms)*64 + bl]);
  float L = 0.f, cv = 0.f;
  for (int ms = 0; ms < 8; ++ms){
    int gg = (g0+ms)*64 + bl;
    float w = __expf(pm[gg] - gm);
    L += pl[gg]*w;
    cv += pctx[(size_t)gg*33 + d]*w;
  }
  ctxf[idx] = cv / L;
}

// ---------------- host ----------------
extern "C" void kernel_launch(void* const* d_in, const int* in_sizes, int n_in,
                              void* d_out, int out_size, void* d_ws, size_t ws_size,
                              hipStream_t stream){
  (void)in_sizes; (void)n_in; (void)out_size; (void)ws_size;
  const float* features     = (const float*)d_in[0];
  const float* gradients    = (const float*)d_in[1];
  const float* mem_keys     = (const float*)d_in[2];
  const float* mem_values   = (const float*)d_in[3];
  const float* mem_ages     = (const float*)d_in[4];
  const float* mem_surprise = (const float*)d_in[5];
  const float* Wk   = (const float*)d_in[6];
  const float* bk   = (const float*)d_in[7];
  const float* Wv   = (const float*)d_in[8];
  const float* bv   = (const float*)d_in[9];
  const float* Wp   = (const float*)d_in[10];
  const float* bp   = (const float*)d_in[11];
  const float* Win  = (const float*)d_in[12];
  const float* b_in = (const float*)d_in[13];
  const float* Wout = (const float*)d_in[14];
  const float* bout = (const float*)d_in[15];
  const float* Wo   = (const float*)d_in[16];
  const float* bo   = (const float*)d_in[17];
  float* out = (float*)d_out;

  float* w = (float*)d_ws;
  size_t off = 0;
  auto alloc = [&](size_t n)->float*{ float* p = w + off; off += (n + 63) & ~(size_t)63; return p; };
  float*    k2       = alloc(16384);
  unsigned* minD2    = (unsigned*)alloc(512);
  float*    f2       = alloc(512);
  float*    gn       = alloc(512);
  int*      slotForB = (int*)alloc(512);
  int*      lastB    = (int*)alloc(16384);
  float*    parr     = alloc(16384);
  float*    newK     = alloc((size_t)512*256);
  float*    newV     = alloc((size_t)512*256);
  float*    qh       = alloc((size_t)512*264);
  ushort_t* khH      = (ushort_t*)alloc((size_t)16384*320/2);
  ushort_t* khL      = (ushort_t*)alloc((size_t)16384*320/2);
  ushort_t* VtGH     = (ushort_t*)alloc((size_t)8*48*16384/2);
  ushort_t* VtGL     = (ushort_t*)alloc((size_t)8*48*16384/2);
  float*    Wpk      = alloc((size_t)256*264);
  float*    Wpv      = alloc((size_t)256*264);
  float*    Wco      = alloc((size_t)264*256);
  ushort_t* WtkH     = (ushort_t*)alloc((size_t)320*256/2);
  ushort_t* WtkL     = (ushort_t*)alloc((size_t)320*256/2);
  ushort_t* WtvH     = (ushort_t*)alloc((size_t)320*256/2);
  ushort_t* WtvL     = (ushort_t*)alloc((size_t)320*256/2);
  ushort_t* WtqH     = (ushort_t*)alloc((size_t)320*256/2);
  ushort_t* WtqL     = (ushort_t*)alloc((size_t)320*256/2);
  float*    bpk      = alloc(264);
  float*    bpv      = alloc(264);
  float*    bpq      = alloc(264);
  float*    bco      = alloc(256);
  float*    ctxf     = alloc((size_t)512*264);
  float*    pm       = alloc((size_t)512*64);
  float*    pl       = alloc((size_t)512*64);
  float*    pctx     = alloc((size_t)512*64*33);

  prep_k2<<<4096, 256, 0, stream>>>(mem_keys, k2, 16384);
  prep_feat<<<128, 256, 0, stream>>>(features, gradients, f2, gn, minD2, 512);
  zero_pads<<<3840, 256, 0, stream>>>(VtGH, VtGL);

  wprep_gemm<<<dim3(5,5,4), 256, 0, stream>>>(Wp, Win, Wout, Wo,
      WtkH, WtkL, WtvH, WtvL, WtqH, WtqL, Wpk, Wpv, Wco);
  wbias_batch<<<dim3(2,4), 256, 0, stream>>>(bp, Win, b_in, bout, Wo, bo, bpk, bpv, bpq, bco);

  gemm_bias<<<dim3(8,4), 256, 0, stream>>>(features, Wk, bk, newK, 512, 256, 256, 256, 0);
  gemm_bias<<<dim3(8,4), 256, 0, stream>>>(features, Wv, bv, newV, 512, 256, 256, 256, 0);

  gemm_mfma_split<<<dim3(4,5),  256, 0, stream>>>(features,   WtqH, WtqL, bpq, qh, nullptr, nullptr, 264, 0);
  gemm_mfma_split<<<dim3(128,5),256, 0, stream>>>(mem_keys,   WtkH, WtkL, bpk, nullptr, khH, khL,   264, 1);
  gemm_mfma_split<<<dim3(128,5),256, 0, stream>>>(mem_values, WtvH, WtvL, bpv, nullptr, VtGH, VtGL, 264, 2);

  surprise_mfma<<<dim3(128,8), 256, 0, stream>>>(mem_keys, features, k2, minD2);
  scan_kernel<<<1, 1024, 0, stream>>>(mem_surprise, mem_ages, minD2, f2, gn, parr, slotForB, lastB);
  fixup_rows<<<512, 64, 0, stream>>>(slotForB, lastB, newK, newV, Wpk, Wpv, bpk, bpv, khH, khL, VtGH, VtGL);

  attn_mfma<<<dim3(8,8,8), 256, 0, stream>>>(qh, khH, khL, VtGH, VtGL, pm, pl, pctx);
  combine_kernel<<<528, 256, 0, stream>>>(pm, pl, pctx, ctxf);
  gemm_bias<<<dim3(8,4), 256, 0, stream>>>(ctxf, Wco, bco, out, 512, 264, 256, 256, 0);
}

// Round 4
// 427.763 us; speedup vs baseline: 2.6145x; 1.2097x over previous
//
#include <hip/hip_runtime.h>
#include <math.h>

typedef unsigned short ushort_t;
typedef float v4f __attribute__((ext_vector_type(4)));
typedef short v8s __attribute__((ext_vector_type(8)));

#define ATTN_MS 16

// ---------------- helpers ----------------
__device__ __forceinline__ unsigned fenc(float f){
  unsigned b = __float_as_uint(f);
  return (b & 0x80000000u) ? ~b : (b | 0x80000000u);
}
__device__ __forceinline__ float fdec(unsigned u){
  unsigned b = (u & 0x80000000u) ? (u ^ 0x80000000u) : ~u;
  return __uint_as_float(b);
}
__device__ __forceinline__ ushort_t bf16_rne(float x){
  unsigned u = __float_as_uint(x);
  unsigned r = u + 0x7FFFu + ((u >> 16) & 1u);
  return (ushort_t)(r >> 16);
}
__device__ __forceinline__ void split2(float x, ushort_t& h, ushort_t& l){
  unsigned u = __float_as_uint(x);
  unsigned r = u + 0x7FFFu + ((u >> 16) & 1u);
  h = (ushort_t)(r >> 16);
  float hf = __uint_as_float(r & 0xFFFF0000u);
  l = bf16_rne(x - hf);
}
__device__ __forceinline__ float bf2f(ushort_t x){ return __uint_as_float(((unsigned)x) << 16); }
union U8 { v8s v; ushort_t u[8]; };

// ---------------- prep: split inputs to bf16 hi/lo + row stats + V-pad zero ----------------
// grid (4096, 4): y0=mem_keys(+k2), y1=mem_values, y2(x<128)=features/gradients(+f2,gn,minD2), y3(x<3840)=V pads
__global__ __launch_bounds__(256) void prep_all(
    const float* __restrict__ features, const float* __restrict__ gradients,
    const float* __restrict__ mem_keys, const float* __restrict__ mem_values,
    ushort_t* __restrict__ FH, ushort_t* __restrict__ FL,
    ushort_t* __restrict__ MKH, ushort_t* __restrict__ MKL,
    ushort_t* __restrict__ MVH, ushort_t* __restrict__ MVL,
    float* __restrict__ k2, float* __restrict__ f2, float* __restrict__ gn,
    unsigned* __restrict__ minD2, ushort_t* __restrict__ VtGH, ushort_t* __restrict__ VtGL){
  int y = blockIdx.y, bx = blockIdx.x, t = threadIdx.x;
  if (y == 3){
    if (bx >= 3840) return;
    const int PER4 = 8*15*16384/4;
    int idx = bx*256 + t;
    if (idx >= 2*PER4) return;
    ushort_t* base = (idx < PER4) ? VtGH : VtGL;
    int i = (idx < PER4) ? idx : idx - PER4;
    int s = i*4;
    int hh = s / (15*16384);
    int r2 = s - hh*(15*16384);
    int row = 33 + (r2 >> 14);
    int col = r2 & 16383;
    ushort4 z; z.x = 0; z.y = 0; z.z = 0; z.w = 0;
    *(ushort4*)(base + (size_t)(hh*48 + row)*16384 + col) = z;
    return;
  }
  int wid = t >> 6, lane = t & 63;
  int row = bx*4 + wid;
  if (y == 2 && bx >= 128) return;
  const float* src = (y == 0) ? mem_keys : (y == 1) ? mem_values : features;
  float4 v = *(const float4*)(src + (size_t)row*256 + lane*4);
  ushort_t h0,h1,h2,h3,l0,l1,l2,l3;
  split2(v.x,h0,l0); split2(v.y,h1,l1); split2(v.z,h2,l2); split2(v.w,h3,l3);
  uint2 hp = make_uint2((unsigned)h0 | ((unsigned)h1<<16), (unsigned)h2 | ((unsigned)h3<<16));
  uint2 lp = make_uint2((unsigned)l0 | ((unsigned)l1<<16), (unsigned)l2 | ((unsigned)l3<<16));
  ushort_t* H = (y == 0) ? MKH : (y == 1) ? MVH : FH;
  ushort_t* L = (y == 0) ? MKL : (y == 1) ? MVL : FL;
  *(uint2*)(H + (size_t)row*256 + lane*4) = hp;
  *(uint2*)(L + (size_t)row*256 + lane*4) = lp;
  if (y == 1) return;
  float s = v.x*v.x + v.y*v.y + v.z*v.z + v.w*v.w;
  if (y == 0){
    for (int off = 32; off > 0; off >>= 1) s += __shfl_down(s, off, 64);
    if (lane == 0) k2[row] = s;
  } else {
    float4 g = *(const float4*)(gradients + (size_t)row*256 + lane*4);
    float tg = g.x*g.x + g.y*g.y + g.z*g.z + g.w*g.w;
    for (int off = 32; off > 0; off >>= 1){ s += __shfl_down(s, off, 64); tg += __shfl_down(tg, off, 64); }
    if (lane == 0){ f2[row] = s; gn[row] = sqrtf(tg); minD2[row] = 0xFFFFFFFFu; }
  }
}

// ---------------- generic f32 GEMM (z-select between two weight sets) ----------------
__global__ __launch_bounds__(256) void gemm_bias(const float* __restrict__ A, const float* __restrict__ W,
                                                 const float* __restrict__ bias, float* __restrict__ C,
                                                 const float* __restrict__ W2, const float* __restrict__ bias2,
                                                 float* __restrict__ C2,
                                                 int M, int K, int N, int ldw, int woff){
  if (blockIdx.z == 1){ W = W2; bias = bias2; C = C2; }
  __shared__ float As[32*68];
  __shared__ float Ws[32*68];
  int m0 = blockIdx.x*64, c0 = blockIdx.y*64;
  int t = threadIdx.x;
  int mq = (t & 15)*4, cq = (t >> 4)*4;
  float acc[16];
  #pragma unroll
  for (int i = 0; i < 16; ++i) acc[i] = 0.f;
  for (int k0 = 0; k0 < K; k0 += 32){
    #pragma unroll
    for (int i = 0; i < 2; ++i){
      int idx = t + 256*i;
      int row = idx >> 3, kk = (idx & 7)*4;
      int gm = m0 + row, gk = k0 + kk;
      float x=0.f, y=0.f, z=0.f, w=0.f;
      if (gm < M){
        const float* ap = A + (size_t)gm*K + gk;
        if (gk + 3 < K){ float4 v = *(const float4*)ap; x=v.x; y=v.y; z=v.z; w=v.w; }
        else {
          if (gk   < K) x = ap[0];
          if (gk+1 < K) y = ap[1];
          if (gk+2 < K) z = ap[2];
          if (gk+3 < K) w = ap[3];
        }
      }
      As[(kk+0)*68+row]=x; As[(kk+1)*68+row]=y; As[(kk+2)*68+row]=z; As[(kk+3)*68+row]=w;
    }
    #pragma unroll
    for (int i = 0; i < 2; ++i){
      int idx = t + 256*i;
      int kk = idx >> 4, cc = (idx & 15)*4;
      int gk = k0 + kk, gc = c0 + cc;
      float4 v = make_float4(0.f,0.f,0.f,0.f);
      if (gk < K){
        const float* wp = W + (size_t)gk*ldw + woff + gc;
        if (gc + 3 < N) v = *(const float4*)wp;
        else {
          if (gc   < N) v.x = wp[0];
          if (gc+1 < N) v.y = wp[1];
          if (gc+2 < N) v.z = wp[2];
          if (gc+3 < N) v.w = wp[3];
        }
      }
      *(float4*)(Ws + kk*68 + cc) = v;
    }
    __syncthreads();
    #pragma unroll
    for (int j = 0; j < 32; ++j){
      float4 a = *(const float4*)(As + j*68 + mq);
      float4 w = *(const float4*)(Ws + j*68 + cq);
      acc[ 0]+=a.x*w.x; acc[ 1]+=a.x*w.y; acc[ 2]+=a.x*w.z; acc[ 3]+=a.x*w.w;
      acc[ 4]+=a.y*w.x; acc[ 5]+=a.y*w.y; acc[ 6]+=a.y*w.z; acc[ 7]+=a.y*w.w;
      acc[ 8]+=a.z*w.x; acc[ 9]+=a.z*w.y; acc[10]+=a.z*w.z; acc[11]+=a.z*w.w;
      acc[12]+=a.w*w.x; acc[13]+=a.w*w.y; acc[14]+=a.w*w.z; acc[15]+=a.w*w.w;
    }
    __syncthreads();
  }
  #pragma unroll
  for (int i = 0; i < 4; ++i){
    int gm = m0 + mq + i;
    if (gm >= M) continue;
    #pragma unroll
    for (int j = 0; j < 4; ++j){
      int gc = c0 + cq + j;
      if (gc >= N) continue;
      C[(size_t)gm*N + gc] = acc[i*4+j] + (bias ? bias[gc] : 0.f);
    }
  }
}

// ---------------- weight prep: fused-projection GEMMs w/ transpose-split epilogue + (z=4) biases ----------------
__global__ __launch_bounds__(256) void wprep_gemm(
    const float* __restrict__ Wp, const float* __restrict__ Win,
    const float* __restrict__ Wout, const float* __restrict__ Wo,
    const float* __restrict__ bp, const float* __restrict__ b_in,
    const float* __restrict__ bout, const float* __restrict__ bo,
    ushort_t* __restrict__ WtkH, ushort_t* __restrict__ WtkL,
    ushort_t* __restrict__ WtvH, ushort_t* __restrict__ WtvL,
    ushort_t* __restrict__ WtqH, ushort_t* __restrict__ WtqL,
    float* __restrict__ Wpk, float* __restrict__ Wpv, float* __restrict__ Wco,
    float* __restrict__ bpq, float* __restrict__ bpk, float* __restrict__ bpv, float* __restrict__ bco){
  __shared__ float As[32*68];
  __shared__ float Ws[32*68];
  int z = blockIdx.z;
  int t = threadIdx.x;
  if (z == 4){
    int flat = (blockIdx.x*5 + blockIdx.y)*256 + t;
    if (flat < 264){
      float a = b_in[flat];
      for (int k = 0; k < 264; ++k) a += bp[k]*Win[(size_t)k*792 + flat];
      bpq[flat] = a;
    } else if (flat < 528){
      int c = flat - 264;
      float a = b_in[264 + c];
      for (int k = 0; k < 264; ++k) a += bp[k]*Win[(size_t)k*792 + 264 + c];
      bpk[c] = a;
    } else if (flat < 792){
      int c = flat - 528;
      float a = b_in[528 + c];
      for (int k = 0; k < 264; ++k) a += bp[k]*Win[(size_t)k*792 + 528 + c];
      bpv[c] = a;
    } else if (flat < 1048){
      int c = flat - 792;
      float a = bo[c];
      for (int k = 0; k < 264; ++k) a += bout[k]*Wo[(size_t)k*256 + c];
      bco[c] = a;
    }
    return;
  }
  const float* A = (z < 3) ? Wp : Wout;
  const float* W = (z < 3) ? Win : Wo;
  const int M = (z < 3) ? 256 : 264;
  const int K = 264;
  const int N = (z < 3) ? 264 : 256;
  const int ldw = (z < 3) ? 792 : 256;
  const int woff = (z == 0) ? 264 : (z == 1) ? 528 : 0;
  int m0 = blockIdx.x*64, c0 = blockIdx.y*64;
  int mq = (t & 15)*4, cq = (t >> 4)*4;
  float acc[16];
  #pragma unroll
  for (int i = 0; i < 16; ++i) acc[i] = 0.f;
  for (int k0 = 0; k0 < K; k0 += 32){
    #pragma unroll
    for (int i = 0; i < 2; ++i){
      int idx = t + 256*i;
      int row = idx >> 3, kk = (idx & 7)*4;
      int gm = m0 + row, gk = k0 + kk;
      float x=0.f, y=0.f, z2=0.f, w=0.f;
      if (gm < M){
        const float* ap = A + (size_t)gm*K + gk;
        if (gk + 3 < K){ float4 v = *(const float4*)ap; x=v.x; y=v.y; z2=v.z; w=v.w; }
        else {
          if (gk   < K) x = ap[0];
          if (gk+1 < K) y = ap[1];
          if (gk+2 < K) z2 = ap[2];
          if (gk+3 < K) w = ap[3];
        }
      }
      As[(kk+0)*68+row]=x; As[(kk+1)*68+row]=y; As[(kk+2)*68+row]=z2; As[(kk+3)*68+row]=w;
    }
    #pragma unroll
    for (int i = 0; i < 2; ++i){
      int idx = t + 256*i;
      int kk = idx >> 4, cc = (idx & 15)*4;
      int gk = k0 + kk, gc = c0 + cc;
      float4 v = make_float4(0.f,0.f,0.f,0.f);
      if (gk < K){
        const float* wp = W + (size_t)gk*ldw + woff + gc;
        if (gc + 3 < N) v = *(const float4*)wp;
        else {
          if (gc   < N) v.x = wp[0];
          if (gc+1 < N) v.y = wp[1];
          if (gc+2 < N) v.z = wp[2];
          if (gc+3 < N) v.w = wp[3];
        }
      }
      *(float4*)(Ws + kk*68 + cc) = v;
    }
    __syncthreads();
    #pragma unroll
    for (int j = 0; j < 32; ++j){
      float4 a = *(const float4*)(As + j*68 + mq);
      float4 w = *(const float4*)(Ws + j*68 + cq);
      acc[ 0]+=a.x*w.x; acc[ 1]+=a.x*w.y; acc[ 2]+=a.x*w.z; acc[ 3]+=a.x*w.w;
      acc[ 4]+=a.y*w.x; acc[ 5]+=a.y*w.y; acc[ 6]+=a.y*w.z; acc[ 7]+=a.y*w.w;
      acc[ 8]+=a.z*w.x; acc[ 9]+=a.z*w.y; acc[10]+=a.z*w.z; acc[11]+=a.z*w.w;
      acc[12]+=a.w*w.x; acc[13]+=a.w*w.y; acc[14]+=a.w*w.z; acc[15]+=a.w*w.w;
    }
    __syncthreads();
  }
  if (z < 3){
    ushort_t* WH = (z==0) ? WtkH : (z==1) ? WtvH : WtqH;
    ushort_t* WL = (z==0) ? WtkL : (z==1) ? WtvL : WtqL;
    float* Wf = (z==0) ? Wpk : (z==1) ? Wpv : nullptr;
    #pragma unroll
    for (int i = 0; i < 4; ++i){
      int gm = m0 + mq + i;
      if (gm >= 256) continue;
      #pragma unroll
      for (int j = 0; j < 4; ++j){
        int gc = c0 + cq + j;
        float r = acc[i*4+j];
        ushort_t hh, ll; split2(r, hh, ll);
        WH[(size_t)gc*256 + gm] = hh;
        WL[(size_t)gc*256 + gm] = ll;
        if (Wf && gc < 264) Wf[(size_t)gm*264 + gc] = r;
      }
    }
  } else {
    #pragma unroll
    for (int i = 0; i < 4; ++i){
      int gm = m0 + mq + i;
      if (gm >= 264) continue;
      #pragma unroll
      for (int j = 0; j < 4; ++j){
        int gc = c0 + cq + j;
        if (gc < 256) Wco[(size_t)gm*256 + gc] = acc[i*4+j];
      }
    }
  }
}

// ---------------- unified big MFMA kernel (pre-split bf16 inputs) ----------------
// grid (128, 8, 4):
//  z=0 (x<4,y<5):  qh  = F  @ Wtq  -> f32 [512][264]
//  z=1 (y<5):      kh  = MK @ Wtk  -> split, head-padded [16384][320]
//  z=2 (y<5):      Vt  = MV @ Wtv  -> split, transposed [8*48][16384]
//  z=3 (y<8):      surprise: min over m of (k2[m] - 2 MK.F) -> atomicMin minD2
__global__ __launch_bounds__(256) void big_mfma(
    const ushort_t* __restrict__ FH, const ushort_t* __restrict__ FL,
    const ushort_t* __restrict__ MKH, const ushort_t* __restrict__ MKL,
    const ushort_t* __restrict__ MVH, const ushort_t* __restrict__ MVL,
    const ushort_t* __restrict__ WtqH, const ushort_t* __restrict__ WtqL,
    const ushort_t* __restrict__ WtkH, const ushort_t* __restrict__ WtkL,
    const ushort_t* __restrict__ WtvH, const ushort_t* __restrict__ WtvL,
    const float* __restrict__ bpq, const float* __restrict__ bpk, const float* __restrict__ bpv,
    const float* __restrict__ k2,
    float* __restrict__ qh, ushort_t* __restrict__ khH, ushort_t* __restrict__ khL,
    ushort_t* __restrict__ VtGH, ushort_t* __restrict__ VtGL, unsigned* __restrict__ minD2){
  int z = blockIdx.z;
  int bx = blockIdx.x, by = blockIdx.y;
  if (z == 0 && bx >= 4) return;
  if (z != 3 && by >= 5) return;
  __shared__ ushort_t AsH[128*40];
  __shared__ ushort_t AsL[128*40];
  __shared__ ushort_t BsH[64*40];
  __shared__ ushort_t BsL[64*40];
  __shared__ unsigned sminU[64];
  const ushort_t* AH = (z == 0) ? FH : (z == 2) ? MVH : MKH;
  const ushort_t* AL = (z == 0) ? FL : (z == 2) ? MVL : MKL;
  const ushort_t* BH = (z == 0) ? WtqH : (z == 1) ? WtkH : (z == 2) ? WtvH : FH;
  const ushort_t* BL = (z == 0) ? WtqL : (z == 1) ? WtkL : WtvL;
  const float* bias = (z == 0) ? bpq : (z == 1) ? bpk : bpv;
  int t = threadIdx.x;
  int m0 = bx*128, n0 = by*64;
  int lane = t & 63, w = t >> 6;
  int wm = (w & 1)*64, wn = (w >> 1)*32;
  int l15 = lane & 15, q = lane >> 4;
  if (z == 3 && t < 64) sminU[t] = 0xFFFFFFFFu;
  v4f acc[4][2];
  #pragma unroll
  for (int i = 0; i < 4; ++i)
    #pragma unroll
    for (int j = 0; j < 2; ++j) acc[i][j] = (v4f){0.f,0.f,0.f,0.f};

  for (int k0 = 0; k0 < 256; k0 += 32){
    #pragma unroll
    for (int rdx = 0; rdx < 2; ++rdx){
      int idx = t + 256*rdx;          // 512 units: 128 rows x 4 chunks
      int row = idx >> 2, ch = idx & 3;
      *(uint4*)(AsH + row*40 + ch*8) = *(const uint4*)(AH + (size_t)(m0+row)*256 + k0 + ch*8);
      if (z < 3)
        *(uint4*)(AsL + row*40 + ch*8) = *(const uint4*)(AL + (size_t)(m0+row)*256 + k0 + ch*8);
    }
    {
      int row = t >> 2, ch = t & 3;   // 256 units: 64 rows x 4 chunks
      *(uint4*)(BsH + row*40 + ch*8) = *(const uint4*)(BH + (size_t)(n0+row)*256 + k0 + ch*8);
      if (z < 3)
        *(uint4*)(BsL + row*40 + ch*8) = *(const uint4*)(BL + (size_t)(n0+row)*256 + k0 + ch*8);
    }
    __syncthreads();
    if (z < 3){
      v8s aH[4], aL[4], bH[2], bL[2];
      #pragma unroll
      for (int im = 0; im < 4; ++im){
        aH[im] = *(const v8s*)(AsH + (wm + im*16 + l15)*40 + q*8);
        aL[im] = *(const v8s*)(AsL + (wm + im*16 + l15)*40 + q*8);
      }
      #pragma unroll
      for (int jn = 0; jn < 2; ++jn){
        bH[jn] = *(const v8s*)(BsH + (wn + jn*16 + l15)*40 + q*8);
        bL[jn] = *(const v8s*)(BsL + (wn + jn*16 + l15)*40 + q*8);
      }
      #pragma unroll
      for (int im = 0; im < 4; ++im)
        #pragma unroll
        for (int jn = 0; jn < 2; ++jn){
          acc[im][jn] = __builtin_amdgcn_mfma_f32_16x16x32_bf16(aH[im], bH[jn], acc[im][jn], 0, 0, 0);
          acc[im][jn] = __builtin_amdgcn_mfma_f32_16x16x32_bf16(aH[im], bL[jn], acc[im][jn], 0, 0, 0);
          acc[im][jn] = __builtin_amdgcn_mfma_f32_16x16x32_bf16(aL[im], bH[jn], acc[im][jn], 0, 0, 0);
        }
    } else {
      v8s aH[4], bH[2];
      #pragma unroll
      for (int im = 0; im < 4; ++im) aH[im] = *(const v8s*)(AsH + (wm + im*16 + l15)*40 + q*8);
      #pragma unroll
      for (int jn = 0; jn < 2; ++jn) bH[jn] = *(const v8s*)(BsH + (wn + jn*16 + l15)*40 + q*8);
      #pragma unroll
      for (int im = 0; im < 4; ++im)
        #pragma unroll
        for (int jn = 0; jn < 2; ++jn)
          acc[im][jn] = __builtin_amdgcn_mfma_f32_16x16x32_bf16(aH[im], bH[jn], acc[im][jn], 0, 0, 0);
    }
    __syncthreads();
  }

  if (z == 3){
    float kk[4][4];
    #pragma unroll
    for (int im = 0; im < 4; ++im)
      #pragma unroll
      for (int r = 0; r < 4; ++r) kk[im][r] = k2[m0 + wm + im*16 + q*4 + r];
    #pragma unroll
    for (int jn = 0; jn < 2; ++jn){
      float mv = INFINITY;
      #pragma unroll
      for (int im = 0; im < 4; ++im)
        #pragma unroll
        for (int r = 0; r < 4; ++r)
          mv = fminf(mv, kk[im][r] - 2.f*acc[im][jn][r]);
      mv = fminf(mv, __shfl_xor(mv, 16, 64));
      mv = fminf(mv, __shfl_xor(mv, 32, 64));
      if (q == 0) atomicMin(&sminU[wn + jn*16 + l15], fenc(mv));
    }
    __syncthreads();
    if (t < 64) atomicMin(&minD2[n0 + t], sminU[t]);
    return;
  }
  #pragma unroll
  for (int im = 0; im < 4; ++im){
    #pragma unroll
    for (int jn = 0; jn < 2; ++jn){
      int n = n0 + wn + jn*16 + l15;
      if (n >= 264) continue;
      float bv = bias[n];
      int mb = m0 + wm + im*16 + q*4;
      if (z == 0){
        #pragma unroll
        for (int r = 0; r < 4; ++r) qh[(size_t)(mb+r)*264 + n] = acc[im][jn][r] + bv;
      } else if (z == 1){
        int hh = n/33, dd = n - hh*33;
        int col = hh*40 + dd;
        #pragma unroll
        for (int r = 0; r < 4; ++r){
          ushort_t sh, sl; split2(acc[im][jn][r] + bv, sh, sl);
          khH[(size_t)(mb+r)*320 + col] = sh;
          khL[(size_t)(mb+r)*320 + col] = sl;
        }
      } else {
        int hh = n/33, dd = n - hh*33;
        size_t rowb = (size_t)(hh*48 + dd)*16384 + mb;
        ushort4 hv, lv;
        split2(acc[im][jn][0] + bv, hv.x, lv.x);
        split2(acc[im][jn][1] + bv, hv.y, lv.y);
        split2(acc[im][jn][2] + bv, hv.z, lv.z);
        split2(acc[im][jn][3] + bv, hv.w, lv.w);
        *(ushort4*)(VtGH + rowb) = hv;
        *(ushort4*)(VtGL + rowb) = lv;
      }
    }
  }
}

// ---------------- eviction scan (finalize folded; fast path + exact fallback) ----------------
#define SCAN_CAP 1024
__global__ __launch_bounds__(1024) void scan_kernel(
    const float* __restrict__ mem_surprise, const float* __restrict__ mem_ages,
    const unsigned* __restrict__ minD2, const float* __restrict__ f2, const float* __restrict__ gn,
    float* __restrict__ parr, int* __restrict__ slotForB, int* __restrict__ lastB){
  __shared__ unsigned hist[2048];
  __shared__ float candV[SCAN_CAP];
  __shared__ int   candI[SCAN_CAP];
  __shared__ float tv[1024];
  __shared__ int   ti[1024];
  __shared__ float ssur[512];
  __shared__ int   smemz[512];
  __shared__ int   wtot[16];
  __shared__ int   sh_misc[8];
  int t = threadIdx.x;

  int mem = 0;
  if (t < 512){
    float d2 = fdec(minD2[t]) + f2[t];
    float s = gn[t]*sqrtf(fmaxf(d2, 0.f));
    ssur[t] = s;
    mem = (s > 0.1f) ? 1 : 0;
    smemz[t] = mem;
  }
  const float LN095 = -0.05129329438755058f;
  #pragma unroll
  for (int j = 0; j < 16; ++j){
    int m = t*16 + j;
    float p = mem_surprise[m] * __expf(mem_ages[m] * LN095);
    parr[m] = p;
    lastB[m] = -1;
  }
  hist[t] = 0u; hist[t + 1024] = 0u;
  if (t < 8) sh_misc[t] = (t == 3) ? 0x7F800000 : 0;
  __syncthreads();
  #pragma unroll
  for (int j = 0; j < 16; ++j){
    int m = t*16 + j;
    unsigned key = __float_as_uint(parr[m]) >> 20;
    if (key > 2047u) key = 2047u;
    atomicAdd(&hist[key], 1u);
  }
  __syncthreads();
  if (t < 512){ ti[t] = (int)(hist[4*t] + hist[4*t+1] + hist[4*t+2] + hist[4*t+3]); }
  __syncthreads();
  if (t < 32){ int s = 0; for (int i = 0; i < 16; ++i) s += ti[16*t + i]; ti[512 + t] = s; }
  __syncthreads();
  if (t == 0){
    int cum = 0, i2 = 0;
    for (; i2 < 32; ++i2){ if (cum + ti[512+i2] >= 512) break; cum += ti[512+i2]; }
    int i1 = i2*16;
    for (;; ++i1){ if (cum + ti[i1] >= 512) break; cum += ti[i1]; }
    int bin = i1*4;
    for (;; ++bin){ if (cum + (int)hist[bin] >= 512) break; cum += (int)hist[bin]; }
    sh_misc[1] = bin;
  }
  __syncthreads();
  int threshKey = sh_misc[1];
  #pragma unroll
  for (int j = 0; j < 16; ++j){
    int m = t*16 + j;
    unsigned key = __float_as_uint(parr[m]) >> 20;
    if (key > 2047u) key = 2047u;
    if ((int)key <= threshKey){
      int pos = atomicAdd(&sh_misc[0], 1);
      if (pos < SCAN_CAP){ candV[pos] = parr[m]; candI[pos] = m; }
    }
  }
  __syncthreads();
  int cnt = sh_misc[0];
  if (t >= cnt && t < SCAN_CAP){ candV[t] = INFINITY; candI[t] = 0x7FFFFFFF; }
  __syncthreads();
  for (int ksz = 2; ksz <= SCAN_CAP; ksz <<= 1){
    for (int jj = ksz >> 1; jj > 0; jj >>= 1){
      int ixj = t ^ jj;
      if (ixj > t){
        float v1 = candV[t], v2 = candV[ixj];
        int i1 = candI[t], i2 = candI[ixj];
        bool lt21 = (v2 < v1) || (v2 == v1 && i2 < i1);
        bool lt12 = (v1 < v2) || (v1 == v2 && i1 < i2);
        bool up = ((t & ksz) == 0);
        bool sw = up ? lt21 : lt12;
        if (sw){ candV[t] = v2; candI[t] = i2; candV[ixj] = v1; candI[ixj] = i1; }
      }
      __syncthreads();
    }
  }
  int lp = 0;
  if (t < 512){
    unsigned long long mask = __ballot(mem != 0);
    int lane = t & 63;
    lp = __popcll(mask & ((1ull << lane) - 1ull));
    if (lane == 0) wtot[t >> 6] = __popcll(mask);
  }
  if (t < 512 && mem) atomicMin(&sh_misc[3], __float_as_int(ssur[t]));
  __syncthreads();
  if (t == 0){
    int ksum = 0;
    for (int wv = 0; wv < 8; ++wv) ksum += wtot[wv];
    sh_misc[4] = ksum;
    bool okf = (cnt <= SCAN_CAP) && (ksum <= cnt);
    if (okf && ksum > 0){
      float minw = __int_as_float(sh_misc[3]);
      okf = (minw > candV[ksum - 1]);
    }
    sh_misc[2] = okf ? 1 : 0;
  }
  __syncthreads();
  if (sh_misc[2] == 1){
    if (t < 512){
      int wv = t >> 6, base = 0;
      for (int i = 0; i < wv; ++i) base += wtot[i];
      int slot = -1;
      if (mem){ slot = candI[base + lp]; atomicMax(&lastB[slot], t); }
      slotForB[t] = slot;
    }
  } else {
    for (int b = 0; b < 512; ++b){
      float bv = parr[t*16]; int bi = t*16;
      #pragma unroll
      for (int j = 1; j < 16; ++j){
        float v = parr[t*16 + j];
        if (v < bv){ bv = v; bi = t*16 + j; }
      }
      tv[t] = bv; ti[t] = bi;
      __syncthreads();
      for (int s = 512; s > 0; s >>= 1){
        if (t < s){
          float v2 = tv[t+s]; int i2 = ti[t+s];
          if (v2 < tv[t] || (v2 == tv[t] && i2 < ti[t])){ tv[t] = v2; ti[t] = i2; }
        }
        __syncthreads();
      }
      int slot = ti[0];
      int memb = smemz[b];
      if (t == 0) slotForB[b] = memb ? slot : -1;
      if (memb && t == (slot >> 4)) parr[slot] = ssur[b];
      __syncthreads();
    }
    if (t < 512){ int s = slotForB[t]; if (s >= 0) atomicMax(&lastB[s], t); }
  }
}

// ---------------- fixup written slots: exact f32 projection -> split stores ----------------
__global__ __launch_bounds__(64) void fixup_rows(const int* __restrict__ slotForB, const int* __restrict__ lastB,
                                                 const float* __restrict__ newK, const float* __restrict__ newV,
                                                 const float* __restrict__ Wpk, const float* __restrict__ Wpv,
                                                 const float* __restrict__ bpk, const float* __restrict__ bpv,
                                                 ushort_t* __restrict__ khH, ushort_t* __restrict__ khL,
                                                 ushort_t* __restrict__ VtH, ushort_t* __restrict__ VtL){
  int b = blockIdx.x;
  int slot = slotForB[b];
  if (slot < 0) return;
  if (lastB[slot] != b) return;
  __shared__ float kr[256], vr[256];
  int t = threadIdx.x;
  *(float4*)(kr + t*4) = *(const float4*)(newK + (size_t)b*256 + t*4);
  *(float4*)(vr + t*4) = *(const float4*)(newV + (size_t)b*256 + t*4);
  __syncthreads();
  for (int c = t; c < 264; c += 64){
    float aK = bpk[c], aV = bpv[c];
    for (int k = 0; k < 256; ++k){
      aK += kr[k]*Wpk[(size_t)k*264 + c];
      aV += vr[k]*Wpv[(size_t)k*264 + c];
    }
    int hh = c/33, dd = c - hh*33;
    ushort_t sh, sl;
    split2(aK, sh, sl);
    khH[(size_t)slot*320 + hh*40 + dd] = sh;
    khL[(size_t)slot*320 + hh*40 + dd] = sl;
    split2(aV, sh, sl);
    VtH[(size_t)(hh*48 + dd)*16384 + slot] = sh;
    VtL[(size_t)(hh*48 + dd)*16384 + slot] = sl;
  }
}

// ---------------- MFMA flash attention, wave-owns-b, register softmax ----------------
// grid (h=8, bt=8, ms=ATTN_MS), 256 threads (4 waves, wave w owns b rows 16w..16w+15)
__global__ __launch_bounds__(256, 3) void attn_mfma(
    const float* __restrict__ qh, const ushort_t* __restrict__ khH, const ushort_t* __restrict__ khL,
    const ushort_t* __restrict__ VtGH, const ushort_t* __restrict__ VtGL,
    float* __restrict__ pm, float* __restrict__ pl, float* __restrict__ pctx){
  const int h = blockIdx.x, bt = blockIdx.y, ms = blockIdx.z;
  const int b0 = bt*64, mbase = ms*(16384/ATTN_MS);
  const int t = threadIdx.x, lane = t & 63, w = t >> 6;
  const int l15 = lane & 15, q = lane >> 4;
  __shared__ ushort_t KH[64*40], KL[64*40];
  __shared__ ushort_t VsH[48*72], VsL[48*72];
  __shared__ ushort_t PH[4*16*72], PL[4*16*72];
  __shared__ float k32f[64];
  const float scale = 0.17407765595569785f; // 1/sqrt(33)

  // loop-invariant Q fragments in registers (b = b0 + 16w + l15, d chunk = q*8..q*8+7)
  const int bq = b0 + 16*w + l15;
  U8 qHU, qLU;
  {
    const float* qp = qh + (size_t)bq*264 + h*33 + q*8;
    #pragma unroll
    for (int j = 0; j < 8; ++j) split2(qp[j]*scale, qHU.u[j], qLU.u[j]);
  }
  const v8s bQH = qHU.v, bQL = qLU.v;
  const float q32v = qh[(size_t)bq*264 + h*33 + 32]*scale;
  float rMv = -INFINITY, rLv = 0.f;
  v4f cacc[3];
  #pragma unroll
  for (int i = 0; i < 3; ++i) cacc[i] = (v4f){0.f,0.f,0.f,0.f};
  ushort_t* PHw = PH + w*16*72;
  ushort_t* PLw = PL + w*16*72;

  for (int mt = 0; mt < 16384/ATTN_MS/64; ++mt){
    const int m0 = mbase + mt*64;
    __syncthreads();   // prior-iter LDS reads complete
    {
      int ml = t >> 2, ch = t & 3;
      *(uint4*)(KH + ml*40 + ch*8) = *(const uint4*)(khH + (size_t)(m0+ml)*320 + h*40 + ch*8);
      *(uint4*)(KL + ml*40 + ch*8) = *(const uint4*)(khL + (size_t)(m0+ml)*320 + h*40 + ch*8);
      if (t < 64)
        k32f[t] = bf2f(khH[(size_t)(m0+t)*320 + h*40 + 32]) + bf2f(khL[(size_t)(m0+t)*320 + h*40 + 32]);
    }
    #pragma unroll
    for (int i = 0; i < 3; ++i){
      int idx = t + 256*i;           // 768 units: 2 arrays x 48 rows x 8 chunks
      int arr = idx >= 384;
      int rem = idx - arr*384;
      int row = rem >> 3, ch = rem & 7;
      const ushort_t* g = (arr ? VtGL : VtGH) + (size_t)(h*48 + row)*16384 + m0 + ch*8;
      *(uint4*)((arr ? VsL : VsH) + row*72 + ch*8) = *(const uint4*)g;
    }
    __syncthreads();   // staging visible
    // ---- QK^T: S[b=16w+l15][m=im*16+q*4+r] ----
    v4f s4[4];
    #pragma unroll
    for (int im = 0; im < 4; ++im){
      v8s aH = *(const v8s*)(KH + (im*16 + l15)*40 + q*8);
      v8s aL = *(const v8s*)(KL + (im*16 + l15)*40 + q*8);
      v4f sv = (v4f){0.f,0.f,0.f,0.f};
      sv = __builtin_amdgcn_mfma_f32_16x16x32_bf16(aH, bQH, sv, 0, 0, 0);
      sv = __builtin_amdgcn_mfma_f32_16x16x32_bf16(aH, bQL, sv, 0, 0, 0);
      sv = __builtin_amdgcn_mfma_f32_16x16x32_bf16(aL, bQH, sv, 0, 0, 0);
      s4[im] = sv;
    }
    #pragma unroll
    for (int im = 0; im < 4; ++im)
      #pragma unroll
      for (int r = 0; r < 4; ++r) s4[im][r] += k32f[im*16 + q*4 + r]*q32v;
    // ---- online softmax (register state, b = 16w+l15) ----
    float mx = -INFINITY;
    #pragma unroll
    for (int im = 0; im < 4; ++im)
      #pragma unroll
      for (int r = 0; r < 4; ++r) mx = fmaxf(mx, s4[im][r]);
    mx = fmaxf(mx, __shfl_xor(mx, 16, 64));
    mx = fmaxf(mx, __shfl_xor(mx, 32, 64));
    float nm = fmaxf(rMv, mx);
    float alf = __expf(rMv - nm);
    rMv = nm;
    float sm = 0.f;
    #pragma unroll
    for (int im = 0; im < 4; ++im){
      v4f p;
      #pragma unroll
      for (int r = 0; r < 4; ++r){ p[r] = __expf(s4[im][r] - nm); sm += p[r]; }
      ushort4 hv, lv;
      split2(p[0], hv.x, lv.x); split2(p[1], hv.y, lv.y);
      split2(p[2], hv.z, lv.z); split2(p[3], hv.w, lv.w);
      *(ushort4*)(PHw + l15*72 + im*16 + q*4) = hv;
      *(ushort4*)(PLw + l15*72 + im*16 + q*4) = lv;
    }
    sm += __shfl_xor(sm, 16, 64);
    sm += __shfl_xor(sm, 32, 64);
    rLv = rLv*alf + sm;
    // rescale ctx acc (b = 16w + q*4 + r) by alf of that b
    #pragma unroll
    for (int r = 0; r < 4; ++r){
      float ar = __shfl(alf, q*4 + r, 64);
      cacc[0][r] *= ar; cacc[1][r] *= ar; cacc[2][r] *= ar;
    }
    // ---- PV: ctx[b][d] += P[b][m] . Vt[d][m] (P private per wave; same-wave LDS ordering) ----
    #pragma unroll
    for (int ks = 0; ks < 2; ++ks){
      v8s paH = *(const v8s*)(PHw + l15*72 + ks*32 + q*8);
      v8s paL = *(const v8s*)(PLw + l15*72 + ks*32 + q*8);
      #pragma unroll
      for (int tile = 0; tile < 3; ++tile){
        v8s vbH = *(const v8s*)(VsH + (tile*16 + l15)*72 + ks*32 + q*8);
        v8s vbL = *(const v8s*)(VsL + (tile*16 + l15)*72 + ks*32 + q*8);
        cacc[tile] = __builtin_amdgcn_mfma_f32_16x16x32_bf16(paH, vbH, cacc[tile], 0, 0, 0);
        cacc[tile] = __builtin_amdgcn_mfma_f32_16x16x32_bf16(paH, vbL, cacc[tile], 0, 0, 0);
        cacc[tile] = __builtin_amdgcn_mfma_f32_16x16x32_bf16(paL, vbH, cacc[tile], 0, 0, 0);
      }
    }
  }
  int g = (h*8 + bt)*ATTN_MS + ms;
  if (q == 0){
    pm[(size_t)g*64 + 16*w + l15] = rMv;
    pl[(size_t)g*64 + 16*w + l15] = rLv;
  }
  #pragma unroll
  for (int tile = 0; tile < 3; ++tile){
    int d = tile*16 + l15;
    if (d < 33){
      #pragma unroll
      for (int r = 0; r < 4; ++r)
        pctx[((size_t)g*64 + 16*w + q*4 + r)*33 + d] = cacc[tile][r];
    }
  }
}

__global__ __launch_bounds__(256) void combine_kernel(const float* __restrict__ pm, const float* __restrict__ pl,
                                                      const float* __restrict__ pctx, float* __restrict__ ctxf){
  int idx = blockIdx.x*256 + threadIdx.x;
  if (idx >= 512*264) return;
  int b = idx / 264, c = idx - b*264;
  int h = c / 33, d = c - h*33;
  int bt = b >> 6, bl = b & 63;
  int g0 = (h*8 + bt)*ATTN_MS;
  float gm = -INFINITY;
  for (int ms = 0; ms < ATTN_MS; ++ms) gm = fmaxf(gm, pm[(g0+ms)*64 + bl]);
  float L = 0.f, cv = 0.f;
  for (int ms = 0; ms < ATTN_MS; ++ms){
    int gg = (g0+ms)*64 + bl;
    float w = __expf(pm[gg] - gm);
    L += pl[gg]*w;
    cv += pctx[(size_t)gg*33 + d]*w;
  }
  ctxf[idx] = cv / L;
}

// ---------------- host ----------------
extern "C" void kernel_launch(void* const* d_in, const int* in_sizes, int n_in,
                              void* d_out, int out_size, void* d_ws, size_t ws_size,
                              hipStream_t stream){
  (void)in_sizes; (void)n_in; (void)out_size; (void)ws_size;
  const float* features     = (const float*)d_in[0];
  const float* gradients    = (const float*)d_in[1];
  const float* mem_keys     = (const float*)d_in[2];
  const float* mem_values   = (const float*)d_in[3];
  const float* mem_ages     = (const float*)d_in[4];
  const float* mem_surprise = (const float*)d_in[5];
  const float* Wk   = (const float*)d_in[6];
  const float* bk   = (const float*)d_in[7];
  const float* Wv   = (const float*)d_in[8];
  const float* bv   = (const float*)d_in[9];
  const float* Wp   = (const float*)d_in[10];
  const float* bp   = (const float*)d_in[11];
  const float* Win  = (const float*)d_in[12];
  const float* b_in = (const float*)d_in[13];
  const float* Wout = (const float*)d_in[14];
  const float* bout = (const float*)d_in[15];
  const float* Wo   = (const float*)d_in[16];
  const float* bo   = (const float*)d_in[17];
  float* out = (float*)d_out;

  float* w = (float*)d_ws;
  size_t off = 0;
  auto alloc = [&](size_t n)->float*{ float* p = w + off; off += (n + 63) & ~(size_t)63; return p; };
  float*    k2       = alloc(16384);
  unsigned* minD2    = (unsigned*)alloc(512);
  float*    f2       = alloc(512);
  float*    gn       = alloc(512);
  int*      slotForB = (int*)alloc(512);
  int*      lastB    = (int*)alloc(16384);
  float*    parr     = alloc(16384);
  float*    newK     = alloc((size_t)512*256);
  float*    newV     = alloc((size_t)512*256);
  float*    qh       = alloc((size_t)512*264);
  ushort_t* khH      = (ushort_t*)alloc((size_t)16384*320/2);
  ushort_t* khL      = (ushort_t*)alloc((size_t)16384*320/2);
  ushort_t* VtGH     = (ushort_t*)alloc((size_t)8*48*16384/2);
  ushort_t* VtGL     = (ushort_t*)alloc((size_t)8*48*16384/2);
  float*    MKbase   = alloc((size_t)16384*256/2*2);     // MKH+MKL contiguous
  ushort_t* MKH      = (ushort_t*)MKbase;
  ushort_t* MKL      = (ushort_t*)(MKbase + (size_t)16384*256/2);
  float*    MVbase   = alloc((size_t)16384*256/2*2);     // MVH+MVL contiguous
  ushort_t* MVH      = (ushort_t*)MVbase;
  ushort_t* MVL      = (ushort_t*)(MVbase + (size_t)16384*256/2);
  ushort_t* FH       = (ushort_t*)alloc((size_t)512*256/2);
  ushort_t* FL       = (ushort_t*)alloc((size_t)512*256/2);
  float*    Wpk      = alloc((size_t)256*264);
  float*    Wpv      = alloc((size_t)256*264);
  float*    Wco      = alloc((size_t)264*256);
  ushort_t* WtkH     = (ushort_t*)alloc((size_t)320*256/2);
  ushort_t* WtkL     = (ushort_t*)alloc((size_t)320*256/2);
  ushort_t* WtvH     = (ushort_t*)alloc((size_t)320*256/2);
  ushort_t* WtvL     = (ushort_t*)alloc((size_t)320*256/2);
  ushort_t* WtqH     = (ushort_t*)alloc((size_t)320*256/2);
  ushort_t* WtqL     = (ushort_t*)alloc((size_t)320*256/2);
  float*    bpq      = alloc(264);
  float*    bpk      = alloc(264);
  float*    bpv      = alloc(264);
  float*    bco      = alloc(256);
  // aliases: MK region (dead after big_mfma) hosts pm/pl/ctxf; MV region hosts pctx
  float*    pm       = MKbase;                       // 1024*64
  float*    pl       = MKbase + (size_t)ATTN_MS*64*64;
  float*    ctxf     = pl + (size_t)ATTN_MS*64*64;   // 512*264
  float*    pctx     = MVbase;                       // 8*8*ATTN_MS*64*33

  prep_all<<<dim3(4096,4), 256, 0, stream>>>(features, gradients, mem_keys, mem_values,
      FH, FL, MKH, MKL, MVH, MVL, k2, f2, gn, minD2, VtGH, VtGL);

  wprep_gemm<<<dim3(5,5,5), 256, 0, stream>>>(Wp, Win, Wout, Wo, bp, b_in, bout, bo,
      WtkH, WtkL, WtvH, WtvL, WtqH, WtqL, Wpk, Wpv, Wco, bpq, bpk, bpv, bco);

  gemm_bias<<<dim3(8,4,2), 256, 0, stream>>>(features, Wk, bk, newK, Wv, bv, newV, 512, 256, 256, 256, 0);

  big_mfma<<<dim3(128,8,4), 256, 0, stream>>>(FH, FL, MKH, MKL, MVH, MVL,
      WtqH, WtqL, WtkH, WtkL, WtvH, WtvL, bpq, bpk, bpv, k2,
      qh, khH, khL, VtGH, VtGL, minD2);

  scan_kernel<<<1, 1024, 0, stream>>>(mem_surprise, mem_ages, minD2, f2, gn, parr, slotForB, lastB);
  fixup_rows<<<512, 64, 0, stream>>>(slotForB, lastB, newK, newV, Wpk, Wpv, bpk, bpv, khH, khL, VtGH, VtGL);

  attn_mfma<<<dim3(8,8,ATTN_MS), 256, 0, stream>>>(qh, khH, khL, VtGH, VtGL, pm, pl, pctx);
  combine_kernel<<<528, 256, 0, stream>>>(pm, pl, pctx, ctxf);
  gemm_bias<<<dim3(8,4,1), 256, 0, stream>>>(ctxf, Wco, bco, out, Wco, bco, out, 512, 264, 256, 256, 0);
}

// Round 5
// 398.789 us; speedup vs baseline: 2.8045x; 1.0727x over previous
//
#include <hip/hip_runtime.h>
#include <math.h>
#include <stdint.h>

typedef unsigned short ushort_t;
typedef float v4f __attribute__((ext_vector_type(4)));
typedef short v8s __attribute__((ext_vector_type(8)));

#define ATTN_MS 16

// ---------------- helpers ----------------
__device__ __forceinline__ unsigned fenc(float f){
  unsigned b = __float_as_uint(f);
  return (b & 0x80000000u) ? ~b : (b | 0x80000000u);
}
__device__ __forceinline__ float fdec(unsigned u){
  unsigned b = (u & 0x80000000u) ? (u ^ 0x80000000u) : ~u;
  return __uint_as_float(b);
}
__device__ __forceinline__ ushort_t bf16_rne(float x){
  unsigned u = __float_as_uint(x);
  unsigned r = u + 0x7FFFu + ((u >> 16) & 1u);
  return (ushort_t)(r >> 16);
}
__device__ __forceinline__ void split2(float x, ushort_t& h, ushort_t& l){
  unsigned u = __float_as_uint(x);
  unsigned r = u + 0x7FFFu + ((u >> 16) & 1u);
  h = (ushort_t)(r >> 16);
  float hf = __uint_as_float(r & 0xFFFF0000u);
  l = bf16_rne(x - hf);
}
__device__ __forceinline__ float bf2f(ushort_t x){ return __uint_as_float(((unsigned)x) << 16); }
union U8 { v8s v; ushort_t u[8]; };

// async global->LDS, 16B per lane; lds dest = wave-uniform base + lane*16
__device__ __forceinline__ void gl2lds16(const void* g, void* l){
  __builtin_amdgcn_global_load_lds(
      (const __attribute__((address_space(1))) unsigned int*)(uintptr_t)g,
      (__attribute__((address_space(3))) unsigned int*)(unsigned int)(uintptr_t)l,
      16, 0, 0);
}

// ---------------- prep: split inputs to bf16 hi/lo + row stats + V-pad zero ----------------
__global__ __launch_bounds__(256) void prep_all(
    const float* __restrict__ features, const float* __restrict__ gradients,
    const float* __restrict__ mem_keys, const float* __restrict__ mem_values,
    ushort_t* __restrict__ FH, ushort_t* __restrict__ FL,
    ushort_t* __restrict__ MKH, ushort_t* __restrict__ MKL,
    ushort_t* __restrict__ MVH, ushort_t* __restrict__ MVL,
    float* __restrict__ k2, float* __restrict__ f2, float* __restrict__ gn,
    unsigned* __restrict__ minD2, ushort_t* __restrict__ VtGH, ushort_t* __restrict__ VtGL){
  int y = blockIdx.y, bx = blockIdx.x, t = threadIdx.x;
  if (y == 3){
    if (bx >= 3840) return;
    const int PER4 = 8*15*16384/4;
    int idx = bx*256 + t;
    if (idx >= 2*PER4) return;
    ushort_t* base = (idx < PER4) ? VtGH : VtGL;
    int i = (idx < PER4) ? idx : idx - PER4;
    int s = i*4;
    int hh = s / (15*16384);
    int r2 = s - hh*(15*16384);
    int row = 33 + (r2 >> 14);
    int col = r2 & 16383;
    ushort4 z; z.x = 0; z.y = 0; z.z = 0; z.w = 0;
    *(ushort4*)(base + (size_t)(hh*48 + row)*16384 + col) = z;
    return;
  }
  int wid = t >> 6, lane = t & 63;
  int row = bx*4 + wid;
  if (y == 2 && bx >= 128) return;
  const float* src = (y == 0) ? mem_keys : (y == 1) ? mem_values : features;
  float4 v = *(const float4*)(src + (size_t)row*256 + lane*4);
  ushort_t h0,h1,h2,h3,l0,l1,l2,l3;
  split2(v.x,h0,l0); split2(v.y,h1,l1); split2(v.z,h2,l2); split2(v.w,h3,l3);
  uint2 hp = make_uint2((unsigned)h0 | ((unsigned)h1<<16), (unsigned)h2 | ((unsigned)h3<<16));
  uint2 lp = make_uint2((unsigned)l0 | ((unsigned)l1<<16), (unsigned)l2 | ((unsigned)l3<<16));
  ushort_t* H = (y == 0) ? MKH : (y == 1) ? MVH : FH;
  ushort_t* L = (y == 0) ? MKL : (y == 1) ? MVL : FL;
  *(uint2*)(H + (size_t)row*256 + lane*4) = hp;
  *(uint2*)(L + (size_t)row*256 + lane*4) = lp;
  if (y == 1) return;
  float s = v.x*v.x + v.y*v.y + v.z*v.z + v.w*v.w;
  if (y == 0){
    for (int off = 32; off > 0; off >>= 1) s += __shfl_down(s, off, 64);
    if (lane == 0) k2[row] = s;
  } else {
    float4 g = *(const float4*)(gradients + (size_t)row*256 + lane*4);
    float tg = g.x*g.x + g.y*g.y + g.z*g.z + g.w*g.w;
    for (int off = 32; off > 0; off >>= 1){ s += __shfl_down(s, off, 64); tg += __shfl_down(tg, off, 64); }
    if (lane == 0){ f2[row] = s; gn[row] = sqrtf(tg); minD2[row] = 0xFFFFFFFFu; }
  }
}

// ---------------- generic f32 GEMM (z-select between two weight sets) ----------------
__global__ __launch_bounds__(256) void gemm_bias(const float* __restrict__ A, const float* __restrict__ W,
                                                 const float* __restrict__ bias, float* __restrict__ C,
                                                 const float* __restrict__ W2, const float* __restrict__ bias2,
                                                 float* __restrict__ C2,
                                                 int M, int K, int N, int ldw, int woff){
  if (blockIdx.z == 1){ W = W2; bias = bias2; C = C2; }
  __shared__ float As[32*68];
  __shared__ float Ws[32*68];
  int m0 = blockIdx.x*64, c0 = blockIdx.y*64;
  int t = threadIdx.x;
  int mq = (t & 15)*4, cq = (t >> 4)*4;
  float acc[16];
  #pragma unroll
  for (int i = 0; i < 16; ++i) acc[i] = 0.f;
  for (int k0 = 0; k0 < K; k0 += 32){
    #pragma unroll
    for (int i = 0; i < 2; ++i){
      int idx = t + 256*i;
      int row = idx >> 3, kk = (idx & 7)*4;
      int gm = m0 + row, gk = k0 + kk;
      float x=0.f, y=0.f, z=0.f, w=0.f;
      if (gm < M){
        const float* ap = A + (size_t)gm*K + gk;
        if (gk + 3 < K){ float4 v = *(const float4*)ap; x=v.x; y=v.y; z=v.z; w=v.w; }
        else {
          if (gk   < K) x = ap[0];
          if (gk+1 < K) y = ap[1];
          if (gk+2 < K) z = ap[2];
          if (gk+3 < K) w = ap[3];
        }
      }
      As[(kk+0)*68+row]=x; As[(kk+1)*68+row]=y; As[(kk+2)*68+row]=z; As[(kk+3)*68+row]=w;
    }
    #pragma unroll
    for (int i = 0; i < 2; ++i){
      int idx = t + 256*i;
      int kk = idx >> 4, cc = (idx & 15)*4;
      int gk = k0 + kk, gc = c0 + cc;
      float4 v = make_float4(0.f,0.f,0.f,0.f);
      if (gk < K){
        const float* wp = W + (size_t)gk*ldw + woff + gc;
        if (gc + 3 < N) v = *(const float4*)wp;
        else {
          if (gc   < N) v.x = wp[0];
          if (gc+1 < N) v.y = wp[1];
          if (gc+2 < N) v.z = wp[2];
          if (gc+3 < N) v.w = wp[3];
        }
      }
      *(float4*)(Ws + kk*68 + cc) = v;
    }
    __syncthreads();
    #pragma unroll
    for (int j = 0; j < 32; ++j){
      float4 a = *(const float4*)(As + j*68 + mq);
      float4 w = *(const float4*)(Ws + j*68 + cq);
      acc[ 0]+=a.x*w.x; acc[ 1]+=a.x*w.y; acc[ 2]+=a.x*w.z; acc[ 3]+=a.x*w.w;
      acc[ 4]+=a.y*w.x; acc[ 5]+=a.y*w.y; acc[ 6]+=a.y*w.z; acc[ 7]+=a.y*w.w;
      acc[ 8]+=a.z*w.x; acc[ 9]+=a.z*w.y; acc[10]+=a.z*w.z; acc[11]+=a.z*w.w;
      acc[12]+=a.w*w.x; acc[13]+=a.w*w.y; acc[14]+=a.w*w.z; acc[15]+=a.w*w.w;
    }
    __syncthreads();
  }
  #pragma unroll
  for (int i = 0; i < 4; ++i){
    int gm = m0 + mq + i;
    if (gm >= M) continue;
    #pragma unroll
    for (int j = 0; j < 4; ++j){
      int gc = c0 + cq + j;
      if (gc >= N) continue;
      C[(size_t)gm*N + gc] = acc[i*4+j] + (bias ? bias[gc] : 0.f);
    }
  }
}

// ---------------- weight prep (unchanged) ----------------
__global__ __launch_bounds__(256) void wprep_gemm(
    const float* __restrict__ Wp, const float* __restrict__ Win,
    const float* __restrict__ Wout, const float* __restrict__ Wo,
    const float* __restrict__ bp, const float* __restrict__ b_in,
    const float* __restrict__ bout, const float* __restrict__ bo,
    ushort_t* __restrict__ WtkH, ushort_t* __restrict__ WtkL,
    ushort_t* __restrict__ WtvH, ushort_t* __restrict__ WtvL,
    ushort_t* __restrict__ WtqH, ushort_t* __restrict__ WtqL,
    float* __restrict__ Wpk, float* __restrict__ Wpv, float* __restrict__ Wco,
    float* __restrict__ bpq, float* __restrict__ bpk, float* __restrict__ bpv, float* __restrict__ bco){
  __shared__ float As[32*68];
  __shared__ float Ws[32*68];
  int z = blockIdx.z;
  int t = threadIdx.x;
  if (z == 4){
    int flat = (blockIdx.x*5 + blockIdx.y)*256 + t;
    if (flat < 264){
      float a = b_in[flat];
      for (int k = 0; k < 264; ++k) a += bp[k]*Win[(size_t)k*792 + flat];
      bpq[flat] = a;
    } else if (flat < 528){
      int c = flat - 264;
      float a = b_in[264 + c];
      for (int k = 0; k < 264; ++k) a += bp[k]*Win[(size_t)k*792 + 264 + c];
      bpk[c] = a;
    } else if (flat < 792){
      int c = flat - 528;
      float a = b_in[528 + c];
      for (int k = 0; k < 264; ++k) a += bp[k]*Win[(size_t)k*792 + 528 + c];
      bpv[c] = a;
    } else if (flat < 1048){
      int c = flat - 792;
      float a = bo[c];
      for (int k = 0; k < 264; ++k) a += bout[k]*Wo[(size_t)k*256 + c];
      bco[c] = a;
    }
    return;
  }
  const float* A = (z < 3) ? Wp : Wout;
  const float* W = (z < 3) ? Win : Wo;
  const int M = (z < 3) ? 256 : 264;
  const int K = 264;
  const int N = (z < 3) ? 264 : 256;
  const int ldw = (z < 3) ? 792 : 256;
  const int woff = (z == 0) ? 264 : (z == 1) ? 528 : 0;
  int m0 = blockIdx.x*64, c0 = blockIdx.y*64;
  int mq = (t & 15)*4, cq = (t >> 4)*4;
  float acc[16];
  #pragma unroll
  for (int i = 0; i < 16; ++i) acc[i] = 0.f;
  for (int k0 = 0; k0 < K; k0 += 32){
    #pragma unroll
    for (int i = 0; i < 2; ++i){
      int idx = t + 256*i;
      int row = idx >> 3, kk = (idx & 7)*4;
      int gm = m0 + row, gk = k0 + kk;
      float x=0.f, y=0.f, z2=0.f, w=0.f;
      if (gm < M){
        const float* ap = A + (size_t)gm*K + gk;
        if (gk + 3 < K){ float4 v = *(const float4*)ap; x=v.x; y=v.y; z2=v.z; w=v.w; }
        else {
          if (gk   < K) x = ap[0];
          if (gk+1 < K) y = ap[1];
          if (gk+2 < K) z2 = ap[2];
          if (gk+3 < K) w = ap[3];
        }
      }
      As[(kk+0)*68+row]=x; As[(kk+1)*68+row]=y; As[(kk+2)*68+row]=z2; As[(kk+3)*68+row]=w;
    }
    #pragma unroll
    for (int i = 0; i < 2; ++i){
      int idx = t + 256*i;
      int kk = idx >> 4, cc = (idx & 15)*4;
      int gk = k0 + kk, gc = c0 + cc;
      float4 v = make_float4(0.f,0.f,0.f,0.f);
      if (gk < K){
        const float* wp = W + (size_t)gk*ldw + woff + gc;
        if (gc + 3 < N) v = *(const float4*)wp;
        else {
          if (gc   < N) v.x = wp[0];
          if (gc+1 < N) v.y = wp[1];
          if (gc+2 < N) v.z = wp[2];
          if (gc+3 < N) v.w = wp[3];
        }
      }
      *(float4*)(Ws + kk*68 + cc) = v;
    }
    __syncthreads();
    #pragma unroll
    for (int j = 0; j < 32; ++j){
      float4 a = *(const float4*)(As + j*68 + mq);
      float4 w = *(const float4*)(Ws + j*68 + cq);
      acc[ 0]+=a.x*w.x; acc[ 1]+=a.x*w.y; acc[ 2]+=a.x*w.z; acc[ 3]+=a.x*w.w;
      acc[ 4]+=a.y*w.x; acc[ 5]+=a.y*w.y; acc[ 6]+=a.y*w.z; acc[ 7]+=a.y*w.w;
      acc[ 8]+=a.z*w.x; acc[ 9]+=a.z*w.y; acc[10]+=a.z*w.z; acc[11]+=a.z*w.w;
      acc[12]+=a.w*w.x; acc[13]+=a.w*w.y; acc[14]+=a.w*w.z; acc[15]+=a.w*w.w;
    }
    __syncthreads();
  }
  if (z < 3){
    ushort_t* WH = (z==0) ? WtkH : (z==1) ? WtvH : WtqH;
    ushort_t* WL = (z==0) ? WtkL : (z==1) ? WtvL : WtqL;
    float* Wf = (z==0) ? Wpk : (z==1) ? Wpv : nullptr;
    #pragma unroll
    for (int i = 0; i < 4; ++i){
      int gm = m0 + mq + i;
      if (gm >= 256) continue;
      #pragma unroll
      for (int j = 0; j < 4; ++j){
        int gc = c0 + cq + j;
        float r = acc[i*4+j];
        ushort_t hh, ll; split2(r, hh, ll);
        WH[(size_t)gc*256 + gm] = hh;
        WL[(size_t)gc*256 + gm] = ll;
        if (Wf && gc < 264) Wf[(size_t)gm*264 + gc] = r;
      }
    }
  } else {
    #pragma unroll
    for (int i = 0; i < 4; ++i){
      int gm = m0 + mq + i;
      if (gm >= 264) continue;
      #pragma unroll
      for (int j = 0; j < 4; ++j){
        int gc = c0 + cq + j;
        if (gc < 256) Wco[(size_t)gm*256 + gc] = acc[i*4+j];
      }
    }
  }
}

// ---------------- unified big MFMA kernel: async staging, row-major 64B-row LDS ----------------
__global__ __launch_bounds__(256, 4) void big_mfma(
    const ushort_t* __restrict__ FH, const ushort_t* __restrict__ FL,
    const ushort_t* __restrict__ MKH, const ushort_t* __restrict__ MKL,
    const ushort_t* __restrict__ MVH, const ushort_t* __restrict__ MVL,
    const ushort_t* __restrict__ WtqH, const ushort_t* __restrict__ WtqL,
    const ushort_t* __restrict__ WtkH, const ushort_t* __restrict__ WtkL,
    const ushort_t* __restrict__ WtvH, const ushort_t* __restrict__ WtvL,
    const float* __restrict__ bpq, const float* __restrict__ bpk, const float* __restrict__ bpv,
    const float* __restrict__ k2,
    float* __restrict__ qh, ushort_t* __restrict__ khH, ushort_t* __restrict__ khL,
    ushort_t* __restrict__ VtGH, ushort_t* __restrict__ VtGL, unsigned* __restrict__ minD2){
  int z = blockIdx.z;
  int bx = blockIdx.x, by = blockIdx.y;
  if (z == 0 && bx >= 4) return;
  if (z != 3 && by >= 5) return;
  __shared__ ushort_t AsH[128*32];
  __shared__ ushort_t AsL[128*32];
  __shared__ ushort_t BsH[64*32];
  __shared__ ushort_t BsL[64*32];
  __shared__ unsigned sminU[64];
  const ushort_t* AH = (z == 0) ? FH : (z == 2) ? MVH : MKH;
  const ushort_t* AL = (z == 0) ? FL : (z == 2) ? MVL : MKL;
  const ushort_t* BH = (z == 0) ? WtqH : (z == 1) ? WtkH : (z == 2) ? WtvH : FH;
  const ushort_t* BL = (z == 0) ? WtqL : (z == 1) ? WtkL : WtvL;
  const float* bias = (z == 0) ? bpq : (z == 1) ? bpk : bpv;
  int t = threadIdx.x;
  int m0 = bx*128, n0 = by*64;
  int lane = t & 63, w = t >> 6;
  int wm = (w & 1)*64, wn = (w >> 1)*32;
  int l15 = lane & 15, q = lane >> 4;
  if (z == 3 && t < 64) sminU[t] = 0xFFFFFFFFu;
  v4f acc[4][2];
  #pragma unroll
  for (int i = 0; i < 4; ++i)
    #pragma unroll
    for (int j = 0; j < 2; ++j) acc[i][j] = (v4f){0.f,0.f,0.f,0.f};

  for (int k0 = 0; k0 < 256; k0 += 32){
    // async stage A: 512 units (128 rows x 4 ch of 16B) -> 2 calls/wave/array
    #pragma unroll
    for (int c = 0; c < 2; ++c){
      int u0 = (c*4 + w)*64;
      int u  = u0 + lane;
      int row = u >> 2, ch = u & 3;
      gl2lds16(AH + (size_t)(m0+row)*256 + k0 + ch*8, AsH + (size_t)u0*8);
      if (z < 3) gl2lds16(AL + (size_t)(m0+row)*256 + k0 + ch*8, AsL + (size_t)u0*8);
    }
    // async stage B: 256 units -> 1 call/wave/array
    {
      int u = w*64 + lane;
      int row = u >> 2, ch = u & 3;
      gl2lds16(BH + (size_t)(n0+row)*256 + k0 + ch*8, BsH + (size_t)w*512);
      if (z < 3) gl2lds16(BL + (size_t)(n0+row)*256 + k0 + ch*8, BsL + (size_t)w*512);
    }
    __syncthreads();
    if (z < 3){
      v8s aH[4], aL[4], bH[2], bL[2];
      #pragma unroll
      for (int im = 0; im < 4; ++im){
        aH[im] = *(const v8s*)(AsH + (wm + im*16 + l15)*32 + q*8);
        aL[im] = *(const v8s*)(AsL + (wm + im*16 + l15)*32 + q*8);
      }
      #pragma unroll
      for (int jn = 0; jn < 2; ++jn){
        bH[jn] = *(const v8s*)(BsH + (wn + jn*16 + l15)*32 + q*8);
        bL[jn] = *(const v8s*)(BsL + (wn + jn*16 + l15)*32 + q*8);
      }
      #pragma unroll
      for (int im = 0; im < 4; ++im)
        #pragma unroll
        for (int jn = 0; jn < 2; ++jn){
          acc[im][jn] = __builtin_amdgcn_mfma_f32_16x16x32_bf16(aH[im], bH[jn], acc[im][jn], 0, 0, 0);
          acc[im][jn] = __builtin_amdgcn_mfma_f32_16x16x32_bf16(aH[im], bL[jn], acc[im][jn], 0, 0, 0);
          acc[im][jn] = __builtin_amdgcn_mfma_f32_16x16x32_bf16(aL[im], bH[jn], acc[im][jn], 0, 0, 0);
        }
    } else {
      v8s aH[4], bH[2];
      #pragma unroll
      for (int im = 0; im < 4; ++im) aH[im] = *(const v8s*)(AsH + (wm + im*16 + l15)*32 + q*8);
      #pragma unroll
      for (int jn = 0; jn < 2; ++jn) bH[jn] = *(const v8s*)(BsH + (wn + jn*16 + l15)*32 + q*8);
      #pragma unroll
      for (int im = 0; im < 4; ++im)
        #pragma unroll
        for (int jn = 0; jn < 2; ++jn)
          acc[im][jn] = __builtin_amdgcn_mfma_f32_16x16x32_bf16(aH[im], bH[jn], acc[im][jn], 0, 0, 0);
    }
    __syncthreads();
  }

  if (z == 3){
    float kk[4][4];
    #pragma unroll
    for (int im = 0; im < 4; ++im)
      #pragma unroll
      for (int r = 0; r < 4; ++r) kk[im][r] = k2[m0 + wm + im*16 + q*4 + r];
    #pragma unroll
    for (int jn = 0; jn < 2; ++jn){
      float mv = INFINITY;
      #pragma unroll
      for (int im = 0; im < 4; ++im)
        #pragma unroll
        for (int r = 0; r < 4; ++r)
          mv = fminf(mv, kk[im][r] - 2.f*acc[im][jn][r]);
      mv = fminf(mv, __shfl_xor(mv, 16, 64));
      mv = fminf(mv, __shfl_xor(mv, 32, 64));
      if (q == 0) atomicMin(&sminU[wn + jn*16 + l15], fenc(mv));
    }
    __syncthreads();
    if (t < 64) atomicMin(&minD2[n0 + t], sminU[t]);
    return;
  }
  #pragma unroll
  for (int im = 0; im < 4; ++im){
    #pragma unroll
    for (int jn = 0; jn < 2; ++jn){
      int n = n0 + wn + jn*16 + l15;
      if (n >= 264) continue;
      float bv = bias[n];
      int mb = m0 + wm + im*16 + q*4;
      if (z == 0){
        #pragma unroll
        for (int r = 0; r < 4; ++r) qh[(size_t)(mb+r)*264 + n] = acc[im][jn][r] + bv;
      } else if (z == 1){
        int hh = n/33, dd = n - hh*33;
        int col = hh*40 + dd;
        #pragma unroll
        for (int r = 0; r < 4; ++r){
          ushort_t sh, sl; split2(acc[im][jn][r] + bv, sh, sl);
          khH[(size_t)(mb+r)*320 + col] = sh;
          khL[(size_t)(mb+r)*320 + col] = sl;
        }
      } else {
        int hh = n/33, dd = n - hh*33;
        size_t rowb = (size_t)(hh*48 + dd)*16384 + mb;
        ushort4 hv, lv;
        split2(acc[im][jn][0] + bv, hv.x, lv.x);
        split2(acc[im][jn][1] + bv, hv.y, lv.y);
        split2(acc[im][jn][2] + bv, hv.z, lv.z);
        split2(acc[im][jn][3] + bv, hv.w, lv.w);
        *(ushort4*)(VtGH + rowb) = hv;
        *(ushort4*)(VtGL + rowb) = lv;
      }
    }
  }
}

// ---------------- eviction scan (unchanged) ----------------
#define SCAN_CAP 1024
__global__ __launch_bounds__(1024) void scan_kernel(
    const float* __restrict__ mem_surprise, const float* __restrict__ mem_ages,
    const unsigned* __restrict__ minD2, const float* __restrict__ f2, const float* __restrict__ gn,
    float* __restrict__ parr, int* __restrict__ slotForB, int* __restrict__ lastB){
  __shared__ unsigned hist[2048];
  __shared__ float candV[SCAN_CAP];
  __shared__ int   candI[SCAN_CAP];
  __shared__ float tv[1024];
  __shared__ int   ti[1024];
  __shared__ float ssur[512];
  __shared__ int   smemz[512];
  __shared__ int   wtot[16];
  __shared__ int   sh_misc[8];
  int t = threadIdx.x;

  int mem = 0;
  if (t < 512){
    float d2 = fdec(minD2[t]) + f2[t];
    float s = gn[t]*sqrtf(fmaxf(d2, 0.f));
    ssur[t] = s;
    mem = (s > 0.1f) ? 1 : 0;
    smemz[t] = mem;
  }
  const float LN095 = -0.05129329438755058f;
  #pragma unroll
  for (int j = 0; j < 16; ++j){
    int m = t*16 + j;
    float p = mem_surprise[m] * __expf(mem_ages[m] * LN095);
    parr[m] = p;
    lastB[m] = -1;
  }
  hist[t] = 0u; hist[t + 1024] = 0u;
  if (t < 8) sh_misc[t] = (t == 3) ? 0x7F800000 : 0;
  __syncthreads();
  #pragma unroll
  for (int j = 0; j < 16; ++j){
    int m = t*16 + j;
    unsigned key = __float_as_uint(parr[m]) >> 20;
    if (key > 2047u) key = 2047u;
    atomicAdd(&hist[key], 1u);
  }
  __syncthreads();
  if (t < 512){ ti[t] = (int)(hist[4*t] + hist[4*t+1] + hist[4*t+2] + hist[4*t+3]); }
  __syncthreads();
  if (t < 32){ int s = 0; for (int i = 0; i < 16; ++i) s += ti[16*t + i]; ti[512 + t] = s; }
  __syncthreads();
  if (t == 0){
    int cum = 0, i2 = 0;
    for (; i2 < 32; ++i2){ if (cum + ti[512+i2] >= 512) break; cum += ti[512+i2]; }
    int i1 = i2*16;
    for (;; ++i1){ if (cum + ti[i1] >= 512) break; cum += ti[i1]; }
    int bin = i1*4;
    for (;; ++bin){ if (cum + (int)hist[bin] >= 512) break; cum += (int)hist[bin]; }
    sh_misc[1] = bin;
  }
  __syncthreads();
  int threshKey = sh_misc[1];
  #pragma unroll
  for (int j = 0; j < 16; ++j){
    int m = t*16 + j;
    unsigned key = __float_as_uint(parr[m]) >> 20;
    if (key > 2047u) key = 2047u;
    if ((int)key <= threshKey){
      int pos = atomicAdd(&sh_misc[0], 1);
      if (pos < SCAN_CAP){ candV[pos] = parr[m]; candI[pos] = m; }
    }
  }
  __syncthreads();
  int cnt = sh_misc[0];
  if (t >= cnt && t < SCAN_CAP){ candV[t] = INFINITY; candI[t] = 0x7FFFFFFF; }
  __syncthreads();
  for (int ksz = 2; ksz <= SCAN_CAP; ksz <<= 1){
    for (int jj = ksz >> 1; jj > 0; jj >>= 1){
      int ixj = t ^ jj;
      if (ixj > t){
        float v1 = candV[t], v2 = candV[ixj];
        int i1 = candI[t], i2 = candI[ixj];
        bool lt21 = (v2 < v1) || (v2 == v1 && i2 < i1);
        bool lt12 = (v1 < v2) || (v1 == v2 && i1 < i2);
        bool up = ((t & ksz) == 0);
        bool sw = up ? lt21 : lt12;
        if (sw){ candV[t] = v2; candI[t] = i2; candV[ixj] = v1; candI[ixj] = i1; }
      }
      __syncthreads();
    }
  }
  int lp = 0;
  if (t < 512){
    unsigned long long mask = __ballot(mem != 0);
    int lane = t & 63;
    lp = __popcll(mask & ((1ull << lane) - 1ull));
    if (lane == 0) wtot[t >> 6] = __popcll(mask);
  }
  if (t < 512 && mem) atomicMin(&sh_misc[3], __float_as_int(ssur[t]));
  __syncthreads();
  if (t == 0){
    int ksum = 0;
    for (int wv = 0; wv < 8; ++wv) ksum += wtot[wv];
    sh_misc[4] = ksum;
    bool okf = (cnt <= SCAN_CAP) && (ksum <= cnt);
    if (okf && ksum > 0){
      float minw = __int_as_float(sh_misc[3]);
      okf = (minw > candV[ksum - 1]);
    }
    sh_misc[2] = okf ? 1 : 0;
  }
  __syncthreads();
  if (sh_misc[2] == 1){
    if (t < 512){
      int wv = t >> 6, base = 0;
      for (int i = 0; i < wv; ++i) base += wtot[i];
      int slot = -1;
      if (mem){ slot = candI[base + lp]; atomicMax(&lastB[slot], t); }
      slotForB[t] = slot;
    }
  } else {
    for (int b = 0; b < 512; ++b){
      float bv = parr[t*16]; int bi = t*16;
      #pragma unroll
      for (int j = 1; j < 16; ++j){
        float v = parr[t*16 + j];
        if (v < bv){ bv = v; bi = t*16 + j; }
      }
      tv[t] = bv; ti[t] = bi;
      __syncthreads();
      for (int s = 512; s > 0; s >>= 1){
        if (t < s){
          float v2 = tv[t+s]; int i2 = ti[t+s];
          if (v2 < tv[t] || (v2 == tv[t] && i2 < ti[t])){ tv[t] = v2; ti[t] = i2; }
        }
        __syncthreads();
      }
      int slot = ti[0];
      int memb = smemz[b];
      if (t == 0) slotForB[b] = memb ? slot : -1;
      if (memb && t == (slot >> 4)) parr[slot] = ssur[b];
      __syncthreads();
    }
    if (t < 512){ int s = slotForB[t]; if (s >= 0) atomicMax(&lastB[s], t); }
  }
}

// ---------------- fixup written slots (unchanged) ----------------
__global__ __launch_bounds__(64) void fixup_rows(const int* __restrict__ slotForB, const int* __restrict__ lastB,
                                                 const float* __restrict__ newK, const float* __restrict__ newV,
                                                 const float* __restrict__ Wpk, const float* __restrict__ Wpv,
                                                 const float* __restrict__ bpk, const float* __restrict__ bpv,
                                                 ushort_t* __restrict__ khH, ushort_t* __restrict__ khL,
                                                 ushort_t* __restrict__ VtH, ushort_t* __restrict__ VtL){
  int b = blockIdx.x;
  int slot = slotForB[b];
  if (slot < 0) return;
  if (lastB[slot] != b) return;
  __shared__ float kr[256], vr[256];
  int t = threadIdx.x;
  *(float4*)(kr + t*4) = *(const float4*)(newK + (size_t)b*256 + t*4);
  *(float4*)(vr + t*4) = *(const float4*)(newV + (size_t)b*256 + t*4);
  __syncthreads();
  for (int c = t; c < 264; c += 64){
    float aK = bpk[c], aV = bpv[c];
    for (int k = 0; k < 256; ++k){
      aK += kr[k]*Wpk[(size_t)k*264 + c];
      aV += vr[k]*Wpv[(size_t)k*264 + c];
    }
    int hh = c/33, dd = c - hh*33;
    ushort_t sh, sl;
    split2(aK, sh, sl);
    khH[(size_t)slot*320 + hh*40 + dd] = sh;
    khL[(size_t)slot*320 + hh*40 + dd] = sl;
    split2(aV, sh, sl);
    VtH[(size_t)(hh*48 + dd)*16384 + slot] = sh;
    VtL[(size_t)(hh*48 + dd)*16384 + slot] = sl;
  }
}

// ---------------- MFMA flash attention: async staging, register softmax ----------------
// grid (h=8, bt=8, ms=16), 4 waves, wave w owns b rows 16w..16w+15
__global__ __launch_bounds__(256, 4) void attn_mfma(
    const float* __restrict__ qh, const ushort_t* __restrict__ khH, const ushort_t* __restrict__ khL,
    const ushort_t* __restrict__ VtGH, const ushort_t* __restrict__ VtGL,
    float* __restrict__ pm, float* __restrict__ pl, float* __restrict__ pctx){
  const int h = blockIdx.x, bt = blockIdx.y, ms = blockIdx.z;
  const int b0 = bt*64, mbase = ms*(16384/ATTN_MS);
  const int t = threadIdx.x, lane = t & 63, w = t >> 6;
  const int l15 = lane & 15, q = lane >> 4;
  __shared__ ushort_t KH[64*32], KL[64*32];       // row-major, 64B rows
  __shared__ ushort_t VsH[48*64], VsL[48*64];     // row-major 128B rows, XOR-chunk swizzle
  __shared__ ushort_t PH[4*16*72], PL[4*16*72];
  __shared__ float k32f[64];
  const float scale = 0.17407765595569785f; // 1/sqrt(33)

  const int bq = b0 + 16*w + l15;
  U8 qHU, qLU;
  {
    const float* qp = qh + (size_t)bq*264 + h*33 + q*8;
    #pragma unroll
    for (int j = 0; j < 8; ++j) split2(qp[j]*scale, qHU.u[j], qLU.u[j]);
  }
  const v8s bQH = qHU.v, bQL = qLU.v;
  const float q32v = qh[(size_t)bq*264 + h*33 + 32]*scale;
  float rMv = -INFINITY, rLv = 0.f;
  v4f cacc[3];
  #pragma unroll
  for (int i = 0; i < 3; ++i) cacc[i] = (v4f){0.f,0.f,0.f,0.f};
  ushort_t* PHw = PH + w*16*72;
  ushort_t* PLw = PL + w*16*72;

  for (int mt = 0; mt < 16384/ATTN_MS/64; ++mt){
    const int m0 = mbase + mt*64;
    __syncthreads();   // prior-iter LDS reads complete
    // K: 256 units (64 rows x 4 ch) -> 1 call/wave/array
    {
      int u = w*64 + lane;
      int row = u >> 2, ch = u & 3;
      gl2lds16(khH + (size_t)(m0+row)*320 + h*40 + ch*8, KH + (size_t)w*512);
      gl2lds16(khL + (size_t)(m0+row)*320 + h*40 + ch*8, KL + (size_t)w*512);
    }
    if (t < 64)
      k32f[t] = bf2f(khH[(size_t)(m0+t)*320 + h*40 + 32]) + bf2f(khL[(size_t)(m0+t)*320 + h*40 + 32]);
    // V: 384 units/array (48 rows x 8 ch), XOR swizzle ch^= (dd&7)
    #pragma unroll
    for (int c = 0; c < 2; ++c){
      if (c == 0 || w < 2){
        int u0 = c*256 + w*64;
        int u = u0 + lane;
        int dd = u >> 3, chl = u & 7;
        int gch = chl ^ (dd & 7);
        size_t gi = (size_t)(h*48 + dd)*16384 + m0 + gch*8;
        gl2lds16(VtGH + gi, VsH + (size_t)u0*8);
        gl2lds16(VtGL + gi, VsL + (size_t)u0*8);
      }
    }
    __syncthreads();   // staging visible
    // ---- QK^T ----
    v4f s4[4];
    #pragma unroll
    for (int im = 0; im < 4; ++im){
      v8s aH = *(const v8s*)(KH + (im*16 + l15)*32 + q*8);
      v8s aL = *(const v8s*)(KL + (im*16 + l15)*32 + q*8);
      v4f sv = (v4f){0.f,0.f,0.f,0.f};
      sv = __builtin_amdgcn_mfma_f32_16x16x32_bf16(aH, bQH, sv, 0, 0, 0);
      sv = __builtin_amdgcn_mfma_f32_16x16x32_bf16(aH, bQL, sv, 0, 0, 0);
      sv = __builtin_amdgcn_mfma_f32_16x16x32_bf16(aL, bQH, sv, 0, 0, 0);
      s4[im] = sv;
    }
    #pragma unroll
    for (int im = 0; im < 4; ++im)
      #pragma unroll
      for (int r = 0; r < 4; ++r) s4[im][r] += k32f[im*16 + q*4 + r]*q32v;
    // ---- online softmax (register state) ----
    float mx = -INFINITY;
    #pragma unroll
    for (int im = 0; im < 4; ++im)
      #pragma unroll
      for (int r = 0; r < 4; ++r) mx = fmaxf(mx, s4[im][r]);
    mx = fmaxf(mx, __shfl_xor(mx, 16, 64));
    mx = fmaxf(mx, __shfl_xor(mx, 32, 64));
    float nm = fmaxf(rMv, mx);
    float alf = __expf(rMv - nm);
    rMv = nm;
    float sm = 0.f;
    #pragma unroll
    for (int im = 0; im < 4; ++im){
      v4f p;
      #pragma unroll
      for (int r = 0; r < 4; ++r){ p[r] = __expf(s4[im][r] - nm); sm += p[r]; }
      ushort4 hv, lv;
      split2(p[0], hv.x, lv.x); split2(p[1], hv.y, lv.y);
      split2(p[2], hv.z, lv.z); split2(p[3], hv.w, lv.w);
      *(ushort4*)(PHw + l15*72 + im*16 + q*4) = hv;
      *(ushort4*)(PLw + l15*72 + im*16 + q*4) = lv;
    }
    sm += __shfl_xor(sm, 16, 64);
    sm += __shfl_xor(sm, 32, 64);
    rLv = rLv*alf + sm;
    #pragma unroll
    for (int r = 0; r < 4; ++r){
      float ar = __shfl(alf, q*4 + r, 64);
      cacc[0][r] *= ar; cacc[1][r] *= ar; cacc[2][r] *= ar;
    }
    // ---- PV ----
    #pragma unroll
    for (int ks = 0; ks < 2; ++ks){
      v8s paH = *(const v8s*)(PHw + l15*72 + ks*32 + q*8);
      v8s paL = *(const v8s*)(PLw + l15*72 + ks*32 + q*8);
      #pragma unroll
      for (int tile = 0; tile < 3; ++tile){
        int vrow = tile*16 + l15;
        int mch = (ks*4 + q) ^ (l15 & 7);
        v8s vbH = *(const v8s*)(VsH + vrow*64 + mch*8);
        v8s vbL = *(const v8s*)(VsL + vrow*64 + mch*8);
        cacc[tile] = __builtin_amdgcn_mfma_f32_16x16x32_bf16(paH, vbH, cacc[tile], 0, 0, 0);
        cacc[tile] = __builtin_amdgcn_mfma_f32_16x16x32_bf16(paH, vbL, cacc[tile], 0, 0, 0);
        cacc[tile] = __builtin_amdgcn_mfma_f32_16x16x32_bf16(paL, vbH, cacc[tile], 0, 0, 0);
      }
    }
  }
  int g = (h*8 + bt)*ATTN_MS + ms;
  if (q == 0){
    pm[(size_t)g*64 + 16*w + l15] = rMv;
    pl[(size_t)g*64 + 16*w + l15] = rLv;
  }
  #pragma unroll
  for (int tile = 0; tile < 3; ++tile){
    int d = tile*16 + l15;
    if (d < 33){
      #pragma unroll
      for (int r = 0; r < 4; ++r)
        pctx[((size_t)g*64 + 16*w + q*4 + r)*33 + d] = cacc[tile][r];
    }
  }
}

__global__ __launch_bounds__(256) void combine_kernel(const float* __restrict__ pm, const float* __restrict__ pl,
                                                      const float* __restrict__ pctx, float* __restrict__ ctxf){
  int idx = blockIdx.x*256 + threadIdx.x;
  if (idx >= 512*264) return;
  int b = idx / 264, c = idx - b*264;
  int h = c / 33, d = c - h*33;
  int bt = b >> 6, bl = b & 63;
  int g0 = (h*8 + bt)*ATTN_MS;
  float gm = -INFINITY;
  for (int ms = 0; ms < ATTN_MS; ++ms) gm = fmaxf(gm, pm[(g0+ms)*64 + bl]);
  float L = 0.f, cv = 0.f;
  for (int ms = 0; ms < ATTN_MS; ++ms){
    int gg = (g0+ms)*64 + bl;
    float w = __expf(pm[gg] - gm);
    L += pl[gg]*w;
    cv += pctx[(size_t)gg*33 + d]*w;
  }
  ctxf[idx] = cv / L;
}

// ---------------- host ----------------
extern "C" void kernel_launch(void* const* d_in, const int* in_sizes, int n_in,
                              void* d_out, int out_size, void* d_ws, size_t ws_size,
                              hipStream_t stream){
  (void)in_sizes; (void)n_in; (void)out_size; (void)ws_size;
  const float* features     = (const float*)d_in[0];
  const float* gradients    = (const float*)d_in[1];
  const float* mem_keys     = (const float*)d_in[2];
  const float* mem_values   = (const float*)d_in[3];
  const float* mem_ages     = (const float*)d_in[4];
  const float* mem_surprise = (const float*)d_in[5];
  const float* Wk   = (const float*)d_in[6];
  const float* bk   = (const float*)d_in[7];
  const float* Wv   = (const float*)d_in[8];
  const float* bv   = (const float*)d_in[9];
  const float* Wp   = (const float*)d_in[10];
  const float* bp   = (const float*)d_in[11];
  const float* Win  = (const float*)d_in[12];
  const float* b_in = (const float*)d_in[13];
  const float* Wout = (const float*)d_in[14];
  const float* bout = (const float*)d_in[15];
  const float* Wo   = (const float*)d_in[16];
  const float* bo   = (const float*)d_in[17];
  float* out = (float*)d_out;

  float* w = (float*)d_ws;
  size_t off = 0;
  auto alloc = [&](size_t n)->float*{ float* p = w + off; off += (n + 63) & ~(size_t)63; return p; };
  float*    k2       = alloc(16384);
  unsigned* minD2    = (unsigned*)alloc(512);
  float*    f2       = alloc(512);
  float*    gn       = alloc(512);
  int*      slotForB = (int*)alloc(512);
  int*      lastB    = (int*)alloc(16384);
  float*    parr     = alloc(16384);
  float*    newK     = alloc((size_t)512*256);
  float*    newV     = alloc((size_t)512*256);
  float*    qh       = alloc((size_t)512*264);
  ushort_t* khH      = (ushort_t*)alloc((size_t)16384*320/2);
  ushort_t* khL      = (ushort_t*)alloc((size_t)16384*320/2);
  ushort_t* VtGH     = (ushort_t*)alloc((size_t)8*48*16384/2);
  ushort_t* VtGL     = (ushort_t*)alloc((size_t)8*48*16384/2);
  float*    MKbase   = alloc((size_t)16384*256/2*2);
  ushort_t* MKH      = (ushort_t*)MKbase;
  ushort_t* MKL      = (ushort_t*)(MKbase + (size_t)16384*256/2);
  float*    MVbase   = alloc((size_t)16384*256/2*2);
  ushort_t* MVH      = (ushort_t*)MVbase;
  ushort_t* MVL      = (ushort_t*)(MVbase + (size_t)16384*256/2);
  ushort_t* FH       = (ushort_t*)alloc((size_t)512*256/2);
  ushort_t* FL       = (ushort_t*)alloc((size_t)512*256/2);
  float*    Wpk      = alloc((size_t)256*264);
  float*    Wpv      = alloc((size_t)256*264);
  float*    Wco      = alloc((size_t)264*256);
  ushort_t* WtkH     = (ushort_t*)alloc((size_t)320*256/2);
  ushort_t* WtkL     = (ushort_t*)alloc((size_t)320*256/2);
  ushort_t* WtvH     = (ushort_t*)alloc((size_t)320*256/2);
  ushort_t* WtvL     = (ushort_t*)alloc((size_t)320*256/2);
  ushort_t* WtqH     = (ushort_t*)alloc((size_t)320*256/2);
  ushort_t* WtqL     = (ushort_t*)alloc((size_t)320*256/2);
  float*    bpq      = alloc(264);
  float*    bpk      = alloc(264);
  float*    bpv      = alloc(264);
  float*    bco      = alloc(256);
  // aliases: MK region (dead after big_mfma) hosts pm/pl/ctxf; MV region hosts pctx
  float*    pm       = MKbase;
  float*    pl       = MKbase + (size_t)ATTN_MS*64*64;
  float*    ctxf     = pl + (size_t)ATTN_MS*64*64;
  float*    pctx     = MVbase;

  prep_all<<<dim3(4096,4), 256, 0, stream>>>(features, gradients, mem_keys, mem_values,
      FH, FL, MKH, MKL, MVH, MVL, k2, f2, gn, minD2, VtGH, VtGL);

  wprep_gemm<<<dim3(5,5,5), 256, 0, stream>>>(Wp, Win, Wout, Wo, bp, b_in, bout, bo,
      WtkH, WtkL, WtvH, WtvL, WtqH, WtqL, Wpk, Wpv, Wco, bpq, bpk, bpv, bco);

  gemm_bias<<<dim3(8,4,2), 256, 0, stream>>>(features, Wk, bk, newK, Wv, bv, newV, 512, 256, 256, 256, 0);

  big_mfma<<<dim3(128,8,4), 256, 0, stream>>>(FH, FL, MKH, MKL, MVH, MVL,
      WtqH, WtqL, WtkH, WtkL, WtvH, WtvL, bpq, bpk, bpv, k2,
      qh, khH, khL, VtGH, VtGL, minD2);

  scan_kernel<<<1, 1024, 0, stream>>>(mem_surprise, mem_ages, minD2, f2, gn, parr, slotForB, lastB);
  fixup_rows<<<512, 64, 0, stream>>>(slotForB, lastB, newK, newV, Wpk, Wpv, bpk, bpv, khH, khL, VtGH, VtGL);

  attn_mfma<<<dim3(8,8,ATTN_MS), 256, 0, stream>>>(qh, khH, khL, VtGH, VtGL, pm, pl, pctx);
  combine_kernel<<<528, 256, 0, stream>>>(pm, pl, pctx, ctxf);
  gemm_bias<<<dim3(8,4,1), 256, 0, stream>>>(ctxf, Wco, bco, out, Wco, bco, out, 512, 264, 256, 256, 0);
}

// Round 6
// 346.234 us; speedup vs baseline: 3.2302x; 1.1518x over previous
//
#include <hip/hip_runtime.h>
#include <math.h>
#include <stdint.h>

typedef unsigned short ushort_t;
typedef float v4f __attribute__((ext_vector_type(4)));
typedef short v8s __attribute__((ext_vector_type(8)));

#define ATTN_MS 16

// ---------------- helpers ----------------
__device__ __forceinline__ unsigned fenc(float f){
  unsigned b = __float_as_uint(f);
  return (b & 0x80000000u) ? ~b : (b | 0x80000000u);
}
__device__ __forceinline__ float fdec(unsigned u){
  unsigned b = (u & 0x80000000u) ? (u ^ 0x80000000u) : ~u;
  return __uint_as_float(b);
}
__device__ __forceinline__ ushort_t bf16_rne(float x){
  unsigned u = __float_as_uint(x);
  unsigned r = u + 0x7FFFu + ((u >> 16) & 1u);
  return (ushort_t)(r >> 16);
}
__device__ __forceinline__ void split2(float x, ushort_t& h, ushort_t& l){
  unsigned u = __float_as_uint(x);
  unsigned r = u + 0x7FFFu + ((u >> 16) & 1u);
  h = (ushort_t)(r >> 16);
  float hf = __uint_as_float(r & 0xFFFF0000u);
  l = bf16_rne(x - hf);
}
union U8 { v8s v; ushort_t u[8]; };

// async global->LDS, 16B per lane; lds dest = wave-uniform base + lane*16
__device__ __forceinline__ void gl2lds16(const void* g, void* l){
  __builtin_amdgcn_global_load_lds(
      (const __attribute__((address_space(1))) unsigned int*)(uintptr_t)g,
      (__attribute__((address_space(3))) unsigned int*)(unsigned int)(uintptr_t)l,
      16, 0, 0);
}

// ---------------- prep: split inputs to bf16 hi/lo + row stats ----------------
__global__ __launch_bounds__(256) void prep_all(
    const float* __restrict__ features, const float* __restrict__ gradients,
    const float* __restrict__ mem_keys, const float* __restrict__ mem_values,
    ushort_t* __restrict__ FH, ushort_t* __restrict__ FL,
    ushort_t* __restrict__ MKH, ushort_t* __restrict__ MKL,
    ushort_t* __restrict__ MVH, ushort_t* __restrict__ MVL,
    float* __restrict__ k2, float* __restrict__ f2, float* __restrict__ gn,
    unsigned* __restrict__ minD2){
  int y = blockIdx.y, bx = blockIdx.x, t = threadIdx.x;
  int wid = t >> 6, lane = t & 63;
  int row = bx*4 + wid;
  if (y == 2 && bx >= 128) return;
  const float* src = (y == 0) ? mem_keys : (y == 1) ? mem_values : features;
  float4 v = *(const float4*)(src + (size_t)row*256 + lane*4);
  ushort_t h0,h1,h2,h3,l0,l1,l2,l3;
  split2(v.x,h0,l0); split2(v.y,h1,l1); split2(v.z,h2,l2); split2(v.w,h3,l3);
  uint2 hp = make_uint2((unsigned)h0 | ((unsigned)h1<<16), (unsigned)h2 | ((unsigned)h3<<16));
  uint2 lp = make_uint2((unsigned)l0 | ((unsigned)l1<<16), (unsigned)l2 | ((unsigned)l3<<16));
  ushort_t* H = (y == 0) ? MKH : (y == 1) ? MVH : FH;
  ushort_t* L = (y == 0) ? MKL : (y == 1) ? MVL : FL;
  *(uint2*)(H + (size_t)row*256 + lane*4) = hp;
  *(uint2*)(L + (size_t)row*256 + lane*4) = lp;
  if (y == 1) return;
  float s = v.x*v.x + v.y*v.y + v.z*v.z + v.w*v.w;
  if (y == 0){
    for (int off = 32; off > 0; off >>= 1) s += __shfl_down(s, off, 64);
    if (lane == 0) k2[row] = s;
  } else {
    float4 g = *(const float4*)(gradients + (size_t)row*256 + lane*4);
    float tg = g.x*g.x + g.y*g.y + g.z*g.z + g.w*g.w;
    for (int off = 32; off > 0; off >>= 1){ s += __shfl_down(s, off, 64); tg += __shfl_down(tg, off, 64); }
    if (lane == 0){ f2[row] = s; gn[row] = sqrtf(tg); minD2[row] = 0xFFFFFFFFu; }
  }
}

// ---------------- generic f32 GEMM (final output projection) ----------------
__global__ __launch_bounds__(256) void gemm_bias(const float* __restrict__ A, const float* __restrict__ W,
                                                 const float* __restrict__ bias, float* __restrict__ C,
                                                 int M, int K, int N, int ldw, int woff){
  __shared__ float As[32*68];
  __shared__ float Ws[32*68];
  int m0 = blockIdx.x*64, c0 = blockIdx.y*64;
  int t = threadIdx.x;
  int mq = (t & 15)*4, cq = (t >> 4)*4;
  float acc[16];
  #pragma unroll
  for (int i = 0; i < 16; ++i) acc[i] = 0.f;
  for (int k0 = 0; k0 < K; k0 += 32){
    #pragma unroll
    for (int i = 0; i < 2; ++i){
      int idx = t + 256*i;
      int row = idx >> 3, kk = (idx & 7)*4;
      int gm = m0 + row, gk = k0 + kk;
      float x=0.f, y=0.f, z=0.f, w=0.f;
      if (gm < M){
        const float* ap = A + (size_t)gm*K + gk;
        if (gk + 3 < K){ float4 v = *(const float4*)ap; x=v.x; y=v.y; z=v.z; w=v.w; }
        else {
          if (gk   < K) x = ap[0];
          if (gk+1 < K) y = ap[1];
          if (gk+2 < K) z = ap[2];
          if (gk+3 < K) w = ap[3];
        }
      }
      As[(kk+0)*68+row]=x; As[(kk+1)*68+row]=y; As[(kk+2)*68+row]=z; As[(kk+3)*68+row]=w;
    }
    #pragma unroll
    for (int i = 0; i < 2; ++i){
      int idx = t + 256*i;
      int kk = idx >> 4, cc = (idx & 15)*4;
      int gk = k0 + kk, gc = c0 + cc;
      float4 v = make_float4(0.f,0.f,0.f,0.f);
      if (gk < K){
        const float* wp = W + (size_t)gk*ldw + woff + gc;
        if (gc + 3 < N) v = *(const float4*)wp;
        else {
          if (gc   < N) v.x = wp[0];
          if (gc+1 < N) v.y = wp[1];
          if (gc+2 < N) v.z = wp[2];
          if (gc+3 < N) v.w = wp[3];
        }
      }
      *(float4*)(Ws + kk*68 + cc) = v;
    }
    __syncthreads();
    #pragma unroll
    for (int j = 0; j < 32; ++j){
      float4 a = *(const float4*)(As + j*68 + mq);
      float4 w = *(const float4*)(Ws + j*68 + cq);
      acc[ 0]+=a.x*w.x; acc[ 1]+=a.x*w.y; acc[ 2]+=a.x*w.z; acc[ 3]+=a.x*w.w;
      acc[ 4]+=a.y*w.x; acc[ 5]+=a.y*w.y; acc[ 6]+=a.y*w.z; acc[ 7]+=a.y*w.w;
      acc[ 8]+=a.z*w.x; acc[ 9]+=a.z*w.y; acc[10]+=a.z*w.z; acc[11]+=a.z*w.w;
      acc[12]+=a.w*w.x; acc[13]+=a.w*w.y; acc[14]+=a.w*w.z; acc[15]+=a.w*w.w;
    }
    __syncthreads();
  }
  #pragma unroll
  for (int i = 0; i < 4; ++i){
    int gm = m0 + mq + i;
    if (gm >= M) continue;
    #pragma unroll
    for (int j = 0; j < 4; ++j){
      int gc = c0 + cq + j;
      if (gc >= N) continue;
      C[(size_t)gm*N + gc] = acc[i*4+j] + (bias ? bias[gc] : 0.f);
    }
  }
}

// ---------------- weight prep pass 1 ----------------
__global__ __launch_bounds__(256) void wprep_gemm(
    const float* __restrict__ Wp, const float* __restrict__ Win,
    const float* __restrict__ Wout, const float* __restrict__ Wo,
    const float* __restrict__ bp, const float* __restrict__ b_in,
    const float* __restrict__ bout, const float* __restrict__ bo,
    ushort_t* __restrict__ WtkH, ushort_t* __restrict__ WtkL,
    ushort_t* __restrict__ WtvH, ushort_t* __restrict__ WtvL,
    ushort_t* __restrict__ WtqH, ushort_t* __restrict__ WtqL,
    float* __restrict__ Wpk, float* __restrict__ Wpv, float* __restrict__ Wco,
    float* __restrict__ bpq, float* __restrict__ bpk, float* __restrict__ bpv, float* __restrict__ bco){
  __shared__ float As[32*68];
  __shared__ float Ws[32*68];
  int z = blockIdx.z;
  int t = threadIdx.x;
  if (z == 4){
    int flat = (blockIdx.x*5 + blockIdx.y)*256 + t;
    if (flat < 264){
      float a = b_in[flat];
      for (int k = 0; k < 264; ++k) a += bp[k]*Win[(size_t)k*792 + flat];
      bpq[flat] = a;
    } else if (flat < 528){
      int c = flat - 264;
      float a = b_in[264 + c];
      for (int k = 0; k < 264; ++k) a += bp[k]*Win[(size_t)k*792 + 264 + c];
      bpk[c] = a;
    } else if (flat < 792){
      int c = flat - 528;
      float a = b_in[528 + c];
      for (int k = 0; k < 264; ++k) a += bp[k]*Win[(size_t)k*792 + 528 + c];
      bpv[c] = a;
    } else if (flat < 1048){
      int c = flat - 792;
      float a = bo[c];
      for (int k = 0; k < 264; ++k) a += bout[k]*Wo[(size_t)k*256 + c];
      bco[c] = a;
    }
    return;
  }
  const float* A = (z < 3) ? Wp : Wout;
  const float* W = (z < 3) ? Win : Wo;
  const int M = (z < 3) ? 256 : 264;
  const int K = 264;
  const int N = (z < 3) ? 264 : 256;
  const int ldw = (z < 3) ? 792 : 256;
  const int woff = (z == 0) ? 264 : (z == 1) ? 528 : 0;
  int m0 = blockIdx.x*64, c0 = blockIdx.y*64;
  int mq = (t & 15)*4, cq = (t >> 4)*4;
  float acc[16];
  #pragma unroll
  for (int i = 0; i < 16; ++i) acc[i] = 0.f;
  for (int k0 = 0; k0 < K; k0 += 32){
    #pragma unroll
    for (int i = 0; i < 2; ++i){
      int idx = t + 256*i;
      int row = idx >> 3, kk = (idx & 7)*4;
      int gm = m0 + row, gk = k0 + kk;
      float x=0.f, y=0.f, z2=0.f, w=0.f;
      if (gm < M){
        const float* ap = A + (size_t)gm*K + gk;
        if (gk + 3 < K){ float4 v = *(const float4*)ap; x=v.x; y=v.y; z2=v.z; w=v.w; }
        else {
          if (gk   < K) x = ap[0];
          if (gk+1 < K) y = ap[1];
          if (gk+2 < K) z2 = ap[2];
          if (gk+3 < K) w = ap[3];
        }
      }
      As[(kk+0)*68+row]=x; As[(kk+1)*68+row]=y; As[(kk+2)*68+row]=z2; As[(kk+3)*68+row]=w;
    }
    #pragma unroll
    for (int i = 0; i < 2; ++i){
      int idx = t + 256*i;
      int kk = idx >> 4, cc = (idx & 15)*4;
      int gk = k0 + kk, gc = c0 + cc;
      float4 v = make_float4(0.f,0.f,0.f,0.f);
      if (gk < K){
        const float* wp = W + (size_t)gk*ldw + woff + gc;
        if (gc + 3 < N) v = *(const float4*)wp;
        else {
          if (gc   < N) v.x = wp[0];
          if (gc+1 < N) v.y = wp[1];
          if (gc+2 < N) v.z = wp[2];
          if (gc+3 < N) v.w = wp[3];
        }
      }
      *(float4*)(Ws + kk*68 + cc) = v;
    }
    __syncthreads();
    #pragma unroll
    for (int j = 0; j < 32; ++j){
      float4 a = *(const float4*)(As + j*68 + mq);
      float4 w = *(const float4*)(Ws + j*68 + cq);
      acc[ 0]+=a.x*w.x; acc[ 1]+=a.x*w.y; acc[ 2]+=a.x*w.z; acc[ 3]+=a.x*w.w;
      acc[ 4]+=a.y*w.x; acc[ 5]+=a.y*w.y; acc[ 6]+=a.y*w.z; acc[ 7]+=a.y*w.w;
      acc[ 8]+=a.z*w.x; acc[ 9]+=a.z*w.y; acc[10]+=a.z*w.z; acc[11]+=a.z*w.w;
      acc[12]+=a.w*w.x; acc[13]+=a.w*w.y; acc[14]+=a.w*w.z; acc[15]+=a.w*w.w;
    }
    __syncthreads();
  }
  if (z < 3){
    ushort_t* WH = (z==0) ? WtkH : (z==1) ? WtvH : WtqH;
    ushort_t* WL = (z==0) ? WtkL : (z==1) ? WtvL : WtqL;
    float* Wf = (z==0) ? Wpk : (z==1) ? Wpv : nullptr;
    #pragma unroll
    for (int i = 0; i < 4; ++i){
      int gm = m0 + mq + i;
      if (gm >= 256) continue;
      #pragma unroll
      for (int j = 0; j < 4; ++j){
        int gc = c0 + cq + j;
        float r = acc[i*4+j];
        ushort_t hh, ll; split2(r, hh, ll);
        WH[(size_t)gc*256 + gm] = hh;
        WL[(size_t)gc*256 + gm] = ll;
        if (Wf && gc < 264) Wf[(size_t)gm*264 + gc] = r;
      }
    }
  } else {
    #pragma unroll
    for (int i = 0; i < 4; ++i){
      int gm = m0 + mq + i;
      if (gm >= 264) continue;
      #pragma unroll
      for (int j = 0; j < 4; ++j){
        int gc = c0 + cq + j;
        if (gc < 256) Wco[(size_t)gm*256 + gc] = acc[i*4+j];
      }
    }
  }
}

// ---------------- weight prep pass 2: composed write-path weights ----------------
// z=0: Wfk = Wk@Wpk -> split Wtfk ; z=1: Wfv = Wv@Wpv -> split Wtfv ; z=2: bfk,bfv
__global__ __launch_bounds__(256) void wprep2(
    const float* __restrict__ Wk, const float* __restrict__ Wv,
    const float* __restrict__ Wpk, const float* __restrict__ Wpv,
    const float* __restrict__ bk, const float* __restrict__ bv,
    const float* __restrict__ bpk, const float* __restrict__ bpv,
    ushort_t* __restrict__ WtfkH, ushort_t* __restrict__ WtfkL,
    ushort_t* __restrict__ WtfvH, ushort_t* __restrict__ WtfvL,
    float* __restrict__ bfk, float* __restrict__ bfv){
  __shared__ float As[32*68];
  __shared__ float Ws[32*68];
  int z = blockIdx.z;
  int t = threadIdx.x;
  if (z == 2){
    int flat = (blockIdx.x*5 + blockIdx.y)*256 + t;
    if (flat < 264){
      float a = bpk[flat];
      for (int k = 0; k < 256; ++k) a += bk[k]*Wpk[(size_t)k*264 + flat];
      bfk[flat] = a;
    } else if (flat < 528){
      int c = flat - 264;
      float a = bpv[c];
      for (int k = 0; k < 256; ++k) a += bv[k]*Wpv[(size_t)k*264 + c];
      bfv[c] = a;
    }
    return;
  }
  if (blockIdx.x >= 4) return;
  const float* A = z ? Wv : Wk;      // [256 x 256]
  const float* W = z ? Wpv : Wpk;    // [256 x 264]
  int m0 = blockIdx.x*64, c0 = blockIdx.y*64;
  int mq = (t & 15)*4, cq = (t >> 4)*4;
  float acc[16];
  #pragma unroll
  for (int i = 0; i < 16; ++i) acc[i] = 0.f;
  for (int k0 = 0; k0 < 256; k0 += 32){
    #pragma unroll
    for (int i = 0; i < 2; ++i){
      int idx = t + 256*i;
      int row = idx >> 3, kk = (idx & 7)*4;
      float4 v = *(const float4*)(A + (size_t)(m0+row)*256 + k0 + kk);
      As[(kk+0)*68+row]=v.x; As[(kk+1)*68+row]=v.y; As[(kk+2)*68+row]=v.z; As[(kk+3)*68+row]=v.w;
    }
    #pragma unroll
    for (int i = 0; i < 2; ++i){
      int idx = t + 256*i;
      int kk = idx >> 4, cc = (idx & 15)*4;
      int gk = k0 + kk, gc = c0 + cc;
      float4 v = make_float4(0.f,0.f,0.f,0.f);
      const float* wp = W + (size_t)gk*264 + gc;
      if (gc + 3 < 264) v = *(const float4*)wp;
      else {
        if (gc   < 264) v.x = wp[0];
        if (gc+1 < 264) v.y = wp[1];
        if (gc+2 < 264) v.z = wp[2];
        if (gc+3 < 264) v.w = wp[3];
      }
      *(float4*)(Ws + kk*68 + cc) = v;
    }
    __syncthreads();
    #pragma unroll
    for (int j = 0; j < 32; ++j){
      float4 a = *(const float4*)(As + j*68 + mq);
      float4 w = *(const float4*)(Ws + j*68 + cq);
      acc[ 0]+=a.x*w.x; acc[ 1]+=a.x*w.y; acc[ 2]+=a.x*w.z; acc[ 3]+=a.x*w.w;
      acc[ 4]+=a.y*w.x; acc[ 5]+=a.y*w.y; acc[ 6]+=a.y*w.z; acc[ 7]+=a.y*w.w;
      acc[ 8]+=a.z*w.x; acc[ 9]+=a.z*w.y; acc[10]+=a.z*w.z; acc[11]+=a.z*w.w;
      acc[12]+=a.w*w.x; acc[13]+=a.w*w.y; acc[14]+=a.w*w.z; acc[15]+=a.w*w.w;
    }
    __syncthreads();
  }
  ushort_t* WH = z ? WtfvH : WtfkH;
  ushort_t* WL = z ? WtfvL : WtfkL;
  #pragma unroll
  for (int i = 0; i < 4; ++i){
    int gm = m0 + mq + i;
    #pragma unroll
    for (int j = 0; j < 4; ++j){
      int gc = c0 + cq + j;
      ushort_t hh, ll; split2(acc[i*4+j], hh, ll);
      WH[(size_t)gc*256 + gm] = hh;
      WL[(size_t)gc*256 + gm] = ll;
    }
  }
}

// ---------------- unified big MFMA kernel ----------------
// grid (128, 8, 6):
//  z=0 (x<4,y<5): qh  = F @Wtq -> f32 [512][264]
//  z=1 (y<5):     kh  = MK@Wtk -> split [16384][320] + k32g f32 [8][16384]
//  z=2 (y<5):     Vt  = MV@Wtv -> split transposed [8*48][16384]
//  z=3 (y<8):     surprise min -> atomicMin minD2
//  z=4 (x<4,y<5): khB = F @Wtfk -> f32 [512][264]
//  z=5 (x<4,y<5): VtB = F @Wtfv -> f32 [512][264]
__global__ __launch_bounds__(256, 4) void big_mfma(
    const ushort_t* __restrict__ FH, const ushort_t* __restrict__ FL,
    const ushort_t* __restrict__ MKH, const ushort_t* __restrict__ MKL,
    const ushort_t* __restrict__ MVH, const ushort_t* __restrict__ MVL,
    const ushort_t* __restrict__ WtqH, const ushort_t* __restrict__ WtqL,
    const ushort_t* __restrict__ WtkH, const ushort_t* __restrict__ WtkL,
    const ushort_t* __restrict__ WtvH, const ushort_t* __restrict__ WtvL,
    const ushort_t* __restrict__ WtfkH, const ushort_t* __restrict__ WtfkL,
    const ushort_t* __restrict__ WtfvH, const ushort_t* __restrict__ WtfvL,
    const float* __restrict__ bpq, const float* __restrict__ bpk, const float* __restrict__ bpv,
    const float* __restrict__ bfk, const float* __restrict__ bfv,
    const float* __restrict__ k2,
    float* __restrict__ qh, float* __restrict__ khB, float* __restrict__ VtB,
    ushort_t* __restrict__ khH, ushort_t* __restrict__ khL, float* __restrict__ k32g,
    ushort_t* __restrict__ VtGH, ushort_t* __restrict__ VtGL, unsigned* __restrict__ minD2){
  int z = blockIdx.z;
  int bx = blockIdx.x, by = blockIdx.y;
  if ((z == 0 || z >= 4) && bx >= 4) return;
  if (z != 3 && by >= 5) return;
  __shared__ ushort_t AsH[128*32];
  __shared__ ushort_t AsL[128*32];
  __shared__ ushort_t BsH[64*32];
  __shared__ ushort_t BsL[64*32];
  __shared__ unsigned sminU[64];
  const ushort_t* AH = (z == 2) ? MVH : (z == 1 || z == 3) ? MKH : FH;
  const ushort_t* AL = (z == 2) ? MVL : (z == 1 || z == 3) ? MKL : FL;
  const ushort_t* BH = (z==0) ? WtqH : (z==1) ? WtkH : (z==2) ? WtvH : (z==3) ? FH : (z==4) ? WtfkH : WtfvH;
  const ushort_t* BL = (z==0) ? WtqL : (z==1) ? WtkL : (z==2) ? WtvL : (z==4) ? WtfkL : WtfvL;
  const float* bias = (z==0) ? bpq : (z==1) ? bpk : (z==2) ? bpv : (z==4) ? bfk : bfv;
  float* Cf = (z==0) ? qh : (z==4) ? khB : VtB;
  int t = threadIdx.x;
  int m0 = bx*128, n0 = by*64;
  int lane = t & 63, w = t >> 6;
  int wm = (w & 1)*64, wn = (w >> 1)*32;
  int l15 = lane & 15, q = lane >> 4;
  if (z == 3 && t < 64) sminU[t] = 0xFFFFFFFFu;
  v4f acc[4][2];
  #pragma unroll
  for (int i = 0; i < 4; ++i)
    #pragma unroll
    for (int j = 0; j < 2; ++j) acc[i][j] = (v4f){0.f,0.f,0.f,0.f};

  for (int k0 = 0; k0 < 256; k0 += 32){
    #pragma unroll
    for (int c = 0; c < 2; ++c){
      int u0 = (c*4 + w)*64;
      int u  = u0 + lane;
      int row = u >> 2, ch = u & 3;
      gl2lds16(AH + (size_t)(m0+row)*256 + k0 + ch*8, AsH + (size_t)u0*8);
      if (z != 3) gl2lds16(AL + (size_t)(m0+row)*256 + k0 + ch*8, AsL + (size_t)u0*8);
    }
    {
      int u = w*64 + lane;
      int row = u >> 2, ch = u & 3;
      gl2lds16(BH + (size_t)(n0+row)*256 + k0 + ch*8, BsH + (size_t)w*512);
      if (z != 3) gl2lds16(BL + (size_t)(n0+row)*256 + k0 + ch*8, BsL + (size_t)w*512);
    }
    __syncthreads();
    if (z != 3){
      v8s aH[4], aL[4], bH[2], bL[2];
      #pragma unroll
      for (int im = 0; im < 4; ++im){
        aH[im] = *(const v8s*)(AsH + (wm + im*16 + l15)*32 + q*8);
        aL[im] = *(const v8s*)(AsL + (wm + im*16 + l15)*32 + q*8);
      }
      #pragma unroll
      for (int jn = 0; jn < 2; ++jn){
        bH[jn] = *(const v8s*)(BsH + (wn + jn*16 + l15)*32 + q*8);
        bL[jn] = *(const v8s*)(BsL + (wn + jn*16 + l15)*32 + q*8);
      }
      #pragma unroll
      for (int im = 0; im < 4; ++im)
        #pragma unroll
        for (int jn = 0; jn < 2; ++jn){
          acc[im][jn] = __builtin_amdgcn_mfma_f32_16x16x32_bf16(aH[im], bH[jn], acc[im][jn], 0, 0, 0);
          acc[im][jn] = __builtin_amdgcn_mfma_f32_16x16x32_bf16(aH[im], bL[jn], acc[im][jn], 0, 0, 0);
          acc[im][jn] = __builtin_amdgcn_mfma_f32_16x16x32_bf16(aL[im], bH[jn], acc[im][jn], 0, 0, 0);
        }
    } else {
      v8s aH[4], bH[2];
      #pragma unroll
      for (int im = 0; im < 4; ++im) aH[im] = *(const v8s*)(AsH + (wm + im*16 + l15)*32 + q*8);
      #pragma unroll
      for (int jn = 0; jn < 2; ++jn) bH[jn] = *(const v8s*)(BsH + (wn + jn*16 + l15)*32 + q*8);
      #pragma unroll
      for (int im = 0; im < 4; ++im)
        #pragma unroll
        for (int jn = 0; jn < 2; ++jn)
          acc[im][jn] = __builtin_amdgcn_mfma_f32_16x16x32_bf16(aH[im], bH[jn], acc[im][jn], 0, 0, 0);
    }
    __syncthreads();
  }

  if (z == 3){
    float kk[4][4];
    #pragma unroll
    for (int im = 0; im < 4; ++im)
      #pragma unroll
      for (int r = 0; r < 4; ++r) kk[im][r] = k2[m0 + wm + im*16 + q*4 + r];
    #pragma unroll
    for (int jn = 0; jn < 2; ++jn){
      float mv = INFINITY;
      #pragma unroll
      for (int im = 0; im < 4; ++im)
        #pragma unroll
        for (int r = 0; r < 4; ++r)
          mv = fminf(mv, kk[im][r] - 2.f*acc[im][jn][r]);
      mv = fminf(mv, __shfl_xor(mv, 16, 64));
      mv = fminf(mv, __shfl_xor(mv, 32, 64));
      if (q == 0) atomicMin(&sminU[wn + jn*16 + l15], fenc(mv));
    }
    __syncthreads();
    if (t < 64) atomicMin(&minD2[n0 + t], sminU[t]);
    return;
  }
  #pragma unroll
  for (int im = 0; im < 4; ++im){
    #pragma unroll
    for (int jn = 0; jn < 2; ++jn){
      int n = n0 + wn + jn*16 + l15;
      if (n >= 264) continue;
      float bv = bias[n];
      int mb = m0 + wm + im*16 + q*4;
      if (z == 1){
        int hh = n/33, dd = n - hh*33;
        int col = hh*40 + dd;
        #pragma unroll
        for (int r = 0; r < 4; ++r){
          float val = acc[im][jn][r] + bv;
          ushort_t sh, sl; split2(val, sh, sl);
          khH[(size_t)(mb+r)*320 + col] = sh;
          khL[(size_t)(mb+r)*320 + col] = sl;
          if (dd == 32) k32g[(size_t)hh*16384 + mb + r] = val;
        }
      } else if (z == 2){
        int hh = n/33, dd = n - hh*33;
        size_t rowb = (size_t)(hh*48 + dd)*16384 + mb;
        ushort4 hv, lv;
        split2(acc[im][jn][0] + bv, hv.x, lv.x);
        split2(acc[im][jn][1] + bv, hv.y, lv.y);
        split2(acc[im][jn][2] + bv, hv.z, lv.z);
        split2(acc[im][jn][3] + bv, hv.w, lv.w);
        *(ushort4*)(VtGH + rowb) = hv;
        *(ushort4*)(VtGL + rowb) = lv;
      } else {
        #pragma unroll
        for (int r = 0; r < 4; ++r) Cf[(size_t)(mb+r)*264 + n] = acc[im][jn][r] + bv;
      }
    }
  }
}

// ---------------- eviction scan (unchanged) ----------------
#define SCAN_CAP 1024
__global__ __launch_bounds__(1024) void scan_kernel(
    const float* __restrict__ mem_surprise, const float* __restrict__ mem_ages,
    const unsigned* __restrict__ minD2, const float* __restrict__ f2, const float* __restrict__ gn,
    float* __restrict__ parr, int* __restrict__ slotForB, int* __restrict__ lastB){
  __shared__ unsigned hist[2048];
  __shared__ float candV[SCAN_CAP];
  __shared__ int   candI[SCAN_CAP];
  __shared__ float tv[1024];
  __shared__ int   ti[1024];
  __shared__ float ssur[512];
  __shared__ int   smemz[512];
  __shared__ int   wtot[16];
  __shared__ int   sh_misc[8];
  int t = threadIdx.x;

  int mem = 0;
  if (t < 512){
    float d2 = fdec(minD2[t]) + f2[t];
    float s = gn[t]*sqrtf(fmaxf(d2, 0.f));
    ssur[t] = s;
    mem = (s > 0.1f) ? 1 : 0;
    smemz[t] = mem;
  }
  const float LN095 = -0.05129329438755058f;
  #pragma unroll
  for (int j = 0; j < 16; ++j){
    int m = t*16 + j;
    float p = mem_surprise[m] * __expf(mem_ages[m] * LN095);
    parr[m] = p;
    lastB[m] = -1;
  }
  hist[t] = 0u; hist[t + 1024] = 0u;
  if (t < 8) sh_misc[t] = (t == 3) ? 0x7F800000 : 0;
  __syncthreads();
  #pragma unroll
  for (int j = 0; j < 16; ++j){
    int m = t*16 + j;
    unsigned key = __float_as_uint(parr[m]) >> 20;
    if (key > 2047u) key = 2047u;
    atomicAdd(&hist[key], 1u);
  }
  __syncthreads();
  if (t < 512){ ti[t] = (int)(hist[4*t] + hist[4*t+1] + hist[4*t+2] + hist[4*t+3]); }
  __syncthreads();
  if (t < 32){ int s = 0; for (int i = 0; i < 16; ++i) s += ti[16*t + i]; ti[512 + t] = s; }
  __syncthreads();
  if (t == 0){
    int cum = 0, i2 = 0;
    for (; i2 < 32; ++i2){ if (cum + ti[512+i2] >= 512) break; cum += ti[512+i2]; }
    int i1 = i2*16;
    for (;; ++i1){ if (cum + ti[i1] >= 512) break; cum += ti[i1]; }
    int bin = i1*4;
    for (;; ++bin){ if (cum + (int)hist[bin] >= 512) break; cum += (int)hist[bin]; }
    sh_misc[1] = bin;
  }
  __syncthreads();
  int threshKey = sh_misc[1];
  #pragma unroll
  for (int j = 0; j < 16; ++j){
    int m = t*16 + j;
    unsigned key = __float_as_uint(parr[m]) >> 20;
    if (key > 2047u) key = 2047u;
    if ((int)key <= threshKey){
      int pos = atomicAdd(&sh_misc[0], 1);
      if (pos < SCAN_CAP){ candV[pos] = parr[m]; candI[pos] = m; }
    }
  }
  __syncthreads();
  int cnt = sh_misc[0];
  if (t >= cnt && t < SCAN_CAP){ candV[t] = INFINITY; candI[t] = 0x7FFFFFFF; }
  __syncthreads();
  for (int ksz = 2; ksz <= SCAN_CAP; ksz <<= 1){
    for (int jj = ksz >> 1; jj > 0; jj >>= 1){
      int ixj = t ^ jj;
      if (ixj > t){
        float v1 = candV[t], v2 = candV[ixj];
        int i1 = candI[t], i2 = candI[ixj];
        bool lt21 = (v2 < v1) || (v2 == v1 && i2 < i1);
        bool lt12 = (v1 < v2) || (v1 == v2 && i1 < i2);
        bool up = ((t & ksz) == 0);
        bool sw = up ? lt21 : lt12;
        if (sw){ candV[t] = v2; candI[t] = i2; candV[ixj] = v1; candI[ixj] = i1; }
      }
      __syncthreads();
    }
  }
  int lp = 0;
  if (t < 512){
    unsigned long long mask = __ballot(mem != 0);
    int lane = t & 63;
    lp = __popcll(mask & ((1ull << lane) - 1ull));
    if (lane == 0) wtot[t >> 6] = __popcll(mask);
  }
  if (t < 512 && mem) atomicMin(&sh_misc[3], __float_as_int(ssur[t]));
  __syncthreads();
  if (t == 0){
    int ksum = 0;
    for (int wv = 0; wv < 8; ++wv) ksum += wtot[wv];
    sh_misc[4] = ksum;
    bool okf = (cnt <= SCAN_CAP) && (ksum <= cnt);
    if (okf && ksum > 0){
      float minw = __int_as_float(sh_misc[3]);
      okf = (minw > candV[ksum - 1]);
    }
    sh_misc[2] = okf ? 1 : 0;
  }
  __syncthreads();
  if (sh_misc[2] == 1){
    if (t < 512){
      int wv = t >> 6, base = 0;
      for (int i = 0; i < wv; ++i) base += wtot[i];
      int slot = -1;
      if (mem){ slot = candI[base + lp]; atomicMax(&lastB[slot], t); }
      slotForB[t] = slot;
    }
  } else {
    for (int b = 0; b < 512; ++b){
      float bv = parr[t*16]; int bi = t*16;
      #pragma unroll
      for (int j = 1; j < 16; ++j){
        float v = parr[t*16 + j];
        if (v < bv){ bv = v; bi = t*16 + j; }
      }
      tv[t] = bv; ti[t] = bi;
      __syncthreads();
      for (int s = 512; s > 0; s >>= 1){
        if (t < s){
          float v2 = tv[t+s]; int i2 = ti[t+s];
          if (v2 < tv[t] || (v2 == tv[t] && i2 < ti[t])){ tv[t] = v2; ti[t] = i2; }
        }
        __syncthreads();
      }
      int slot = ti[0];
      int memb = smemz[b];
      if (t == 0) slotForB[b] = memb ? slot : -1;
      if (memb && t == (slot >> 4)) parr[slot] = ssur[b];
      __syncthreads();
    }
    if (t < 512){ int s = slotForB[t]; if (s >= 0) atomicMax(&lastB[s], t); }
  }
}

// ---------------- fixup: pure scatter of precomputed rows ----------------
__global__ __launch_bounds__(64) void fixup_rows(const int* __restrict__ slotForB, const int* __restrict__ lastB,
                                                 const float* __restrict__ khB, const float* __restrict__ VtB,
                                                 ushort_t* __restrict__ khH, ushort_t* __restrict__ khL,
                                                 ushort_t* __restrict__ VtH, ushort_t* __restrict__ VtL,
                                                 float* __restrict__ k32g){
  int b = blockIdx.x;
  int slot = slotForB[b];
  if (slot < 0) return;
  if (lastB[slot] != b) return;
  int t = threadIdx.x;
  for (int c = t; c < 264; c += 64){
    int hh = c/33, dd = c - hh*33;
    float kv = khB[(size_t)b*264 + c];
    ushort_t sh, sl;
    split2(kv, sh, sl);
    khH[(size_t)slot*320 + hh*40 + dd] = sh;
    khL[(size_t)slot*320 + hh*40 + dd] = sl;
    if (dd == 32) k32g[(size_t)hh*16384 + slot] = kv;
    float vv = VtB[(size_t)b*264 + c];
    split2(vv, sh, sl);
    VtH[(size_t)(hh*48 + dd)*16384 + slot] = sh;
    VtL[(size_t)(hh*48 + dd)*16384 + slot] = sl;
  }
}

// ---------------- MFMA flash attention: full-async staging, register softmax ----------------
__global__ __launch_bounds__(256, 4) void attn_mfma(
    const float* __restrict__ qh, const ushort_t* __restrict__ khH, const ushort_t* __restrict__ khL,
    const ushort_t* __restrict__ VtGH, const ushort_t* __restrict__ VtGL, const float* __restrict__ k32g,
    float* __restrict__ pm, float* __restrict__ pl, float* __restrict__ pctx){
  const int h = blockIdx.x, bt = blockIdx.y, ms = blockIdx.z;
  const int b0 = bt*64, mbase = ms*(16384/ATTN_MS);
  const int t = threadIdx.x, lane = t & 63, w = t >> 6;
  const int l15 = lane & 15, q = lane >> 4;
  __shared__ ushort_t KH[64*32], KL[64*32];       // row-major, 64B rows
  __shared__ ushort_t VsH[48*64], VsL[48*64];     // row-major 128B rows, XOR-chunk swizzle
  __shared__ ushort_t PH[4*16*72], PL[4*16*72];
  __shared__ float k32fs[64];
  const float scale = 0.17407765595569785f; // 1/sqrt(33)

  const int bq = b0 + 16*w + l15;
  U8 qHU, qLU;
  {
    const float* qp = qh + (size_t)bq*264 + h*33 + q*8;
    #pragma unroll
    for (int j = 0; j < 8; ++j) split2(qp[j]*scale, qHU.u[j], qLU.u[j]);
  }
  const v8s bQH = qHU.v, bQL = qLU.v;
  const float q32v = qh[(size_t)bq*264 + h*33 + 32]*scale;
  float rMv = -INFINITY, rLv = 0.f;
  v4f cacc[3];
  #pragma unroll
  for (int i = 0; i < 3; ++i) cacc[i] = (v4f){0.f,0.f,0.f,0.f};
  ushort_t* PHw = PH + w*16*72;
  ushort_t* PLw = PL + w*16*72;

  // zero V pad rows 33..47 once (never re-staged)
  {
    unsigned* vh32 = (unsigned*)(VsH + 33*64);
    unsigned* vl32 = (unsigned*)(VsL + 33*64);
    for (int e = t; e < 480; e += 256){ vh32[e] = 0u; vl32[e] = 0u; }
  }

  for (int mt = 0; mt < 16384/ATTN_MS/64; ++mt){
    const int m0 = mbase + mt*64;
    __syncthreads();   // prior-iter LDS reads complete; pad zeros visible (iter 0)
    {
      // K rows 0..63, d 0..31 (4 chunks/row)
      int u = w*64 + lane;
      int row = u >> 2, ch = u & 3;
      gl2lds16(khH + (size_t)(m0+row)*320 + h*40 + ch*8, KH + (size_t)w*512);
      gl2lds16(khL + (size_t)(m0+row)*320 + h*40 + ch*8, KL + (size_t)w*512);
      // V rows 0..31 (8 chunks/row, XOR swizzle)
      int dd = u >> 3, chl = u & 7;
      int gch = chl ^ (dd & 7);
      gl2lds16(VtGH + (size_t)(h*48 + dd)*16384 + m0 + gch*8, VsH + (size_t)w*512);
      gl2lds16(VtGL + (size_t)(h*48 + dd)*16384 + m0 + gch*8, VsL + (size_t)w*512);
    }
    if (w == 0){
      if (lane < 8){
        // V row 32 (chunk swizzle identity since 32&7==0)
        gl2lds16(VtGH + (size_t)(h*48 + 32)*16384 + m0 + lane*8, VsH + 32*64);
        gl2lds16(VtGL + (size_t)(h*48 + 32)*16384 + m0 + lane*8, VsL + 32*64);
      }
      if (lane < 16){
        gl2lds16(k32g + ((size_t)h << 14) + m0 + lane*4, k32fs);
      }
    }
    __syncthreads();   // staging visible
    // ---- QK^T ----
    v4f s4[4];
    #pragma unroll
    for (int im = 0; im < 4; ++im){
      v8s aH = *(const v8s*)(KH + (im*16 + l15)*32 + q*8);
      v8s aL = *(const v8s*)(KL + (im*16 + l15)*32 + q*8);
      v4f sv = (v4f){0.f,0.f,0.f,0.f};
      sv = __builtin_amdgcn_mfma_f32_16x16x32_bf16(aH, bQH, sv, 0, 0, 0);
      sv = __builtin_amdgcn_mfma_f32_16x16x32_bf16(aH, bQL, sv, 0, 0, 0);
      sv = __builtin_amdgcn_mfma_f32_16x16x32_bf16(aL, bQH, sv, 0, 0, 0);
      s4[im] = sv;
    }
    #pragma unroll
    for (int im = 0; im < 4; ++im){
      float4 kv = *(const float4*)(k32fs + im*16 + q*4);
      s4[im][0] += kv.x*q32v; s4[im][1] += kv.y*q32v;
      s4[im][2] += kv.z*q32v; s4[im][3] += kv.w*q32v;
    }
    // ---- online softmax (register state) ----
    float mx = -INFINITY;
    #pragma unroll
    for (int im = 0; im < 4; ++im)
      #pragma unroll
      for (int r = 0; r < 4; ++r) mx = fmaxf(mx, s4[im][r]);
    mx = fmaxf(mx, __shfl_xor(mx, 16, 64));
    mx = fmaxf(mx, __shfl_xor(mx, 32, 64));
    float nm = fmaxf(rMv, mx);
    float alf = __expf(rMv - nm);
    rMv = nm;
    float sm = 0.f;
    #pragma unroll
    for (int im = 0; im < 4; ++im){
      v4f p;
      #pragma unroll
      for (int r = 0; r < 4; ++r){ p[r] = __expf(s4[im][r] - nm); sm += p[r]; }
      ushort4 hv, lv;
      split2(p[0], hv.x, lv.x); split2(p[1], hv.y, lv.y);
      split2(p[2], hv.z, lv.z); split2(p[3], hv.w, lv.w);
      *(ushort4*)(PHw + l15*72 + im*16 + q*4) = hv;
      *(ushort4*)(PLw + l15*72 + im*16 + q*4) = lv;
    }
    sm += __shfl_xor(sm, 16, 64);
    sm += __shfl_xor(sm, 32, 64);
    rLv = rLv*alf + sm;
    #pragma unroll
    for (int r = 0; r < 4; ++r){
      float ar = __shfl(alf, q*4 + r, 64);
      cacc[0][r] *= ar; cacc[1][r] *= ar; cacc[2][r] *= ar;
    }
    // ---- PV ----
    #pragma unroll
    for (int ks = 0; ks < 2; ++ks){
      v8s paH = *(const v8s*)(PHw + l15*72 + ks*32 + q*8);
      v8s paL = *(const v8s*)(PLw + l15*72 + ks*32 + q*8);
      #pragma unroll
      for (int tile = 0; tile < 3; ++tile){
        int vrow = tile*16 + l15;
        int mch = (ks*4 + q) ^ (l15 & 7);
        v8s vbH = *(const v8s*)(VsH + vrow*64 + mch*8);
        v8s vbL = *(const v8s*)(VsL + vrow*64 + mch*8);
        cacc[tile] = __builtin_amdgcn_mfma_f32_16x16x32_bf16(paH, vbH, cacc[tile], 0, 0, 0);
        cacc[tile] = __builtin_amdgcn_mfma_f32_16x16x32_bf16(paH, vbL, cacc[tile], 0, 0, 0);
        cacc[tile] = __builtin_amdgcn_mfma_f32_16x16x32_bf16(paL, vbH, cacc[tile], 0, 0, 0);
      }
    }
  }
  int g = (h*8 + bt)*ATTN_MS + ms;
  if (q == 0){
    pm[(size_t)g*64 + 16*w + l15] = rMv;
    pl[(size_t)g*64 + 16*w + l15] = rLv;
  }
  #pragma unroll
  for (int tile = 0; tile < 3; ++tile){
    int d = tile*16 + l15;
    if (d < 33){
      #pragma unroll
      for (int r = 0; r < 4; ++r)
        pctx[((size_t)g*64 + 16*w + q*4 + r)*33 + d] = cacc[tile][r];
    }
  }
}

__global__ __launch_bounds__(256) void combine_kernel(const float* __restrict__ pm, const float* __restrict__ pl,
                                                      const float* __restrict__ pctx, float* __restrict__ ctxf){
  int idx = blockIdx.x*256 + threadIdx.x;
  if (idx >= 512*264) return;
  int b = idx / 264, c = idx - b*264;
  int h = c / 33, d = c - h*33;
  int bt = b >> 6, bl = b & 63;
  int g0 = (h*8 + bt)*ATTN_MS;
  float gm = -INFINITY;
  for (int ms = 0; ms < ATTN_MS; ++ms) gm = fmaxf(gm, pm[(g0+ms)*64 + bl]);
  float L = 0.f, cv = 0.f;
  for (int ms = 0; ms < ATTN_MS; ++ms){
    int gg = (g0+ms)*64 + bl;
    float w = __expf(pm[gg] - gm);
    L += pl[gg]*w;
    cv += pctx[(size_t)gg*33 + d]*w;
  }
  ctxf[idx] = cv / L;
}

// ---------------- host ----------------
extern "C" void kernel_launch(void* const* d_in, const int* in_sizes, int n_in,
                              void* d_out, int out_size, void* d_ws, size_t ws_size,
                              hipStream_t stream){
  (void)in_sizes; (void)n_in; (void)out_size; (void)ws_size;
  const float* features     = (const float*)d_in[0];
  const float* gradients    = (const float*)d_in[1];
  const float* mem_keys     = (const float*)d_in[2];
  const float* mem_values   = (const float*)d_in[3];
  const float* mem_ages     = (const float*)d_in[4];
  const float* mem_surprise = (const float*)d_in[5];
  const float* Wk   = (const float*)d_in[6];
  const float* bk   = (const float*)d_in[7];
  const float* Wv   = (const float*)d_in[8];
  const float* bv   = (const float*)d_in[9];
  const float* Wp   = (const float*)d_in[10];
  const float* bp   = (const float*)d_in[11];
  const float* Win  = (const float*)d_in[12];
  const float* b_in = (const float*)d_in[13];
  const float* Wout = (const float*)d_in[14];
  const float* bout = (const float*)d_in[15];
  const float* Wo   = (const float*)d_in[16];
  const float* bo   = (const float*)d_in[17];
  float* out = (float*)d_out;

  float* w = (float*)d_ws;
  size_t off = 0;
  auto alloc = [&](size_t n)->float*{ float* p = w + off; off += (n + 63) & ~(size_t)63; return p; };
  float*    k2       = alloc(16384);
  unsigned* minD2    = (unsigned*)alloc(512);
  float*    f2       = alloc(512);
  float*    gn       = alloc(512);
  int*      slotForB = (int*)alloc(512);
  int*      lastB    = (int*)alloc(16384);
  float*    parr     = alloc(16384);
  float*    khB      = alloc((size_t)512*264);
  float*    VtB      = alloc((size_t)512*264);
  float*    qh       = alloc((size_t)512*264);
  float*    k32g     = alloc((size_t)8*16384);
  ushort_t* khH      = (ushort_t*)alloc((size_t)16384*320/2);
  ushort_t* khL      = (ushort_t*)alloc((size_t)16384*320/2);
  ushort_t* VtGH     = (ushort_t*)alloc((size_t)8*48*16384/2);
  ushort_t* VtGL     = (ushort_t*)alloc((size_t)8*48*16384/2);
  float*    MKbase   = alloc((size_t)16384*256/2*2);
  ushort_t* MKH      = (ushort_t*)MKbase;
  ushort_t* MKL      = (ushort_t*)(MKbase + (size_t)16384*256/2);
  float*    MVbase   = alloc((size_t)16384*256/2*2);
  ushort_t* MVH      = (ushort_t*)MVbase;
  ushort_t* MVL      = (ushort_t*)(MVbase + (size_t)16384*256/2);
  ushort_t* FH       = (ushort_t*)alloc((size_t)512*256/2);
  ushort_t* FL       = (ushort_t*)alloc((size_t)512*256/2);
  float*    Wpk      = alloc((size_t)256*264);
  float*    Wpv      = alloc((size_t)256*264);
  float*    Wco      = alloc((size_t)264*256);
  ushort_t* WtkH     = (ushort_t*)alloc((size_t)320*256/2);
  ushort_t* WtkL     = (ushort_t*)alloc((size_t)320*256/2);
  ushort_t* WtvH     = (ushort_t*)alloc((size_t)320*256/2);
  ushort_t* WtvL     = (ushort_t*)alloc((size_t)320*256/2);
  ushort_t* WtqH     = (ushort_t*)alloc((size_t)320*256/2);
  ushort_t* WtqL     = (ushort_t*)alloc((size_t)320*256/2);
  ushort_t* WtfkH    = (ushort_t*)alloc((size_t)320*256/2);
  ushort_t* WtfkL    = (ushort_t*)alloc((size_t)320*256/2);
  ushort_t* WtfvH    = (ushort_t*)alloc((size_t)320*256/2);
  ushort_t* WtfvL    = (ushort_t*)alloc((size_t)320*256/2);
  float*    bpq      = alloc(264);
  float*    bpk      = alloc(264);
  float*    bpv      = alloc(264);
  float*    bco      = alloc(256);
  float*    bfk      = alloc(264);
  float*    bfv      = alloc(264);
  // aliases: MK region (dead after big_mfma) hosts pm/pl/ctxf; MV region hosts pctx
  float*    pm       = MKbase;
  float*    pl       = MKbase + (size_t)ATTN_MS*64*64;
  float*    ctxf     = pl + (size_t)ATTN_MS*64*64;
  float*    pctx     = MVbase;

  prep_all<<<dim3(4096,3), 256, 0, stream>>>(features, gradients, mem_keys, mem_values,
      FH, FL, MKH, MKL, MVH, MVL, k2, f2, gn, minD2);

  wprep_gemm<<<dim3(5,5,5), 256, 0, stream>>>(Wp, Win, Wout, Wo, bp, b_in, bout, bo,
      WtkH, WtkL, WtvH, WtvL, WtqH, WtqL, Wpk, Wpv, Wco, bpq, bpk, bpv, bco);

  wprep2<<<dim3(5,5,3), 256, 0, stream>>>(Wk, Wv, Wpk, Wpv, bk, bv, bpk, bpv,
      WtfkH, WtfkL, WtfvH, WtfvL, bfk, bfv);

  big_mfma<<<dim3(128,8,6), 256, 0, stream>>>(FH, FL, MKH, MKL, MVH, MVL,
      WtqH, WtqL, WtkH, WtkL, WtvH, WtvL, WtfkH, WtfkL, WtfvH, WtfvL,
      bpq, bpk, bpv, bfk, bfv, k2,
      qh, khB, VtB, khH, khL, k32g, VtGH, VtGL, minD2);

  scan_kernel<<<1, 1024, 0, stream>>>(mem_surprise, mem_ages, minD2, f2, gn, parr, slotForB, lastB);
  fixup_rows<<<512, 64, 0, stream>>>(slotForB, lastB, khB, VtB, khH, khL, VtGH, VtGL, k32g);

  attn_mfma<<<dim3(8,8,ATTN_MS), 256, 0, stream>>>(qh, khH, khL, VtGH, VtGL, k32g, pm, pl, pctx);
  combine_kernel<<<528, 256, 0, stream>>>(pm, pl, pctx, ctxf);
  gemm_bias<<<dim3(8,4), 256, 0, stream>>>(ctxf, Wco, bco, out, 512, 264, 256, 256, 0);
}